// Round 12
// baseline (666.510 us; speedup 1.0000x reference)
//
#include <hip/hip_runtime.h>
#include <hip/hip_bf16.h>

#define KS 5
#define K3 125

__device__ inline float4 f4fma(float a, float4 b, float4 c) {
    c.x = fmaf(a, b.x, c.x); c.y = fmaf(a, b.y, c.y);
    c.z = fmaf(a, b.z, c.z); c.w = fmaf(a, b.w, c.w);
    return c;
}

__device__ inline unsigned enc_f(float f) {
    int b = __float_as_int(f);
    return (b >= 0) ? ((unsigned)b | 0x80000000u) : ~((unsigned)b);
}

// ---------------------------------------------------------------------------
// Inline basis helpers
// ---------------------------------------------------------------------------
__device__ inline void edge_basis(const float* __restrict__ pseudo, int e,
                                  float* bs, int* ks) {
    float fr[3];
    int bot[3];
#pragma unroll
    for (int d = 0; d < 3; ++d) {
        float v = pseudo[e * 3 + d] * (float)(KS - 1);
        float fl = fminf(floorf(v), (float)(KS - 2));
        fr[d] = v - fl;
        bot[d] = (int)fl;
    }
    const int strides[3] = {1, KS, KS * KS};
#pragma unroll
    for (int s = 0; s < 8; ++s) {
        float b = 1.f;
        int w = 0;
#pragma unroll
        for (int d = 0; d < 3; ++d) {
            int bit = (s >> d) & 1;
            b *= bit ? fr[d] : (1.f - fr[d]);
            w += (bot[d] + bit) * strides[d];
        }
        bs[s] = b;
        ks[s] = w;
    }
}

__device__ inline void edge_fracs(const float* __restrict__ pseudo, int e, float* bs) {
    float fr[3];
#pragma unroll
    for (int d = 0; d < 3; ++d) {
        float v = pseudo[e * 3 + d] * (float)(KS - 1);
        float fl = fminf(floorf(v), (float)(KS - 2));
        fr[d] = v - fl;
    }
#pragma unroll
    for (int s = 0; s < 8; ++s) {
        float b = 1.f;
#pragma unroll
        for (int d = 0; d < 3; ++d) b *= ((s >> d) & 1) ? fr[d] : (1.f - fr[d]);
        bs[s] = b;
    }
}

__device__ inline int edge_bucket(const float* __restrict__ pseudo, int e) {
    int kb = 0;
#pragma unroll
    for (int d = 0; d < 3; ++d) {
        float v = pseudo[e * 3 + d] * (float)(KS - 1);
        int fl = (int)fminf(floorf(v), (float)(KS - 2));
        kb += fl << (2 * d);
    }
    return kb;
}

// ---------------------------------------------------------------------------
// Pre-pass 1 (all 4 levels): 64-bucket histogram + int degree.
// ---------------------------------------------------------------------------
__global__ __launch_bounds__(256) void hist_deg_all(
    const float* __restrict__ p0, const float* __restrict__ p1,
    const float* __restrict__ p2, const float* __restrict__ p3,
    const int* __restrict__ d0, const int* __restrict__ d1,
    const int* __restrict__ d2, const int* __restrict__ d3,
    int* __restrict__ hist, int* __restrict__ degi) {
    int b = blockIdx.x;
    int l, lb, E, dof;
    const float* ps;
    const int* ds;
    if (b < 512)      { l = 0; lb = b;       ps = p0; ds = d0; E = 131072; dof = 0; }
    else if (b < 640) { l = 1; lb = b - 512; ps = p1; ds = d1; E = 32768;  dof = 16384; }
    else if (b < 672) { l = 2; lb = b - 640; ps = p2; ds = d2; E = 8192;   dof = 20480; }
    else              { l = 3; lb = b - 672; ps = p3; ds = d3; E = 2048;   dof = 21504; }
    __shared__ int h[64];
    int t = threadIdx.x;
    if (t < 64) h[t] = 0;
    __syncthreads();
    int e = lb * 256 + t;
    if (e < E) {
        atomicAdd(&h[edge_bucket(ps, e)], 1);
        atomicAdd(&degi[dof + ds[e]], 1);
    }
    __syncthreads();
    if (t < 64 && h[t]) atomicAdd(&hist[l * 64 + t], h[t]);
}

// ---------------------------------------------------------------------------
// Pre-pass 2: bucket layout per level (blockIdx = level).
// ---------------------------------------------------------------------------
__global__ void scan_pad_all(const int* __restrict__ hist, int* __restrict__ gcur,
                             int* __restrict__ tileOf, int* __restrict__ pack) {
    const int TBv[4] = {0, 2112, 2112 + 576, 2112 + 576 + 192};
    int l = blockIdx.x;
    int tileBase = TBv[l];
    __shared__ int sh[64];
    int t = threadIdx.x;
    int cnt = hist[l * 64 + t];
    int tiles = (cnt + 63) >> 6;
    sh[t] = tiles;
    __syncthreads();
    for (int d = 1; d < 64; d <<= 1) {
        int v = (t >= d) ? sh[t - d] : 0;
        __syncthreads();
        sh[t] += v;
        __syncthreads();
    }
    int tb = tileBase + sh[t] - tiles;
    int eb = tb * 64;
    gcur[l * 64 + t] = eb;
    for (int q = 0; q < tiles; ++q) tileOf[tb + q] = t;
    for (int idx = eb + cnt; idx < eb + tiles * 64; ++idx) pack[idx] = -1;
}

// ---------------------------------------------------------------------------
// Pre-pass 2b: per-level dst-CSR offsets from degi. One block per level.
// off gets n+1 entries; cur[j] initialized to off[j] for the pos scatter.
// ---------------------------------------------------------------------------
__global__ __launch_bounds__(1024) void csr_scan_all(const int* __restrict__ degi,
                                                     int* __restrict__ off,
                                                     int* __restrict__ cur) {
    const int Nv[4] = {16384, 4096, 1024, 256};
    const int DOFv[4] = {0, 16384, 20480, 21504};
    const int OFFv[4] = {0, 16385, 20482, 21507};
    int l = blockIdx.x;
    int n = Nv[l];
    const int* d = degi + DOFv[l];
    int* o = off + OFFv[l];
    int* c = cur + DOFv[l];
    __shared__ int ls[1024];
    int t = threadIdx.x;
    int per = (n + 1023) >> 10;
    int beg = t * per;
    int end = (beg + per < n) ? beg + per : n;
    int s = 0;
    for (int j = beg; j < end; ++j) s += d[j];
    ls[t] = s;
    __syncthreads();
    for (int dd = 1; dd < 1024; dd <<= 1) {
        int v = (t >= dd) ? ls[t - dd] : 0;
        __syncthreads();
        ls[t] += v;
        __syncthreads();
    }
    int base = (t == 0) ? 0 : ls[t - 1];
    for (int j = beg; j < end; ++j) {
        o[j] = base;
        c[j] = base;
        base += d[j];
    }
    if (t == 1023) o[n] = ls[1023];
}

// ---------------------------------------------------------------------------
// Pre-pass 3: block-local counting sort of edges by cube bucket.
// ---------------------------------------------------------------------------
__global__ __launch_bounds__(256) void scatter_all(
    const float* __restrict__ p0, const float* __restrict__ p1,
    const float* __restrict__ p2, const float* __restrict__ p3,
    int* __restrict__ gcur, int* __restrict__ pack) {
    int b = blockIdx.x;
    int l, lb, E;
    const float* ps;
    if (b < 128)      { l = 0; lb = b;       ps = p0; E = 131072; }
    else if (b < 160) { l = 1; lb = b - 128; ps = p1; E = 32768; }
    else if (b < 168) { l = 2; lb = b - 160; ps = p2; E = 8192; }
    else              { l = 3; lb = b - 168; ps = p3; E = 2048; }
    int* gc = gcur + l * 64;
    __shared__ int h[64], lbk[64], gb[64], sh[64];
    __shared__ int sp[1024];
    __shared__ unsigned char skk[1024];
    int t = threadIdx.x;
    int ebase = lb * 1024;
    int kbv[4];
    if (t < 64) h[t] = 0;
    __syncthreads();
#pragma unroll
    for (int j = 0; j < 4; ++j) {
        int e = ebase + j * 256 + t;
        if (e < E) {
            kbv[j] = edge_bucket(ps, e);
            atomicAdd(&h[kbv[j]], 1);
        } else
            kbv[j] = -1;
    }
    __syncthreads();
    if (t < 64) sh[t] = h[t];
    __syncthreads();
    for (int d = 1; d < 64; d <<= 1) {
        int v = (t < 64 && t >= d) ? sh[t - d] : 0;
        __syncthreads();
        if (t < 64) sh[t] += v;
        __syncthreads();
    }
    if (t < 64) {
        int c = h[t];
        lbk[t] = sh[t] - c;
        gb[t] = c ? atomicAdd(&gc[t], c) : 0;
        h[t] = 0;
    }
    __syncthreads();
#pragma unroll
    for (int j = 0; j < 4; ++j) {
        int e = ebase + j * 256 + t;
        if (kbv[j] >= 0) {
            int pos = lbk[kbv[j]] + atomicAdd(&h[kbv[j]], 1);
            sp[pos] = e;
            skk[pos] = (unsigned char)kbv[j];
        }
    }
    __syncthreads();
    int Pb = E - ebase;
    if (Pb > 1024) Pb = 1024;
    for (int j = t; j < Pb; j += 256) {
        int k = skk[j];
        pack[gb[k] + (j - lbk[k])] = sp[j];
    }
}

// ---------------------------------------------------------------------------
// Pre-pass 4: pos[e] = slot of edge e within its dst's CSR run.
// ---------------------------------------------------------------------------
__global__ __launch_bounds__(256) void pos_all(
    const int* __restrict__ d0, const int* __restrict__ d1,
    const int* __restrict__ d2, const int* __restrict__ d3,
    int* __restrict__ cur, int* __restrict__ posArr) {
    int b = blockIdx.x;
    int lb, E, dof, eof_;
    const int* ds;
    if (b < 512)      { lb = b;       ds = d0; E = 131072; dof = 0;     eof_ = 0; }
    else if (b < 640) { lb = b - 512; ds = d1; E = 32768;  dof = 16384; eof_ = 131072; }
    else if (b < 672) { lb = b - 640; ds = d2; E = 8192;   dof = 20480; eof_ = 163840; }
    else              { lb = b - 672; ds = d3; E = 2048;   dof = 21504; eof_ = 172032; }
    int e = lb * 256 + threadIdx.x;
    if (e < E) posArr[eof_ + e] = atomicAdd(&cur[dof + ds[e]], 1);
}

// ---------------------------------------------------------------------------
// Fused conv1 (in_c = 1): writes per-edge row to y[pos[e]] (no atomics).
// ---------------------------------------------------------------------------
__global__ __launch_bounds__(256) void conv1_y(const float* __restrict__ x,
                                               const int* __restrict__ src,
                                               const float* __restrict__ pseudo,
                                               const int* __restrict__ pos,
                                               const float* __restrict__ W,
                                               float* __restrict__ y, int E) {
    const int lane = threadIdx.x & 63;
    const int wid = threadIdx.x >> 6;
    const int sub = lane >> 5;
    const int o = lane & 31;
    int e = (blockIdx.x * 4 + wid) * 2 + sub;
    if (e >= E) return;
    float bs[8];
    int ks[8];
    edge_basis(pseudo, e, bs, ks);
    float acc = 0.f;
#pragma unroll
    for (int s = 0; s < 8; ++s) acc = fmaf(bs[s], W[ks[s] * 32 + o], acc);
    y[(size_t)pos[e] * 32 + o] = acc * x[src[e]];
}

// ---------------------------------------------------------------------------
// Cube GEMV v5 — R10's register-batched pipeline, atomics replaced by plain
// stores into the dst-CSR-ordered y buffer (y[pos[e]] row per edge).
// ---------------------------------------------------------------------------
template <int IN_C, int OUT_C>
__global__ __launch_bounds__(256) void gemv_cube_v5(
    const float* __restrict__ x, const int* __restrict__ src,
    const float* __restrict__ pseudo, const int* __restrict__ pack,
    const int* __restrict__ tileOf, const int* __restrict__ pos,
    const float* __restrict__ W, float* __restrict__ y, int tileBase) {
    constexpr int G = OUT_C / 4;    // lanes per sub-group
    constexpr int SG = 64 / G;      // sub-groups per wave
    constexpr int EPW = 2 * SG;     // edges per wave
    constexpr int EPB = 4 * EPW;    // edges per block
    constexpr int BPT = 64 / EPB;   // blocks per tile (1 or 2)
    constexpr int XSTR = IN_C + 4;  // padded x stride
    __shared__ float xs[EPB * XSTR];
    const int tid = threadIdx.x;
    const int wv = tid >> 6, lane = tid & 63;
    const int sg = lane / G, og = lane % G;
    int t = tileBase + blockIdx.x / BPT;
    int kb = tileOf[t];
    if (kb < 0) return;  // pad tile (uniform exit)
    kb = __builtin_amdgcn_readfirstlane(kb);
    const int kbase = (kb & 3) + 5 * ((kb >> 2) & 3) + 25 * ((kb >> 4) & 3);
    const int eL0 = wv * EPW + sg * 2;
    const int eL1 = eL0 + 1;
    const int gbase = t * 64 + (blockIdx.x % BPT) * EPB;
    int e0 = pack[gbase + eL0];
    int e1 = pack[gbase + eL1];
    float bs0[8], bs1[8];
    int p0 = -1, p1 = -1;
    float4 xq0 = make_float4(0.f, 0.f, 0.f, 0.f);
    float4 xq1 = make_float4(0.f, 0.f, 0.f, 0.f);
    if (e0 >= 0) {
        edge_fracs(pseudo, e0, bs0);
        p0 = pos[e0];
        if (og * 4 < IN_C) xq0 = *(const float4*)(x + (size_t)src[e0] * IN_C + og * 4);
    } else {
#pragma unroll
        for (int s = 0; s < 8; ++s) bs0[s] = 0.f;
    }
    if (e1 >= 0) {
        edge_fracs(pseudo, e1, bs1);
        p1 = pos[e1];
        if (og * 4 < IN_C) xq1 = *(const float4*)(x + (size_t)src[e1] * IN_C + og * 4);
    } else {
#pragma unroll
        for (int s = 0; s < 8; ++s) bs1[s] = 0.f;
    }
    // stage both x rows (wave-synchronous: same-wave LDS ops are in order)
    if (og * 4 < IN_C) {
        *(float4*)&xs[eL0 * XSTR + og * 4] = xq0;
        *(float4*)&xs[eL1 * XSTR + og * 4] = xq1;
    }
    constexpr int CUBE = IN_C * OUT_C;
    const float* __restrict__ Wb = W + (size_t)kbase * CUBE;
    const float* __restrict__ xr0 = &xs[eL0 * XSTR];
    const float* __restrict__ xr1 = &xs[eL1 * XSTR];
    float4 acc0 = make_float4(0.f, 0.f, 0.f, 0.f);
    float4 acc1 = make_float4(0.f, 0.f, 0.f, 0.f);
#pragma unroll 1
    for (int i = 0; i < IN_C; i += 2) {
        float2 xa = *(const float2*)&xr0[i];
        float2 xb = *(const float2*)&xr1[i];
        float4 wreg[16];
#pragma unroll
        for (int s = 0; s < 8; ++s) {
            const int soff = ((s & 1) + 5 * ((s >> 1) & 1) + 25 * ((s >> 2) & 1)) * CUBE;
            const float4* __restrict__ Wc = (const float4*)(Wb + soff + i * OUT_C) + og;
            wreg[2 * s] = Wc[0];
            wreg[2 * s + 1] = Wc[G];
        }
        __builtin_amdgcn_sched_barrier(0);  // pin: all 16 loads in flight before fmas
#pragma unroll
        for (int s = 0; s < 8; ++s) {
            acc0 = f4fma(bs0[s] * xa.x, wreg[2 * s], acc0);
            acc0 = f4fma(bs0[s] * xa.y, wreg[2 * s + 1], acc0);
            acc1 = f4fma(bs1[s] * xb.x, wreg[2 * s], acc1);
            acc1 = f4fma(bs1[s] * xb.y, wreg[2 * s + 1], acc1);
        }
    }
    if (p0 >= 0) *(float4*)(y + (size_t)p0 * OUT_C + og * 4) = acc0;
    if (p1 >= 0) *(float4*)(y + (size_t)p1 * OUT_C + og * 4) = acc1;
}

// ---------------------------------------------------------------------------
// Finalize (gather): out = (sum of this dst's CSR run of y)/deg + x@R + B,
// ELU. Rows for dst j are contiguous [off[j], off[j+1]) -> coalesced reads.
// ---------------------------------------------------------------------------
template <int IN_C, int OUT_C>
__global__ __launch_bounds__(256) void fin_gather_k(
    const float* __restrict__ xin, const float* __restrict__ R,
    const float* __restrict__ B, const int* __restrict__ off,
    const float* __restrict__ y, float* __restrict__ out, int n) {
    const int lane = threadIdx.x & 63;
    const int wid = threadIdx.x >> 6;
    constexpr int EPW = 64 / OUT_C;
    const int sub = (EPW == 2) ? (lane >> 5) : 0;
    const int o = lane & (OUT_C - 1);
    int j = (blockIdx.x * (blockDim.x >> 6) + wid) * EPW + sub;
    if (j >= n) return;
    float xv = (o < IN_C) ? xin[j * IN_C + o] : 0.f;
    float acc = B[o];
#pragma unroll 4
    for (int i = 0; i < IN_C; ++i) {
        float xi = __shfl(xv, i, OUT_C);
        acc = fmaf(xi, R[i * OUT_C + o], acc);
    }
    int b0 = off[j], b1 = off[j + 1];
    float s = 0.f;
    for (int r = b0; r < b1; ++r) s += y[(size_t)r * OUT_C + o];
    float d = fmaxf((float)(b1 - b0), 1.f);
    float v = s / d + acc;
    out[j * OUT_C + o] = (v > 0.f) ? v : expm1f(v);
}

// Same + fused max-pool scatter (level-ending conv).
template <int IN_C, int OUT_C>
__global__ __launch_bounds__(256) void fin_gather_pool_k(
    const float* __restrict__ xin, const float* __restrict__ R,
    const float* __restrict__ B, const int* __restrict__ off,
    const float* __restrict__ y, const int* __restrict__ cluster,
    unsigned* __restrict__ pool, float* __restrict__ out, int n) {
    constexpr int LOGC = (OUT_C == 32) ? 5 : 6;
    const int lane = threadIdx.x & 63;
    const int wid = threadIdx.x >> 6;
    constexpr int EPW = 64 / OUT_C;
    const int sub = (EPW == 2) ? (lane >> 5) : 0;
    const int o = lane & (OUT_C - 1);
    int j = (blockIdx.x * (blockDim.x >> 6) + wid) * EPW + sub;
    if (j >= n) return;
    float xv = (o < IN_C) ? xin[j * IN_C + o] : 0.f;
    float acc = B[o];
#pragma unroll 4
    for (int i = 0; i < IN_C; ++i) {
        float xi = __shfl(xv, i, OUT_C);
        acc = fmaf(xi, R[i * OUT_C + o], acc);
    }
    int b0 = off[j], b1 = off[j + 1];
    float s = 0.f;
    for (int r = b0; r < b1; ++r) s += y[(size_t)r * OUT_C + o];
    float d = fmaxf((float)(b1 - b0), 1.f);
    float v = s / d + acc;
    v = (v > 0.f) ? v : expm1f(v);
    out[j * OUT_C + o] = v;
    atomicMax(&pool[(cluster[j] << LOGC) + o], enc_f(v));
}

// ---------------------------------------------------------------------------
// Fallback kernels (small-ws path only): edge-centric conv w/ atomics.
// ---------------------------------------------------------------------------
__global__ __launch_bounds__(256) void conv1_fused(const float* __restrict__ x,
                                                   const int* __restrict__ src,
                                                   const int* __restrict__ dst,
                                                   const float* __restrict__ pseudo,
                                                   const float* __restrict__ W,
                                                   float* __restrict__ out, int E) {
    const int lane = threadIdx.x & 63;
    const int wid = threadIdx.x >> 6;
    const int sub = lane >> 5;
    const int o = lane & 31;
    int e = (blockIdx.x * 4 + wid) * 2 + sub;
    if (e >= E) return;
    float bs[8];
    int ks[8];
    edge_basis(pseudo, e, bs, ks);
    float acc = 0.f;
#pragma unroll
    for (int s = 0; s < 8; ++s) acc = fmaf(bs[s], W[ks[s] * 32 + o], acc);
    atomicAdd(&out[(size_t)dst[e] * 32 + o], acc * x[src[e]]);
}

template <int IN_C, int OUT_C>
__global__ __launch_bounds__(256) void conv_edges_inline(
    const float* __restrict__ x, const int* __restrict__ src,
    const int* __restrict__ dst, const float* __restrict__ pseudo,
    const float* __restrict__ W, float* __restrict__ out, int E) {
    const int lane = threadIdx.x & 63;
    const int wid = threadIdx.x >> 6;
    constexpr int EPW = 64 / OUT_C;
    const int sub = (EPW == 2) ? (lane >> 5) : 0;
    const int o = lane & (OUT_C - 1);
    long e = (long)(blockIdx.x * (blockDim.x >> 6) + wid) * EPW + sub;
    if (e >= E) return;
    float bs[8];
    int ks[8];
    edge_basis(pseudo, e, bs, ks);
    const int s_ = src[e];
    const int d_ = dst[e];
    float xv = (o < IN_C) ? x[s_ * IN_C + o] : 0.f;
    float acc = 0.f;
#pragma unroll
    for (int s = 0; s < 8; ++s) {
        const float b = bs[s];
        const float* Wk = W + (long)ks[s] * IN_C * OUT_C;
#pragma unroll 4
        for (int i = 0; i < IN_C; ++i) {
            float xi = __shfl(xv, i, OUT_C);
            acc = fmaf(b * xi, Wk[i * OUT_C + o], acc);
        }
    }
    atomicAdd(&out[(long)d_ * OUT_C + o], acc);
}

__global__ void deg_kernel(const int* __restrict__ dst, float* __restrict__ deg, int E) {
    int e = blockIdx.x * blockDim.x + threadIdx.x;
    if (e >= E) return;
    atomicAdd(&deg[dst[e]], 1.0f);
}

template <int IN_C, int OUT_C>
__global__ __launch_bounds__(256) void finalize_k(
    const float* __restrict__ xin, const float* __restrict__ R,
    const float* __restrict__ B, const float* __restrict__ deg,
    float* __restrict__ out, int n) {
    const int lane = threadIdx.x & 63;
    const int wid = threadIdx.x >> 6;
    constexpr int EPW = 64 / OUT_C;
    const int sub = (EPW == 2) ? (lane >> 5) : 0;
    const int o = lane & (OUT_C - 1);
    int j = (blockIdx.x * (blockDim.x >> 6) + wid) * EPW + sub;
    if (j >= n) return;
    float xv = (o < IN_C) ? xin[j * IN_C + o] : 0.f;
    float acc = B[o];
#pragma unroll 4
    for (int i = 0; i < IN_C; ++i) {
        float xi = __shfl(xv, i, OUT_C);
        acc = fmaf(xi, R[i * OUT_C + o], acc);
    }
    float d = fmaxf(deg[j], 1.f);
    float v = out[j * OUT_C + o] / d + acc;
    out[j * OUT_C + o] = (v > 0.f) ? v : expm1f(v);
}

__global__ void pool_scatter(const float* __restrict__ h, const int* __restrict__ cluster,
                             unsigned* __restrict__ pool, int n, int logC) {
    int idx = blockIdx.x * blockDim.x + threadIdx.x;
    if (idx >= (n << logC)) return;
    int j = idx >> logC;
    int c = idx & ((1 << logC) - 1);
    atomicMax(&pool[(cluster[j] << logC) + c], enc_f(h[idx]));
}

__global__ void pool_decode(const unsigned* __restrict__ pool, float* __restrict__ out, int total) {
    int idx = blockIdx.x * blockDim.x + threadIdx.x;
    if (idx >= total) return;
    unsigned u = pool[idx];
    int b = (u & 0x80000000u) ? (int)(u & 0x7FFFFFFFu) : (int)(~u);
    out[idx] = __int_as_float(b);
}

// ---------------------------------------------------------------------------
// Head: mean(64x64) -> fc1 -> fc2 -> log_softmax
// ---------------------------------------------------------------------------
__global__ void head_kernel(const float* __restrict__ h, const float* __restrict__ fc1w,
                            const float* __restrict__ fc1b, const float* __restrict__ fc2w,
                            const float* __restrict__ fc2b, float* __restrict__ out) {
    __shared__ float m[64], t[64], u[10];
    int lane = threadIdx.x;
    float s = 0.f;
    for (int j = 0; j < 64; ++j) s += h[j * 64 + lane];
    m[lane] = s * (1.f / 64.f);
    __syncthreads();
    float a = fc1b[lane];
    for (int i = 0; i < 64; ++i) a = fmaf(m[i], fc1w[i * 64 + lane], a);
    t[lane] = a;
    __syncthreads();
    if (lane < 10) {
        float b = fc2b[lane];
        for (int i = 0; i < 64; ++i) b = fmaf(t[i], fc2w[i * 10 + lane], b);
        u[lane] = b;
    }
    __syncthreads();
    if (lane < 10) {
        float mx = u[0];
        for (int i = 1; i < 10; ++i) mx = fmaxf(mx, u[i]);
        float se = 0.f;
        for (int i = 0; i < 10; ++i) se += expf(u[i] - mx);
        out[lane] = u[lane] - mx - logf(se);
    }
}

// ---------------------------------------------------------------------------
// Host side
// ---------------------------------------------------------------------------
static inline int cdiv(int a, int b) { return (a + b - 1) / b; }

extern "C" void kernel_launch(void* const* d_in, const int* in_sizes, int n_in,
                              void* d_out, int out_size, void* d_ws, size_t ws_size,
                              hipStream_t stream) {
    const float* x = (const float*)d_in[0];
    const int* src[4] = {(const int*)d_in[1], (const int*)d_in[5], (const int*)d_in[9], (const int*)d_in[13]};
    const int* dst[4] = {(const int*)d_in[2], (const int*)d_in[6], (const int*)d_in[10], (const int*)d_in[14]};
    const float* pseudo[4] = {(const float*)d_in[3], (const float*)d_in[7], (const float*)d_in[11], (const float*)d_in[15]};
    const int* cluster[4] = {(const int*)d_in[4], (const int*)d_in[8], (const int*)d_in[12], (const int*)d_in[16]};
    const float* Wp[8], *Rp[8], *Bp[8];
    for (int l = 0; l < 8; ++l) {
        Wp[l] = (const float*)d_in[17 + 3 * l];
        Rp[l] = (const float*)d_in[18 + 3 * l];
        Bp[l] = (const float*)d_in[19 + 3 * l];
    }
    const float* fc1w = (const float*)d_in[41];
    const float* fc1b = (const float*)d_in[42];
    const float* fc2w = (const float*)d_in[43];
    const float* fc2b = (const float*)d_in[44];
    float* outp = (float*)d_out;

    const int NS[5] = {16384, 4096, 1024, 256, 64};
    const int ES[4] = {16384 * 8, 4096 * 8, 1024 * 8, 256 * 8};
    const int MT[4] = {2048 + 64, 512 + 64, 128 + 64, 32 + 64};
    const int TB_[4] = {0, 2112, 2112 + 576, 2112 + 576 + 192};
    const int TOT_TILES = 2112 + 576 + 192 + 96;  // 2976
    const int DOF[4] = {0, 16384, 20480, 21504};
    const int DTOT = 21760;
    const int OFF2[4] = {0, 16385, 20482, 21507};
    const int OFFTOT = 21764;
    const int EBASE[4] = {0, 131072, 163840, 172032};
    const int ETOT = 174080;

    char* w = (char*)d_ws;
    auto take = [&](size_t bytes) -> char* {
        char* r = w;
        w += (bytes + 255) & ~(size_t)255;
        return r;
    };
    float* bufA = (float*)take((size_t)NS[0] * 64 * 4);
    float* bufB = (float*)take((size_t)NS[0] * 64 * 4);
    unsigned* pool = (unsigned*)take((size_t)NS[1] * 64 * 4);
    int* hist = (int*)take((size_t)4 * 64 * 4);
    int* degi = (int*)take((size_t)DTOT * 4);
    size_t fallbackNeed = (size_t)(w - (char*)d_ws);
    int* gcur = (int*)take((size_t)4 * 64 * 4);
    int* tileOf = (int*)take((size_t)TOT_TILES * 4);
    int* pack = (int*)take((size_t)TOT_TILES * 64 * 4);
    int* csr = (int*)take((size_t)OFFTOT * 4);
    int* cur = (int*)take((size_t)DTOT * 4);
    int* posArr = (int*)take((size_t)ETOT * 4);
    float* y = (float*)take((size_t)ES[0] * 32 * 4);  // 16.8 MB (max conv row set)
    size_t need = (size_t)(w - (char*)d_ws);
    bool fast = ws_size >= need;

    const int TB = 256;

    if (fast) {
        // ---------- pre-pass: hist+deg, layouts, sorts, CSR (5 launches) ---
        hipMemsetAsync(hist, 0, (size_t)(4 * 64 + DTOT) * 4, stream);
        hipMemsetAsync(tileOf, 0xFF, (size_t)TOT_TILES * 4, stream);
        hist_deg_all<<<680, 256, 0, stream>>>(pseudo[0], pseudo[1], pseudo[2], pseudo[3],
                                              dst[0], dst[1], dst[2], dst[3], hist, degi);
        scan_pad_all<<<4, 64, 0, stream>>>(hist, gcur, tileOf, pack);
        csr_scan_all<<<4, 1024, 0, stream>>>(degi, csr, cur);
        scatter_all<<<170, 256, 0, stream>>>(pseudo[0], pseudo[1], pseudo[2], pseudo[3],
                                             gcur, pack);
        pos_all<<<680, 256, 0, stream>>>(dst[0], dst[1], dst[2], dst[3], cur, posArr);

        // ---------------- Level 0: conv1 (1->32), conv12 (32->32) ----------
        {
            int E = ES[0], n = NS[0];
            const int* off = csr + OFF2[0];
            const int* pos = posArr + EBASE[0];
            conv1_y<<<cdiv(E, 8), TB, 0, stream>>>(x, src[0], pseudo[0], pos, Wp[0], y, E);
            fin_gather_k<1, 32><<<cdiv(n, 8), TB, 0, stream>>>(x, Rp[0], Bp[0], off, y, bufA, n);
            hipMemsetAsync(pool, 0, (size_t)NS[1] * 32 * 4, stream);
            gemv_cube_v5<32, 32><<<MT[0], TB, 0, stream>>>(
                bufA, src[0], pseudo[0], pack, tileOf, pos, Wp[1], y, TB_[0]);
            fin_gather_pool_k<32, 32><<<cdiv(n, 8), TB, 0, stream>>>(
                bufA, Rp[1], Bp[1], off, y, cluster[0], pool, bufB, n);
            pool_decode<<<cdiv(NS[1] * 32, TB), TB, 0, stream>>>(pool, bufA, NS[1] * 32);
        }
        // ---------------- Level 1: conv2 (32->64), conv3 (64->64) ----------
        {
            int n = NS[1];
            const int* off = csr + OFF2[1];
            const int* pos = posArr + EBASE[1];
            gemv_cube_v5<32, 64><<<MT[1] * 2, TB, 0, stream>>>(
                bufA, src[1], pseudo[1], pack, tileOf, pos, Wp[2], y, TB_[1]);
            fin_gather_k<32, 64><<<cdiv(n, 4), TB, 0, stream>>>(bufA, Rp[2], Bp[2], off, y, bufB, n);
            hipMemsetAsync(pool, 0, (size_t)NS[2] * 64 * 4, stream);
            gemv_cube_v5<64, 64><<<MT[1] * 2, TB, 0, stream>>>(
                bufB, src[1], pseudo[1], pack, tileOf, pos, Wp[3], y, TB_[1]);
            fin_gather_pool_k<64, 64><<<cdiv(n, 4), TB, 0, stream>>>(
                bufB, Rp[3], Bp[3], off, y, cluster[1], pool, bufA, n);
            pool_decode<<<cdiv(NS[2] * 64, TB), TB, 0, stream>>>(pool, bufB, NS[2] * 64);
        }
        // ---------------- Level 2: conv4, conv5 (64->64) -------------------
        {
            int n = NS[2];
            const int* off = csr + OFF2[2];
            const int* pos = posArr + EBASE[2];
            gemv_cube_v5<64, 64><<<MT[2] * 2, TB, 0, stream>>>(
                bufB, src[2], pseudo[2], pack, tileOf, pos, Wp[4], y, TB_[2]);
            fin_gather_k<64, 64><<<cdiv(n, 4), TB, 0, stream>>>(bufB, Rp[4], Bp[4], off, y, bufA, n);
            hipMemsetAsync(pool, 0, (size_t)NS[3] * 64 * 4, stream);
            gemv_cube_v5<64, 64><<<MT[2] * 2, TB, 0, stream>>>(
                bufA, src[2], pseudo[2], pack, tileOf, pos, Wp[5], y, TB_[2]);
            fin_gather_pool_k<64, 64><<<cdiv(n, 4), TB, 0, stream>>>(
                bufA, Rp[5], Bp[5], off, y, cluster[2], pool, bufB, n);
            pool_decode<<<cdiv(NS[3] * 64, TB), TB, 0, stream>>>(pool, bufA, NS[3] * 64);
        }
        // ---------------- Level 3: conv6, conv7 (64->64) -------------------
        {
            int n = NS[3];
            const int* off = csr + OFF2[3];
            const int* pos = posArr + EBASE[3];
            gemv_cube_v5<64, 64><<<MT[3] * 2, TB, 0, stream>>>(
                bufA, src[3], pseudo[3], pack, tileOf, pos, Wp[6], y, TB_[3]);
            fin_gather_k<64, 64><<<cdiv(n, 4), TB, 0, stream>>>(bufA, Rp[6], Bp[6], off, y, bufB, n);
            hipMemsetAsync(pool, 0, (size_t)NS[4] * 64 * 4, stream);
            gemv_cube_v5<64, 64><<<MT[3] * 2, TB, 0, stream>>>(
                bufB, src[3], pseudo[3], pack, tileOf, pos, Wp[7], y, TB_[3]);
            fin_gather_pool_k<64, 64><<<cdiv(n, 4), TB, 0, stream>>>(
                bufB, Rp[7], Bp[7], off, y, cluster[3], pool, bufA, n);
            pool_decode<<<cdiv(NS[4] * 64, TB), TB, 0, stream>>>(pool, bufB, NS[4] * 64);
        }
        head_kernel<<<1, 64, 0, stream>>>(bufB, fc1w, fc1b, fc2w, fc2b, outp);
    } else if (ws_size >= fallbackNeed) {
        // ---------------- legacy edge-centric fallback ---------------------
        float* h0 = bufA;
        float* h1 = bufB;
        float* deg = (float*)degi;
        for (int l = 0; l < 4; ++l) {
            int E = ES[l], n = NS[l];
            hipMemsetAsync(deg, 0, n * 4, stream);
            deg_kernel<<<cdiv(E, TB), TB, 0, stream>>>(dst[l], deg, E);
            for (int cc = 0; cc < 2; ++cc) {
                int li = (l == 0) ? cc : 2 * l + cc;
                if (l == 0 && cc == 0) {
                    hipMemsetAsync(h0, 0, (size_t)n * 32 * 4, stream);
                    conv1_fused<<<cdiv(E, 8), TB, 0, stream>>>(x, src[0], dst[0], pseudo[0], Wp[0], h0, E);
                    finalize_k<1, 32><<<cdiv(n, 8), TB, 0, stream>>>(x, Rp[0], Bp[0], deg, h0, n);
                } else {
                    int ic = (l == 0) ? 32 : ((l == 1 && cc == 0) ? 32 : 64);
                    int oc = (l == 0) ? 32 : 64;
                    hipMemsetAsync(h1, 0, (size_t)n * oc * 4, stream);
                    if (ic == 32 && oc == 32) {
                        conv_edges_inline<32, 32><<<cdiv(E, 8), TB, 0, stream>>>(h0, src[l], dst[l], pseudo[l], Wp[li], h1, E);
                        finalize_k<32, 32><<<cdiv(n, 8), TB, 0, stream>>>(h0, Rp[li], Bp[li], deg, h1, n);
                    } else if (ic == 32) {
                        conv_edges_inline<32, 64><<<cdiv(E, 4), TB, 0, stream>>>(h0, src[l], dst[l], pseudo[l], Wp[li], h1, E);
                        finalize_k<32, 64><<<cdiv(n, 4), TB, 0, stream>>>(h0, Rp[li], Bp[li], deg, h1, n);
                    } else {
                        conv_edges_inline<64, 64><<<cdiv(E, 4), TB, 0, stream>>>(h0, src[l], dst[l], pseudo[l], Wp[li], h1, E);
                        finalize_k<64, 64><<<cdiv(n, 4), TB, 0, stream>>>(h0, Rp[li], Bp[li], deg, h1, n);
                    }
                    float* tmp = h0; h0 = h1; h1 = tmp;
                }
            }
            int oc = (l == 0) ? 32 : 64;
            int logC = (l == 0) ? 5 : 6;
            hipMemsetAsync(pool, 0, (size_t)NS[l + 1] * oc * 4, stream);
            pool_scatter<<<cdiv(n * oc, TB), TB, 0, stream>>>(h0, cluster[l], pool, n, logC);
            pool_decode<<<cdiv(NS[l + 1] * oc, TB), TB, 0, stream>>>(pool, h1, NS[l + 1] * oc);
            float* tmp = h0; h0 = h1; h1 = tmp;
        }
        head_kernel<<<1, 64, 0, stream>>>(h0, fc1w, fc1b, fc2w, fc2b, outp);
    }
}

// Round 13
// 643.595 us; speedup vs baseline: 1.0356x; 1.0356x over previous
//
#include <hip/hip_runtime.h>
#include <hip/hip_bf16.h>

#define KS 5
#define K3 125

__device__ inline float4 f4fma(float a, float4 b, float4 c) {
    c.x = fmaf(a, b.x, c.x); c.y = fmaf(a, b.y, c.y);
    c.z = fmaf(a, b.z, c.z); c.w = fmaf(a, b.w, c.w);
    return c;
}

__device__ inline unsigned enc_f(float f) {
    int b = __float_as_int(f);
    return (b >= 0) ? ((unsigned)b | 0x80000000u) : ~((unsigned)b);
}

// ---------------------------------------------------------------------------
// Inline basis helpers
// ---------------------------------------------------------------------------
__device__ inline void edge_basis(const float* __restrict__ pseudo, int e,
                                  float* bs, int* ks) {
    float fr[3];
    int bot[3];
#pragma unroll
    for (int d = 0; d < 3; ++d) {
        float v = pseudo[e * 3 + d] * (float)(KS - 1);
        float fl = fminf(floorf(v), (float)(KS - 2));
        fr[d] = v - fl;
        bot[d] = (int)fl;
    }
    const int strides[3] = {1, KS, KS * KS};
#pragma unroll
    for (int s = 0; s < 8; ++s) {
        float b = 1.f;
        int w = 0;
#pragma unroll
        for (int d = 0; d < 3; ++d) {
            int bit = (s >> d) & 1;
            b *= bit ? fr[d] : (1.f - fr[d]);
            w += (bot[d] + bit) * strides[d];
        }
        bs[s] = b;
        ks[s] = w;
    }
}

__device__ inline void edge_fracs(const float* __restrict__ pseudo, int e, float* bs) {
    float fr[3];
#pragma unroll
    for (int d = 0; d < 3; ++d) {
        float v = pseudo[e * 3 + d] * (float)(KS - 1);
        float fl = fminf(floorf(v), (float)(KS - 2));
        fr[d] = v - fl;
    }
#pragma unroll
    for (int s = 0; s < 8; ++s) {
        float b = 1.f;
#pragma unroll
        for (int d = 0; d < 3; ++d) b *= ((s >> d) & 1) ? fr[d] : (1.f - fr[d]);
        bs[s] = b;
    }
}

__device__ inline int edge_bucket(const float* __restrict__ pseudo, int e) {
    int kb = 0;
#pragma unroll
    for (int d = 0; d < 3; ++d) {
        float v = pseudo[e * 3 + d] * (float)(KS - 1);
        int fl = (int)fminf(floorf(v), (float)(KS - 2));
        kb += fl << (2 * d);
    }
    return kb;
}

// ---------------------------------------------------------------------------
// Pre-pass 1 (all 4 levels): 64-bucket histogram + int degree.
// ---------------------------------------------------------------------------
__global__ __launch_bounds__(256) void hist_deg_all(
    const float* __restrict__ p0, const float* __restrict__ p1,
    const float* __restrict__ p2, const float* __restrict__ p3,
    const int* __restrict__ d0, const int* __restrict__ d1,
    const int* __restrict__ d2, const int* __restrict__ d3,
    int* __restrict__ hist, int* __restrict__ degi) {
    int b = blockIdx.x;
    int l, lb, E, dof;
    const float* ps;
    const int* ds;
    if (b < 512)      { l = 0; lb = b;       ps = p0; ds = d0; E = 131072; dof = 0; }
    else if (b < 640) { l = 1; lb = b - 512; ps = p1; ds = d1; E = 32768;  dof = 16384; }
    else if (b < 672) { l = 2; lb = b - 640; ps = p2; ds = d2; E = 8192;   dof = 20480; }
    else              { l = 3; lb = b - 672; ps = p3; ds = d3; E = 2048;   dof = 21504; }
    __shared__ int h[64];
    int t = threadIdx.x;
    if (t < 64) h[t] = 0;
    __syncthreads();
    int e = lb * 256 + t;
    if (e < E) {
        atomicAdd(&h[edge_bucket(ps, e)], 1);
        atomicAdd(&degi[dof + ds[e]], 1);
    }
    __syncthreads();
    if (t < 64 && h[t]) atomicAdd(&hist[l * 64 + t], h[t]);
}

// ---------------------------------------------------------------------------
// Pre-pass 2: bucket layout per level (blockIdx = level).
// ---------------------------------------------------------------------------
__global__ void scan_pad_all(const int* __restrict__ hist, int* __restrict__ gcur,
                             int* __restrict__ tileOf, int* __restrict__ pack) {
    const int TBv[4] = {0, 2112, 2112 + 576, 2112 + 576 + 192};
    int l = blockIdx.x;
    int tileBase = TBv[l];
    __shared__ int sh[64];
    int t = threadIdx.x;
    int cnt = hist[l * 64 + t];
    int tiles = (cnt + 63) >> 6;
    sh[t] = tiles;
    __syncthreads();
    for (int d = 1; d < 64; d <<= 1) {
        int v = (t >= d) ? sh[t - d] : 0;
        __syncthreads();
        sh[t] += v;
        __syncthreads();
    }
    int tb = tileBase + sh[t] - tiles;
    int eb = tb * 64;
    gcur[l * 64 + t] = eb;
    for (int q = 0; q < tiles; ++q) tileOf[tb + q] = t;
    for (int idx = eb + cnt; idx < eb + tiles * 64; ++idx) pack[idx] = -1;
}

// ---------------------------------------------------------------------------
// Pre-pass 2b: per-level dst-CSR offsets from degi. One block per level.
// ---------------------------------------------------------------------------
__global__ __launch_bounds__(1024) void csr_scan_all(const int* __restrict__ degi,
                                                     int* __restrict__ off,
                                                     int* __restrict__ cur) {
    const int Nv[4] = {16384, 4096, 1024, 256};
    const int DOFv[4] = {0, 16384, 20480, 21504};
    const int OFFv[4] = {0, 16385, 20482, 21507};
    int l = blockIdx.x;
    int n = Nv[l];
    const int* d = degi + DOFv[l];
    int* o = off + OFFv[l];
    int* c = cur + DOFv[l];
    __shared__ int ls[1024];
    int t = threadIdx.x;
    int per = (n + 1023) >> 10;
    int beg = t * per;
    int end = (beg + per < n) ? beg + per : n;
    int s = 0;
    for (int j = beg; j < end; ++j) s += d[j];
    ls[t] = s;
    __syncthreads();
    for (int dd = 1; dd < 1024; dd <<= 1) {
        int v = (t >= dd) ? ls[t - dd] : 0;
        __syncthreads();
        ls[t] += v;
        __syncthreads();
    }
    int base = (t == 0) ? 0 : ls[t - 1];
    for (int j = beg; j < end; ++j) {
        o[j] = base;
        c[j] = base;
        base += d[j];
    }
    if (t == 1023) o[n] = ls[1023];
}

// ---------------------------------------------------------------------------
// Pre-pass 3: block-local counting sort of edges by cube bucket.
// ---------------------------------------------------------------------------
__global__ __launch_bounds__(256) void scatter_all(
    const float* __restrict__ p0, const float* __restrict__ p1,
    const float* __restrict__ p2, const float* __restrict__ p3,
    int* __restrict__ gcur, int* __restrict__ pack) {
    int b = blockIdx.x;
    int l, lb, E;
    const float* ps;
    if (b < 128)      { l = 0; lb = b;       ps = p0; E = 131072; }
    else if (b < 160) { l = 1; lb = b - 128; ps = p1; E = 32768; }
    else if (b < 168) { l = 2; lb = b - 160; ps = p2; E = 8192; }
    else              { l = 3; lb = b - 168; ps = p3; E = 2048; }
    int* gc = gcur + l * 64;
    __shared__ int h[64], lbk[64], gb[64], sh[64];
    __shared__ int sp[1024];
    __shared__ unsigned char skk[1024];
    int t = threadIdx.x;
    int ebase = lb * 1024;
    int kbv[4];
    if (t < 64) h[t] = 0;
    __syncthreads();
#pragma unroll
    for (int j = 0; j < 4; ++j) {
        int e = ebase + j * 256 + t;
        if (e < E) {
            kbv[j] = edge_bucket(ps, e);
            atomicAdd(&h[kbv[j]], 1);
        } else
            kbv[j] = -1;
    }
    __syncthreads();
    if (t < 64) sh[t] = h[t];
    __syncthreads();
    for (int d = 1; d < 64; d <<= 1) {
        int v = (t < 64 && t >= d) ? sh[t - d] : 0;
        __syncthreads();
        if (t < 64) sh[t] += v;
        __syncthreads();
    }
    if (t < 64) {
        int c = h[t];
        lbk[t] = sh[t] - c;
        gb[t] = c ? atomicAdd(&gc[t], c) : 0;
        h[t] = 0;
    }
    __syncthreads();
#pragma unroll
    for (int j = 0; j < 4; ++j) {
        int e = ebase + j * 256 + t;
        if (kbv[j] >= 0) {
            int pos = lbk[kbv[j]] + atomicAdd(&h[kbv[j]], 1);
            sp[pos] = e;
            skk[pos] = (unsigned char)kbv[j];
        }
    }
    __syncthreads();
    int Pb = E - ebase;
    if (Pb > 1024) Pb = 1024;
    for (int j = t; j < Pb; j += 256) {
        int k = skk[j];
        pack[gb[k] + (j - lbk[k])] = sp[j];
    }
}

// ---------------------------------------------------------------------------
// Pre-pass 4: pos[e] = slot of edge e within its dst's CSR run.
// ---------------------------------------------------------------------------
__global__ __launch_bounds__(256) void pos_all(
    const int* __restrict__ d0, const int* __restrict__ d1,
    const int* __restrict__ d2, const int* __restrict__ d3,
    int* __restrict__ cur, int* __restrict__ posArr) {
    int b = blockIdx.x;
    int lb, E, dof, eof_;
    const int* ds;
    if (b < 512)      { lb = b;       ds = d0; E = 131072; dof = 0;     eof_ = 0; }
    else if (b < 640) { lb = b - 512; ds = d1; E = 32768;  dof = 16384; eof_ = 131072; }
    else if (b < 672) { lb = b - 640; ds = d2; E = 8192;   dof = 20480; eof_ = 163840; }
    else              { lb = b - 672; ds = d3; E = 2048;   dof = 21504; eof_ = 172032; }
    int e = lb * 256 + threadIdx.x;
    if (e < E) posArr[eof_ + e] = atomicAdd(&cur[dof + ds[e]], 1);
}

// ---------------------------------------------------------------------------
// Fused conv1 (in_c = 1): writes per-edge row to y[pos[e]] (no atomics).
// ---------------------------------------------------------------------------
__global__ __launch_bounds__(256) void conv1_y(const float* __restrict__ x,
                                               const int* __restrict__ src,
                                               const float* __restrict__ pseudo,
                                               const int* __restrict__ pos,
                                               const float* __restrict__ W,
                                               float* __restrict__ y, int E) {
    const int lane = threadIdx.x & 63;
    const int wid = threadIdx.x >> 6;
    const int sub = lane >> 5;
    const int o = lane & 31;
    int e = (blockIdx.x * 4 + wid) * 2 + sub;
    if (e >= E) return;
    float bs[8];
    int ks[8];
    edge_basis(pseudo, e, bs, ks);
    float acc = 0.f;
#pragma unroll
    for (int s = 0; s < 8; ++s) acc = fmaf(bs[s], W[ks[s] * 32 + o], acc);
    y[(size_t)pos[e] * 32 + o] = acc * x[src[e]];
}

// ---------------------------------------------------------------------------
// Cube GEMV v6 — v5 + __launch_bounds__(256, 4): caps occupancy at 4 waves/EU
// so the register allocator has a 128-VGPR budget and can keep all 16 W
// float4 loads in flight (R12's VGPR=32 showed the default budget forced
// load serialization). Plain stores into dst-CSR-ordered y.
// ---------------------------------------------------------------------------
template <int IN_C, int OUT_C>
__global__ __launch_bounds__(256, 4) void gemv_cube_v6(
    const float* __restrict__ x, const int* __restrict__ src,
    const float* __restrict__ pseudo, const int* __restrict__ pack,
    const int* __restrict__ tileOf, const int* __restrict__ pos,
    const float* __restrict__ W, float* __restrict__ y, int tileBase) {
    constexpr int G = OUT_C / 4;    // lanes per sub-group
    constexpr int SG = 64 / G;      // sub-groups per wave
    constexpr int EPW = 2 * SG;     // edges per wave
    constexpr int EPB = 4 * EPW;    // edges per block
    constexpr int BPT = 64 / EPB;   // blocks per tile (1 or 2)
    constexpr int XSTR = IN_C + 4;  // padded x stride
    __shared__ float xs[EPB * XSTR];
    const int tid = threadIdx.x;
    const int wv = tid >> 6, lane = tid & 63;
    const int sg = lane / G, og = lane % G;
    int t = tileBase + blockIdx.x / BPT;
    int kb = tileOf[t];
    if (kb < 0) return;  // pad tile (uniform exit)
    kb = __builtin_amdgcn_readfirstlane(kb);
    const int kbase = (kb & 3) + 5 * ((kb >> 2) & 3) + 25 * ((kb >> 4) & 3);
    const int eL0 = wv * EPW + sg * 2;
    const int eL1 = eL0 + 1;
    const int gbase = t * 64 + (blockIdx.x % BPT) * EPB;
    int e0 = pack[gbase + eL0];
    int e1 = pack[gbase + eL1];
    float bs0[8], bs1[8];
    int p0 = -1, p1 = -1;
    float4 xq0 = make_float4(0.f, 0.f, 0.f, 0.f);
    float4 xq1 = make_float4(0.f, 0.f, 0.f, 0.f);
    if (e0 >= 0) {
        edge_fracs(pseudo, e0, bs0);
        p0 = pos[e0];
        if (og * 4 < IN_C) xq0 = *(const float4*)(x + (size_t)src[e0] * IN_C + og * 4);
    } else {
#pragma unroll
        for (int s = 0; s < 8; ++s) bs0[s] = 0.f;
    }
    if (e1 >= 0) {
        edge_fracs(pseudo, e1, bs1);
        p1 = pos[e1];
        if (og * 4 < IN_C) xq1 = *(const float4*)(x + (size_t)src[e1] * IN_C + og * 4);
    } else {
#pragma unroll
        for (int s = 0; s < 8; ++s) bs1[s] = 0.f;
    }
    // stage both x rows (wave-synchronous: same-wave LDS ops are in order)
    if (og * 4 < IN_C) {
        *(float4*)&xs[eL0 * XSTR + og * 4] = xq0;
        *(float4*)&xs[eL1 * XSTR + og * 4] = xq1;
    }
    constexpr int CUBE = IN_C * OUT_C;
    const float* __restrict__ Wb = W + (size_t)kbase * CUBE;
    const float* __restrict__ xr0 = &xs[eL0 * XSTR];
    const float* __restrict__ xr1 = &xs[eL1 * XSTR];
    float4 acc0 = make_float4(0.f, 0.f, 0.f, 0.f);
    float4 acc1 = make_float4(0.f, 0.f, 0.f, 0.f);
#pragma unroll 1
    for (int i = 0; i < IN_C; i += 2) {
        float2 xa = *(const float2*)&xr0[i];
        float2 xb = *(const float2*)&xr1[i];
        float4 wreg[16];
#pragma unroll
        for (int s = 0; s < 8; ++s) {
            const int soff = ((s & 1) + 5 * ((s >> 1) & 1) + 25 * ((s >> 2) & 1)) * CUBE;
            const float4* __restrict__ Wc = (const float4*)(Wb + soff + i * OUT_C) + og;
            wreg[2 * s] = Wc[0];
            wreg[2 * s + 1] = Wc[G];
        }
        __builtin_amdgcn_sched_barrier(0);  // pin: all 16 loads in flight before fmas
#pragma unroll
        for (int s = 0; s < 8; ++s) {
            acc0 = f4fma(bs0[s] * xa.x, wreg[2 * s], acc0);
            acc0 = f4fma(bs0[s] * xa.y, wreg[2 * s + 1], acc0);
            acc1 = f4fma(bs1[s] * xb.x, wreg[2 * s], acc1);
            acc1 = f4fma(bs1[s] * xb.y, wreg[2 * s + 1], acc1);
        }
    }
    if (p0 >= 0) *(float4*)(y + (size_t)p0 * OUT_C + og * 4) = acc0;
    if (p1 >= 0) *(float4*)(y + (size_t)p1 * OUT_C + og * 4) = acc1;
}

// ---------------------------------------------------------------------------
// Finalize (gather): out = (sum of this dst's CSR run of y)/deg + x@R + B,
// ELU. 4-way unrolled reduction (4 independent loads in flight).
// ---------------------------------------------------------------------------
template <int IN_C, int OUT_C>
__device__ inline float csr_sum(const int* __restrict__ off,
                                const float* __restrict__ y, int j, int o,
                                float& dcount) {
    int b0 = off[j], b1 = off[j + 1];
    dcount = fmaxf((float)(b1 - b0), 1.f);
    float s0 = 0.f, s1 = 0.f, s2 = 0.f, s3 = 0.f;
    int r = b0;
    for (; r + 4 <= b1; r += 4) {
        s0 += y[(size_t)(r + 0) * OUT_C + o];
        s1 += y[(size_t)(r + 1) * OUT_C + o];
        s2 += y[(size_t)(r + 2) * OUT_C + o];
        s3 += y[(size_t)(r + 3) * OUT_C + o];
    }
    for (; r < b1; ++r) s0 += y[(size_t)r * OUT_C + o];
    return (s0 + s1) + (s2 + s3);
}

template <int IN_C, int OUT_C>
__global__ __launch_bounds__(256) void fin_gather_k(
    const float* __restrict__ xin, const float* __restrict__ R,
    const float* __restrict__ B, const int* __restrict__ off,
    const float* __restrict__ y, float* __restrict__ out, int n) {
    const int lane = threadIdx.x & 63;
    const int wid = threadIdx.x >> 6;
    constexpr int EPW = 64 / OUT_C;
    const int sub = (EPW == 2) ? (lane >> 5) : 0;
    const int o = lane & (OUT_C - 1);
    int j = (blockIdx.x * (blockDim.x >> 6) + wid) * EPW + sub;
    if (j >= n) return;
    float xv = (o < IN_C) ? xin[j * IN_C + o] : 0.f;
    float acc = B[o];
#pragma unroll 4
    for (int i = 0; i < IN_C; ++i) {
        float xi = __shfl(xv, i, OUT_C);
        acc = fmaf(xi, R[i * OUT_C + o], acc);
    }
    float d;
    float s = csr_sum<IN_C, OUT_C>(off, y, j, o, d);
    float v = s / d + acc;
    out[j * OUT_C + o] = (v > 0.f) ? v : expm1f(v);
}

// Same + fused max-pool scatter (level-ending conv).
template <int IN_C, int OUT_C>
__global__ __launch_bounds__(256) void fin_gather_pool_k(
    const float* __restrict__ xin, const float* __restrict__ R,
    const float* __restrict__ B, const int* __restrict__ off,
    const float* __restrict__ y, const int* __restrict__ cluster,
    unsigned* __restrict__ pool, float* __restrict__ out, int n) {
    constexpr int LOGC = (OUT_C == 32) ? 5 : 6;
    const int lane = threadIdx.x & 63;
    const int wid = threadIdx.x >> 6;
    constexpr int EPW = 64 / OUT_C;
    const int sub = (EPW == 2) ? (lane >> 5) : 0;
    const int o = lane & (OUT_C - 1);
    int j = (blockIdx.x * (blockDim.x >> 6) + wid) * EPW + sub;
    if (j >= n) return;
    float xv = (o < IN_C) ? xin[j * IN_C + o] : 0.f;
    float acc = B[o];
#pragma unroll 4
    for (int i = 0; i < IN_C; ++i) {
        float xi = __shfl(xv, i, OUT_C);
        acc = fmaf(xi, R[i * OUT_C + o], acc);
    }
    float d;
    float s = csr_sum<IN_C, OUT_C>(off, y, j, o, d);
    float v = s / d + acc;
    v = (v > 0.f) ? v : expm1f(v);
    out[j * OUT_C + o] = v;
    atomicMax(&pool[(cluster[j] << LOGC) + o], enc_f(v));
}

// ---------------------------------------------------------------------------
// Fallback kernels (small-ws path only): edge-centric conv w/ atomics.
// ---------------------------------------------------------------------------
__global__ __launch_bounds__(256) void conv1_fused(const float* __restrict__ x,
                                                   const int* __restrict__ src,
                                                   const int* __restrict__ dst,
                                                   const float* __restrict__ pseudo,
                                                   const float* __restrict__ W,
                                                   float* __restrict__ out, int E) {
    const int lane = threadIdx.x & 63;
    const int wid = threadIdx.x >> 6;
    const int sub = lane >> 5;
    const int o = lane & 31;
    int e = (blockIdx.x * 4 + wid) * 2 + sub;
    if (e >= E) return;
    float bs[8];
    int ks[8];
    edge_basis(pseudo, e, bs, ks);
    float acc = 0.f;
#pragma unroll
    for (int s = 0; s < 8; ++s) acc = fmaf(bs[s], W[ks[s] * 32 + o], acc);
    atomicAdd(&out[(size_t)dst[e] * 32 + o], acc * x[src[e]]);
}

template <int IN_C, int OUT_C>
__global__ __launch_bounds__(256) void conv_edges_inline(
    const float* __restrict__ x, const int* __restrict__ src,
    const int* __restrict__ dst, const float* __restrict__ pseudo,
    const float* __restrict__ W, float* __restrict__ out, int E) {
    const int lane = threadIdx.x & 63;
    const int wid = threadIdx.x >> 6;
    constexpr int EPW = 64 / OUT_C;
    const int sub = (EPW == 2) ? (lane >> 5) : 0;
    const int o = lane & (OUT_C - 1);
    long e = (long)(blockIdx.x * (blockDim.x >> 6) + wid) * EPW + sub;
    if (e >= E) return;
    float bs[8];
    int ks[8];
    edge_basis(pseudo, e, bs, ks);
    const int s_ = src[e];
    const int d_ = dst[e];
    float xv = (o < IN_C) ? x[s_ * IN_C + o] : 0.f;
    float acc = 0.f;
#pragma unroll
    for (int s = 0; s < 8; ++s) {
        const float b = bs[s];
        const float* Wk = W + (long)ks[s] * IN_C * OUT_C;
#pragma unroll 4
        for (int i = 0; i < IN_C; ++i) {
            float xi = __shfl(xv, i, OUT_C);
            acc = fmaf(b * xi, Wk[i * OUT_C + o], acc);
        }
    }
    atomicAdd(&out[(long)d_ * OUT_C + o], acc);
}

__global__ void deg_kernel(const int* __restrict__ dst, float* __restrict__ deg, int E) {
    int e = blockIdx.x * blockDim.x + threadIdx.x;
    if (e >= E) return;
    atomicAdd(&deg[dst[e]], 1.0f);
}

template <int IN_C, int OUT_C>
__global__ __launch_bounds__(256) void finalize_k(
    const float* __restrict__ xin, const float* __restrict__ R,
    const float* __restrict__ B, const float* __restrict__ deg,
    float* __restrict__ out, int n) {
    const int lane = threadIdx.x & 63;
    const int wid = threadIdx.x >> 6;
    constexpr int EPW = 64 / OUT_C;
    const int sub = (EPW == 2) ? (lane >> 5) : 0;
    const int o = lane & (OUT_C - 1);
    int j = (blockIdx.x * (blockDim.x >> 6) + wid) * EPW + sub;
    if (j >= n) return;
    float xv = (o < IN_C) ? xin[j * IN_C + o] : 0.f;
    float acc = B[o];
#pragma unroll 4
    for (int i = 0; i < IN_C; ++i) {
        float xi = __shfl(xv, i, OUT_C);
        acc = fmaf(xi, R[i * OUT_C + o], acc);
    }
    float d = fmaxf(deg[j], 1.f);
    float v = out[j * OUT_C + o] / d + acc;
    out[j * OUT_C + o] = (v > 0.f) ? v : expm1f(v);
}

__global__ void pool_scatter(const float* __restrict__ h, const int* __restrict__ cluster,
                             unsigned* __restrict__ pool, int n, int logC) {
    int idx = blockIdx.x * blockDim.x + threadIdx.x;
    if (idx >= (n << logC)) return;
    int j = idx >> logC;
    int c = idx & ((1 << logC) - 1);
    atomicMax(&pool[(cluster[j] << logC) + c], enc_f(h[idx]));
}

__global__ void pool_decode(const unsigned* __restrict__ pool, float* __restrict__ out, int total) {
    int idx = blockIdx.x * blockDim.x + threadIdx.x;
    if (idx >= total) return;
    unsigned u = pool[idx];
    int b = (u & 0x80000000u) ? (int)(u & 0x7FFFFFFFu) : (int)(~u);
    out[idx] = __int_as_float(b);
}

// ---------------------------------------------------------------------------
// Head: mean(64x64) -> fc1 -> fc2 -> log_softmax
// ---------------------------------------------------------------------------
__global__ void head_kernel(const float* __restrict__ h, const float* __restrict__ fc1w,
                            const float* __restrict__ fc1b, const float* __restrict__ fc2w,
                            const float* __restrict__ fc2b, float* __restrict__ out) {
    __shared__ float m[64], t[64], u[10];
    int lane = threadIdx.x;
    float s = 0.f;
    for (int j = 0; j < 64; ++j) s += h[j * 64 + lane];
    m[lane] = s * (1.f / 64.f);
    __syncthreads();
    float a = fc1b[lane];
    for (int i = 0; i < 64; ++i) a = fmaf(m[i], fc1w[i * 64 + lane], a);
    t[lane] = a;
    __syncthreads();
    if (lane < 10) {
        float b = fc2b[lane];
        for (int i = 0; i < 64; ++i) b = fmaf(t[i], fc2w[i * 10 + lane], b);
        u[lane] = b;
    }
    __syncthreads();
    if (lane < 10) {
        float mx = u[0];
        for (int i = 1; i < 10; ++i) mx = fmaxf(mx, u[i]);
        float se = 0.f;
        for (int i = 0; i < 10; ++i) se += expf(u[i] - mx);
        out[lane] = u[lane] - mx - logf(se);
    }
}

// ---------------------------------------------------------------------------
// Host side
// ---------------------------------------------------------------------------
static inline int cdiv(int a, int b) { return (a + b - 1) / b; }

extern "C" void kernel_launch(void* const* d_in, const int* in_sizes, int n_in,
                              void* d_out, int out_size, void* d_ws, size_t ws_size,
                              hipStream_t stream) {
    const float* x = (const float*)d_in[0];
    const int* src[4] = {(const int*)d_in[1], (const int*)d_in[5], (const int*)d_in[9], (const int*)d_in[13]};
    const int* dst[4] = {(const int*)d_in[2], (const int*)d_in[6], (const int*)d_in[10], (const int*)d_in[14]};
    const float* pseudo[4] = {(const float*)d_in[3], (const float*)d_in[7], (const float*)d_in[11], (const float*)d_in[15]};
    const int* cluster[4] = {(const int*)d_in[4], (const int*)d_in[8], (const int*)d_in[12], (const int*)d_in[16]};
    const float* Wp[8], *Rp[8], *Bp[8];
    for (int l = 0; l < 8; ++l) {
        Wp[l] = (const float*)d_in[17 + 3 * l];
        Rp[l] = (const float*)d_in[18 + 3 * l];
        Bp[l] = (const float*)d_in[19 + 3 * l];
    }
    const float* fc1w = (const float*)d_in[41];
    const float* fc1b = (const float*)d_in[42];
    const float* fc2w = (const float*)d_in[43];
    const float* fc2b = (const float*)d_in[44];
    float* outp = (float*)d_out;

    const int NS[5] = {16384, 4096, 1024, 256, 64};
    const int ES[4] = {16384 * 8, 4096 * 8, 1024 * 8, 256 * 8};
    const int MT[4] = {2048 + 64, 512 + 64, 128 + 64, 32 + 64};
    const int TB_[4] = {0, 2112, 2112 + 576, 2112 + 576 + 192};
    const int TOT_TILES = 2112 + 576 + 192 + 96;  // 2976
    const int DOF[4] = {0, 16384, 20480, 21504};
    const int DTOT = 21760;
    const int OFF2[4] = {0, 16385, 20482, 21507};
    const int OFFTOT = 21764;
    const int EBASE[4] = {0, 131072, 163840, 172032};
    const int ETOT = 174080;

    char* w = (char*)d_ws;
    auto take = [&](size_t bytes) -> char* {
        char* r = w;
        w += (bytes + 255) & ~(size_t)255;
        return r;
    };
    float* bufA = (float*)take((size_t)NS[0] * 64 * 4);
    float* bufB = (float*)take((size_t)NS[0] * 64 * 4);
    unsigned* pool = (unsigned*)take((size_t)NS[1] * 64 * 4);
    int* hist = (int*)take((size_t)4 * 64 * 4);
    int* degi = (int*)take((size_t)DTOT * 4);
    size_t fallbackNeed = (size_t)(w - (char*)d_ws);
    int* gcur = (int*)take((size_t)4 * 64 * 4);
    int* tileOf = (int*)take((size_t)TOT_TILES * 4);
    int* pack = (int*)take((size_t)TOT_TILES * 64 * 4);
    int* csr = (int*)take((size_t)OFFTOT * 4);
    int* cur = (int*)take((size_t)DTOT * 4);
    int* posArr = (int*)take((size_t)ETOT * 4);
    float* y = (float*)take((size_t)ES[0] * 32 * 4);  // 16.8 MB (max conv row set)
    size_t need = (size_t)(w - (char*)d_ws);
    bool fast = ws_size >= need;

    const int TB = 256;

    if (fast) {
        // ---------- pre-pass: hist+deg, layouts, sorts, CSR (5 launches) ---
        (void)hipMemsetAsync(hist, 0, (size_t)(4 * 64 + DTOT) * 4, stream);
        (void)hipMemsetAsync(tileOf, 0xFF, (size_t)TOT_TILES * 4, stream);
        hist_deg_all<<<680, 256, 0, stream>>>(pseudo[0], pseudo[1], pseudo[2], pseudo[3],
                                              dst[0], dst[1], dst[2], dst[3], hist, degi);
        scan_pad_all<<<4, 64, 0, stream>>>(hist, gcur, tileOf, pack);
        csr_scan_all<<<4, 1024, 0, stream>>>(degi, csr, cur);
        scatter_all<<<170, 256, 0, stream>>>(pseudo[0], pseudo[1], pseudo[2], pseudo[3],
                                             gcur, pack);
        pos_all<<<680, 256, 0, stream>>>(dst[0], dst[1], dst[2], dst[3], cur, posArr);

        // ---------------- Level 0: conv1 (1->32), conv12 (32->32) ----------
        {
            int E = ES[0], n = NS[0];
            const int* off = csr + OFF2[0];
            const int* pos = posArr + EBASE[0];
            conv1_y<<<cdiv(E, 8), TB, 0, stream>>>(x, src[0], pseudo[0], pos, Wp[0], y, E);
            fin_gather_k<1, 32><<<cdiv(n, 8), TB, 0, stream>>>(x, Rp[0], Bp[0], off, y, bufA, n);
            (void)hipMemsetAsync(pool, 0, (size_t)NS[1] * 32 * 4, stream);
            gemv_cube_v6<32, 32><<<MT[0], TB, 0, stream>>>(
                bufA, src[0], pseudo[0], pack, tileOf, pos, Wp[1], y, TB_[0]);
            fin_gather_pool_k<32, 32><<<cdiv(n, 8), TB, 0, stream>>>(
                bufA, Rp[1], Bp[1], off, y, cluster[0], pool, bufB, n);
            pool_decode<<<cdiv(NS[1] * 32, TB), TB, 0, stream>>>(pool, bufA, NS[1] * 32);
        }
        // ---------------- Level 1: conv2 (32->64), conv3 (64->64) ----------
        {
            int n = NS[1];
            const int* off = csr + OFF2[1];
            const int* pos = posArr + EBASE[1];
            gemv_cube_v6<32, 64><<<MT[1] * 2, TB, 0, stream>>>(
                bufA, src[1], pseudo[1], pack, tileOf, pos, Wp[2], y, TB_[1]);
            fin_gather_k<32, 64><<<cdiv(n, 4), TB, 0, stream>>>(bufA, Rp[2], Bp[2], off, y, bufB, n);
            (void)hipMemsetAsync(pool, 0, (size_t)NS[2] * 64 * 4, stream);
            gemv_cube_v6<64, 64><<<MT[1] * 2, TB, 0, stream>>>(
                bufB, src[1], pseudo[1], pack, tileOf, pos, Wp[3], y, TB_[1]);
            fin_gather_pool_k<64, 64><<<cdiv(n, 4), TB, 0, stream>>>(
                bufB, Rp[3], Bp[3], off, y, cluster[1], pool, bufA, n);
            pool_decode<<<cdiv(NS[2] * 64, TB), TB, 0, stream>>>(pool, bufB, NS[2] * 64);
        }
        // ---------------- Level 2: conv4, conv5 (64->64) -------------------
        {
            int n = NS[2];
            const int* off = csr + OFF2[2];
            const int* pos = posArr + EBASE[2];
            gemv_cube_v6<64, 64><<<MT[2] * 2, TB, 0, stream>>>(
                bufB, src[2], pseudo[2], pack, tileOf, pos, Wp[4], y, TB_[2]);
            fin_gather_k<64, 64><<<cdiv(n, 4), TB, 0, stream>>>(bufB, Rp[4], Bp[4], off, y, bufA, n);
            (void)hipMemsetAsync(pool, 0, (size_t)NS[3] * 64 * 4, stream);
            gemv_cube_v6<64, 64><<<MT[2] * 2, TB, 0, stream>>>(
                bufA, src[2], pseudo[2], pack, tileOf, pos, Wp[5], y, TB_[2]);
            fin_gather_pool_k<64, 64><<<cdiv(n, 4), TB, 0, stream>>>(
                bufA, Rp[5], Bp[5], off, y, cluster[2], pool, bufB, n);
            pool_decode<<<cdiv(NS[3] * 64, TB), TB, 0, stream>>>(pool, bufA, NS[3] * 64);
        }
        // ---------------- Level 3: conv6, conv7 (64->64) -------------------
        {
            int n = NS[3];
            const int* off = csr + OFF2[3];
            const int* pos = posArr + EBASE[3];
            gemv_cube_v6<64, 64><<<MT[3] * 2, TB, 0, stream>>>(
                bufA, src[3], pseudo[3], pack, tileOf, pos, Wp[6], y, TB_[3]);
            fin_gather_k<64, 64><<<cdiv(n, 4), TB, 0, stream>>>(bufA, Rp[6], Bp[6], off, y, bufB, n);
            (void)hipMemsetAsync(pool, 0, (size_t)NS[4] * 64 * 4, stream);
            gemv_cube_v6<64, 64><<<MT[3] * 2, TB, 0, stream>>>(
                bufB, src[3], pseudo[3], pack, tileOf, pos, Wp[7], y, TB_[3]);
            fin_gather_pool_k<64, 64><<<cdiv(n, 4), TB, 0, stream>>>(
                bufB, Rp[7], Bp[7], off, y, cluster[3], pool, bufA, n);
            pool_decode<<<cdiv(NS[4] * 64, TB), TB, 0, stream>>>(pool, bufB, NS[4] * 64);
        }
        head_kernel<<<1, 64, 0, stream>>>(bufB, fc1w, fc1b, fc2w, fc2b, outp);
    } else if (ws_size >= fallbackNeed) {
        // ---------------- legacy edge-centric fallback ---------------------
        float* h0 = bufA;
        float* h1 = bufB;
        float* deg = (float*)degi;
        for (int l = 0; l < 4; ++l) {
            int E = ES[l], n = NS[l];
            (void)hipMemsetAsync(deg, 0, n * 4, stream);
            deg_kernel<<<cdiv(E, TB), TB, 0, stream>>>(dst[l], deg, E);
            for (int cc = 0; cc < 2; ++cc) {
                int li = (l == 0) ? cc : 2 * l + cc;
                if (l == 0 && cc == 0) {
                    (void)hipMemsetAsync(h0, 0, (size_t)n * 32 * 4, stream);
                    conv1_fused<<<cdiv(E, 8), TB, 0, stream>>>(x, src[0], dst[0], pseudo[0], Wp[0], h0, E);
                    finalize_k<1, 32><<<cdiv(n, 8), TB, 0, stream>>>(x, Rp[0], Bp[0], deg, h0, n);
                } else {
                    int ic = (l == 0) ? 32 : ((l == 1 && cc == 0) ? 32 : 64);
                    int oc = (l == 0) ? 32 : 64;
                    (void)hipMemsetAsync(h1, 0, (size_t)n * oc * 4, stream);
                    if (ic == 32 && oc == 32) {
                        conv_edges_inline<32, 32><<<cdiv(E, 8), TB, 0, stream>>>(h0, src[l], dst[l], pseudo[l], Wp[li], h1, E);
                        finalize_k<32, 32><<<cdiv(n, 8), TB, 0, stream>>>(h0, Rp[li], Bp[li], deg, h1, n);
                    } else if (ic == 32) {
                        conv_edges_inline<32, 64><<<cdiv(E, 4), TB, 0, stream>>>(h0, src[l], dst[l], pseudo[l], Wp[li], h1, E);
                        finalize_k<32, 64><<<cdiv(n, 4), TB, 0, stream>>>(h0, Rp[li], Bp[li], deg, h1, n);
                    } else {
                        conv_edges_inline<64, 64><<<cdiv(E, 4), TB, 0, stream>>>(h0, src[l], dst[l], pseudo[l], Wp[li], h1, E);
                        finalize_k<64, 64><<<cdiv(n, 4), TB, 0, stream>>>(h0, Rp[li], Bp[li], deg, h1, n);
                    }
                    float* tmp = h0; h0 = h1; h1 = tmp;
                }
            }
            int oc = (l == 0) ? 32 : 64;
            int logC = (l == 0) ? 5 : 6;
            (void)hipMemsetAsync(pool, 0, (size_t)NS[l + 1] * oc * 4, stream);
            pool_scatter<<<cdiv(n * oc, TB), TB, 0, stream>>>(h0, cluster[l], pool, n, logC);
            pool_decode<<<cdiv(NS[l + 1] * oc, TB), TB, 0, stream>>>(pool, h1, NS[l + 1] * oc);
            float* tmp = h0; h0 = h1; h1 = tmp;
        }
        head_kernel<<<1, 64, 0, stream>>>(h0, fc1w, fc1b, fc2w, fc2b, outp);
    }
}

// Round 14
// 443.392 us; speedup vs baseline: 1.5032x; 1.4515x over previous
//
#include <hip/hip_runtime.h>
#include <hip/hip_bf16.h>

#define KS 5
#define K3 125

typedef __attribute__((ext_vector_type(8))) short short8;
typedef __attribute__((ext_vector_type(4))) float floatx4;

__device__ inline unsigned enc_f(float f) {
    int b = __float_as_int(f);
    return (b >= 0) ? ((unsigned)b | 0x80000000u) : ~((unsigned)b);
}

__device__ inline unsigned short f2bf(float f) {
    unsigned u = __float_as_uint(f);
    u += 0x7FFFu + ((u >> 16) & 1u);  // RNE
    return (unsigned short)(u >> 16);
}
__device__ inline unsigned pack2bf(float a, float b) {
    return (unsigned)f2bf(a) | ((unsigned)f2bf(b) << 16);
}

// ---------------------------------------------------------------------------
// Inline basis helpers
// ---------------------------------------------------------------------------
__device__ inline void edge_basis(const float* __restrict__ pseudo, int e,
                                  float* bs, int* ks) {
    float fr[3];
    int bot[3];
#pragma unroll
    for (int d = 0; d < 3; ++d) {
        float v = pseudo[e * 3 + d] * (float)(KS - 1);
        float fl = fminf(floorf(v), (float)(KS - 2));
        fr[d] = v - fl;
        bot[d] = (int)fl;
    }
    const int strides[3] = {1, KS, KS * KS};
#pragma unroll
    for (int s = 0; s < 8; ++s) {
        float b = 1.f;
        int w = 0;
#pragma unroll
        for (int d = 0; d < 3; ++d) {
            int bit = (s >> d) & 1;
            b *= bit ? fr[d] : (1.f - fr[d]);
            w += (bot[d] + bit) * strides[d];
        }
        bs[s] = b;
        ks[s] = w;
    }
}

__device__ inline void edge_fracs(const float* __restrict__ pseudo, int e, float* bs) {
    float fr[3];
#pragma unroll
    for (int d = 0; d < 3; ++d) {
        float v = pseudo[e * 3 + d] * (float)(KS - 1);
        float fl = fminf(floorf(v), (float)(KS - 2));
        fr[d] = v - fl;
    }
#pragma unroll
    for (int s = 0; s < 8; ++s) {
        float b = 1.f;
#pragma unroll
        for (int d = 0; d < 3; ++d) b *= ((s >> d) & 1) ? fr[d] : (1.f - fr[d]);
        bs[s] = b;
    }
}

__device__ inline int edge_bucket(const float* __restrict__ pseudo, int e) {
    int kb = 0;
#pragma unroll
    for (int d = 0; d < 3; ++d) {
        float v = pseudo[e * 3 + d] * (float)(KS - 1);
        int fl = (int)fminf(floorf(v), (float)(KS - 2));
        kb += fl << (2 * d);
    }
    return kb;
}

// ---------------------------------------------------------------------------
// Pre-pass 1: 64-bucket histogram + int degree (all levels).
// ---------------------------------------------------------------------------
__global__ __launch_bounds__(256) void hist_deg_all(
    const float* __restrict__ p0, const float* __restrict__ p1,
    const float* __restrict__ p2, const float* __restrict__ p3,
    const int* __restrict__ d0, const int* __restrict__ d1,
    const int* __restrict__ d2, const int* __restrict__ d3,
    int* __restrict__ hist, int* __restrict__ degi) {
    int b = blockIdx.x;
    int l, lb, E, dof;
    const float* ps;
    const int* ds;
    if (b < 512)      { l = 0; lb = b;       ps = p0; ds = d0; E = 131072; dof = 0; }
    else if (b < 640) { l = 1; lb = b - 512; ps = p1; ds = d1; E = 32768;  dof = 16384; }
    else if (b < 672) { l = 2; lb = b - 640; ps = p2; ds = d2; E = 8192;   dof = 20480; }
    else              { l = 3; lb = b - 672; ps = p3; ds = d3; E = 2048;   dof = 21504; }
    __shared__ int h[64];
    int t = threadIdx.x;
    if (t < 64) h[t] = 0;
    __syncthreads();
    int e = lb * 256 + t;
    if (e < E) {
        atomicAdd(&h[edge_bucket(ps, e)], 1);
        atomicAdd(&degi[dof + ds[e]], 1);
    }
    __syncthreads();
    if (t < 64 && h[t]) atomicAdd(&hist[l * 64 + t], h[t]);
}

// ---------------------------------------------------------------------------
// Pre-pass 2: bucket layout per level (blockIdx = level).
// ---------------------------------------------------------------------------
__global__ void scan_pad_all(const int* __restrict__ hist, int* __restrict__ gcur,
                             int* __restrict__ tileOf, int* __restrict__ pack) {
    const int TBv[4] = {0, 2112, 2112 + 576, 2112 + 576 + 192};
    int l = blockIdx.x;
    int tileBase = TBv[l];
    __shared__ int sh[64];
    int t = threadIdx.x;
    int cnt = hist[l * 64 + t];
    int tiles = (cnt + 63) >> 6;
    sh[t] = tiles;
    __syncthreads();
    for (int d = 1; d < 64; d <<= 1) {
        int v = (t >= d) ? sh[t - d] : 0;
        __syncthreads();
        sh[t] += v;
        __syncthreads();
    }
    int tb = tileBase + sh[t] - tiles;
    int eb = tb * 64;
    gcur[l * 64 + t] = eb;
    for (int q = 0; q < tiles; ++q) tileOf[tb + q] = t;
    for (int idx = eb + cnt; idx < eb + tiles * 64; ++idx) pack[idx] = -1;
}

// ---------------------------------------------------------------------------
// Pre-pass 2b: per-level dst-CSR offsets from degi.
// ---------------------------------------------------------------------------
__global__ __launch_bounds__(1024) void csr_scan_all(const int* __restrict__ degi,
                                                     int* __restrict__ off,
                                                     int* __restrict__ cur) {
    const int Nv[4] = {16384, 4096, 1024, 256};
    const int DOFv[4] = {0, 16384, 20480, 21504};
    const int OFFv[4] = {0, 16385, 20482, 21507};
    int l = blockIdx.x;
    int n = Nv[l];
    const int* d = degi + DOFv[l];
    int* o = off + OFFv[l];
    int* c = cur + DOFv[l];
    __shared__ int ls[1024];
    int t = threadIdx.x;
    int per = (n + 1023) >> 10;
    int beg = t * per;
    int end = (beg + per < n) ? beg + per : n;
    int s = 0;
    for (int j = beg; j < end; ++j) s += d[j];
    ls[t] = s;
    __syncthreads();
    for (int dd = 1; dd < 1024; dd <<= 1) {
        int v = (t >= dd) ? ls[t - dd] : 0;
        __syncthreads();
        ls[t] += v;
        __syncthreads();
    }
    int base = (t == 0) ? 0 : ls[t - 1];
    for (int j = beg; j < end; ++j) {
        o[j] = base;
        c[j] = base;
        base += d[j];
    }
    if (t == 1023) o[n] = ls[1023];
}

// ---------------------------------------------------------------------------
// Pre-pass 3: block-local counting sort of edges by cube bucket.
// ---------------------------------------------------------------------------
__global__ __launch_bounds__(256) void scatter_all(
    const float* __restrict__ p0, const float* __restrict__ p1,
    const float* __restrict__ p2, const float* __restrict__ p3,
    int* __restrict__ gcur, int* __restrict__ pack) {
    int b = blockIdx.x;
    int l, lb, E;
    const float* ps;
    if (b < 128)      { l = 0; lb = b;       ps = p0; E = 131072; }
    else if (b < 160) { l = 1; lb = b - 128; ps = p1; E = 32768; }
    else if (b < 168) { l = 2; lb = b - 160; ps = p2; E = 8192; }
    else              { l = 3; lb = b - 168; ps = p3; E = 2048; }
    int* gc = gcur + l * 64;
    __shared__ int h[64], lbk[64], gb[64], sh[64];
    __shared__ int sp[1024];
    __shared__ unsigned char skk[1024];
    int t = threadIdx.x;
    int ebase = lb * 1024;
    int kbv[4];
    if (t < 64) h[t] = 0;
    __syncthreads();
#pragma unroll
    for (int j = 0; j < 4; ++j) {
        int e = ebase + j * 256 + t;
        if (e < E) {
            kbv[j] = edge_bucket(ps, e);
            atomicAdd(&h[kbv[j]], 1);
        } else
            kbv[j] = -1;
    }
    __syncthreads();
    if (t < 64) sh[t] = h[t];
    __syncthreads();
    for (int d = 1; d < 64; d <<= 1) {
        int v = (t < 64 && t >= d) ? sh[t - d] : 0;
        __syncthreads();
        if (t < 64) sh[t] += v;
        __syncthreads();
    }
    if (t < 64) {
        int c = h[t];
        lbk[t] = sh[t] - c;
        gb[t] = c ? atomicAdd(&gc[t], c) : 0;
        h[t] = 0;
    }
    __syncthreads();
#pragma unroll
    for (int j = 0; j < 4; ++j) {
        int e = ebase + j * 256 + t;
        if (kbv[j] >= 0) {
            int pos = lbk[kbv[j]] + atomicAdd(&h[kbv[j]], 1);
            sp[pos] = e;
            skk[pos] = (unsigned char)kbv[j];
        }
    }
    __syncthreads();
    int Pb = E - ebase;
    if (Pb > 1024) Pb = 1024;
    for (int j = t; j < Pb; j += 256) {
        int k = skk[j];
        pack[gb[k] + (j - lbk[k])] = sp[j];
    }
}

// ---------------------------------------------------------------------------
// Pre-pass 4: pos[e] = slot of edge e within its dst's CSR run.
// ---------------------------------------------------------------------------
__global__ __launch_bounds__(256) void pos_all(
    const int* __restrict__ d0, const int* __restrict__ d1,
    const int* __restrict__ d2, const int* __restrict__ d3,
    int* __restrict__ cur, int* __restrict__ posArr) {
    int b = blockIdx.x;
    int lb, E, dof, eof_;
    const int* ds;
    if (b < 512)      { lb = b;       ds = d0; E = 131072; dof = 0;     eof_ = 0; }
    else if (b < 640) { lb = b - 512; ds = d1; E = 32768;  dof = 16384; eof_ = 131072; }
    else if (b < 672) { lb = b - 640; ds = d2; E = 8192;   dof = 20480; eof_ = 163840; }
    else              { lb = b - 672; ds = d3; E = 2048;   dof = 21504; eof_ = 172032; }
    int e = lb * 256 + threadIdx.x;
    if (e < E) posArr[eof_ + e] = atomicAdd(&cur[dof + ds[e]], 1);
}

// ---------------------------------------------------------------------------
// Pre-pass 5: convert W (fp32 [k][i][o]) -> Wt (bf16 [k][o][i]) for the 7
// MFMA-path layers. One element per thread.
// Layer table: L12(32,32) L2(32,64) L3..L7(64,64).
// ---------------------------------------------------------------------------
__global__ __launch_bounds__(256) void wcvt_all(
    const float* __restrict__ w12, const float* __restrict__ w2,
    const float* __restrict__ w3, const float* __restrict__ w4,
    const float* __restrict__ w5, const float* __restrict__ w6,
    const float* __restrict__ w7, short* __restrict__ Wt) {
    int idx = blockIdx.x * 256 + threadIdx.x;
    if (idx >= 2944000) return;
    const float* Wsrc;
    int IC, OC, local;
    if (idx < 128000)       { Wsrc = w12; IC = 32; OC = 32; local = idx; }
    else if (idx < 384000)  { Wsrc = w2;  IC = 32; OC = 64; local = idx - 128000; }
    else if (idx < 896000)  { Wsrc = w3;  IC = 64; OC = 64; local = idx - 384000; }
    else if (idx < 1408000) { Wsrc = w4;  IC = 64; OC = 64; local = idx - 896000; }
    else if (idx < 1920000) { Wsrc = w5;  IC = 64; OC = 64; local = idx - 1408000; }
    else if (idx < 2432000) { Wsrc = w6;  IC = 64; OC = 64; local = idx - 1920000; }
    else                    { Wsrc = w7;  IC = 64; OC = 64; local = idx - 2432000; }
    int per = IC * OC;
    int k = local / per;
    int r = local % per;
    int o = r / IC;
    int i = r % IC;
    Wt[idx] = (short)f2bf(Wsrc[(size_t)(k * IC + i) * OC + o]);
}

// ---------------------------------------------------------------------------
// Fused conv1 (in_c = 1): per-edge row to y[pos[e]] (fp32, no atomics).
// ---------------------------------------------------------------------------
__global__ __launch_bounds__(256) void conv1_y(const float* __restrict__ x,
                                               const int* __restrict__ src,
                                               const float* __restrict__ pseudo,
                                               const int* __restrict__ pos,
                                               const float* __restrict__ W,
                                               float* __restrict__ y, int E) {
    const int lane = threadIdx.x & 63;
    const int wid = threadIdx.x >> 6;
    const int sub = lane >> 5;
    const int o = lane & 31;
    int e = (blockIdx.x * 4 + wid) * 2 + sub;
    if (e >= E) return;
    float bs[8];
    int ks[8];
    edge_basis(pseudo, e, bs, ks);
    float acc = 0.f;
#pragma unroll
    for (int s = 0; s < 8; ++s) acc = fmaf(bs[s], W[ks[s] * 32 + o], acc);
    y[(size_t)pos[e] * 32 + o] = acc * x[src[e]];
}

// ---------------------------------------------------------------------------
// MFMA bucket-tile conv. One block (4 waves) per 64-edge bucket-uniform tile.
// C[64,OUT_C] = A[64, 8*IN_C] * B[8*IN_C, OUT_C], where
//   A[e][s*IN_C+i] = basis_s(e) * x[src_e][i]   (staged bf16 in LDS, +8 pad)
//   B = tile's 2x2x2 W cube from pre-transposed bf16 Wt[k][o][i].
// MFMA 16x16x32 bf16. Verified layouts: A[m=lane&15][k=quad*8+j];
// C/D col=lane&15, row=quad*4+reg; B mirrors A with n=lane&15.
// Wave w computes rows [16w,16w+16) x all OUT_C. Output -> y[pos[e]] fp32.
// ---------------------------------------------------------------------------
template <int IN_C, int OUT_C>
__global__ __launch_bounds__(256) void mfma_conv(
    const float* __restrict__ x, const int* __restrict__ src,
    const float* __restrict__ pseudo, const int* __restrict__ pack,
    const int* __restrict__ tileOf, const int* __restrict__ pos,
    const short* __restrict__ Wt, float* __restrict__ y, int tileBase) {
    constexpr int K = 8 * IN_C;
    constexpr int KP = K + 8;       // padded row (shorts); keeps 16B align
    constexpr int NT = OUT_C / 16;  // n-tiles per wave
    constexpr int IP = IN_C / 4;    // x elems per staging part
    __shared__ short As[64 * KP];
    __shared__ int posL[64];
    const int tid = threadIdx.x;
    int t = tileBase + blockIdx.x;
    int kb = tileOf[t];
    if (kb < 0) return;  // pad tile (uniform exit)
    kb = __builtin_amdgcn_readfirstlane(kb);
    const int kbase = (kb & 3) + 5 * ((kb >> 2) & 3) + 25 * ((kb >> 4) & 3);

    // ---- stage A (bf16, basis-scaled) + posL ----
    {
        const int eLoc = tid >> 2, part = tid & 3;
        int e = pack[t * 64 + eLoc];
        float bs[8];
        if (e >= 0) edge_fracs(pseudo, e, bs);
        else {
#pragma unroll
            for (int s = 0; s < 8; ++s) bs[s] = 0.f;
        }
        if (part == 0) posL[eLoc] = (e >= 0) ? pos[e] : -1;
        float4 xq[IP / 4];
#pragma unroll
        for (int g = 0; g < IP / 4; ++g)
            xq[g] = (e >= 0)
                        ? *(const float4*)(x + (size_t)src[e] * IN_C + part * IP + g * 4)
                        : make_float4(0.f, 0.f, 0.f, 0.f);
#pragma unroll
        for (int s = 0; s < 8; ++s) {
            const float b = bs[s];
            short* rowp = &As[eLoc * KP + s * IN_C + part * IP];
#pragma unroll
            for (int g = 0; g < IP / 4; ++g) {
                unsigned lo = pack2bf(b * xq[g].x, b * xq[g].y);
                unsigned hi = pack2bf(b * xq[g].z, b * xq[g].w);
                *(uint2*)(rowp + 4 * g) = make_uint2(lo, hi);
            }
        }
    }
    __syncthreads();

    // ---- MFMA main loop ----
    const int wave = tid >> 6, lane = tid & 63;
    const int quad = lane >> 4, lm = lane & 15;
    floatx4 acc[NT];
#pragma unroll
    for (int nt = 0; nt < NT; ++nt) acc[nt] = (floatx4){0.f, 0.f, 0.f, 0.f};
    const short* myrow = &As[(wave * 16 + lm) * KP];
#pragma unroll
    for (int kstep = 0; kstep < K / 32; ++kstep) {
        const int kg = kstep * 32;
        const int s = kg / IN_C;
        const int i0 = kg % IN_C;
        const int ks = kbase + (s & 1) + 5 * ((s >> 1) & 1) + 25 * ((s >> 2) & 1);
        short8 a = *(const short8*)&myrow[kg + quad * 8];
#pragma unroll
        for (int nt = 0; nt < NT; ++nt) {
            const short* bp =
                Wt + ((size_t)ks * OUT_C + nt * 16 + lm) * IN_C + i0 + quad * 8;
            short8 bfr = *(const short8*)bp;
            acc[nt] = __builtin_amdgcn_mfma_f32_16x16x32_bf16(a, bfr, acc[nt], 0, 0, 0);
        }
    }
    // ---- epilogue: C row = edge (quad*4+reg), col = o (lane&15) ----
#pragma unroll
    for (int nt = 0; nt < NT; ++nt) {
#pragma unroll
        for (int r = 0; r < 4; ++r) {
            int row = wave * 16 + quad * 4 + r;
            int p = posL[row];
            if (p >= 0) y[(size_t)p * OUT_C + nt * 16 + lm] = acc[nt][r];
        }
    }
}

// ---------------------------------------------------------------------------
// Finalize (gather): out = (sum of dst's CSR run of y)/deg + x@R + B, ELU.
// ---------------------------------------------------------------------------
template <int IN_C, int OUT_C>
__device__ inline float csr_sum(const int* __restrict__ off,
                                const float* __restrict__ y, int j, int o,
                                float& dcount) {
    int b0 = off[j], b1 = off[j + 1];
    dcount = fmaxf((float)(b1 - b0), 1.f);
    float s0 = 0.f, s1 = 0.f, s2 = 0.f, s3 = 0.f;
    int r = b0;
    for (; r + 4 <= b1; r += 4) {
        s0 += y[(size_t)(r + 0) * OUT_C + o];
        s1 += y[(size_t)(r + 1) * OUT_C + o];
        s2 += y[(size_t)(r + 2) * OUT_C + o];
        s3 += y[(size_t)(r + 3) * OUT_C + o];
    }
    for (; r < b1; ++r) s0 += y[(size_t)r * OUT_C + o];
    return (s0 + s1) + (s2 + s3);
}

template <int IN_C, int OUT_C>
__global__ __launch_bounds__(256) void fin_gather_k(
    const float* __restrict__ xin, const float* __restrict__ R,
    const float* __restrict__ B, const int* __restrict__ off,
    const float* __restrict__ y, float* __restrict__ out, int n) {
    const int lane = threadIdx.x & 63;
    const int wid = threadIdx.x >> 6;
    constexpr int EPW = 64 / OUT_C;
    const int sub = (EPW == 2) ? (lane >> 5) : 0;
    const int o = lane & (OUT_C - 1);
    int j = (blockIdx.x * (blockDim.x >> 6) + wid) * EPW + sub;
    if (j >= n) return;
    float xv = (o < IN_C) ? xin[j * IN_C + o] : 0.f;
    float acc = B[o];
#pragma unroll 4
    for (int i = 0; i < IN_C; ++i) {
        float xi = __shfl(xv, i, OUT_C);
        acc = fmaf(xi, R[i * OUT_C + o], acc);
    }
    float d;
    float s = csr_sum<IN_C, OUT_C>(off, y, j, o, d);
    float v = s / d + acc;
    out[j * OUT_C + o] = (v > 0.f) ? v : expm1f(v);
}

template <int IN_C, int OUT_C>
__global__ __launch_bounds__(256) void fin_gather_pool_k(
    const float* __restrict__ xin, const float* __restrict__ R,
    const float* __restrict__ B, const int* __restrict__ off,
    const float* __restrict__ y, const int* __restrict__ cluster,
    unsigned* __restrict__ pool, float* __restrict__ out, int n) {
    constexpr int LOGC = (OUT_C == 32) ? 5 : 6;
    const int lane = threadIdx.x & 63;
    const int wid = threadIdx.x >> 6;
    constexpr int EPW = 64 / OUT_C;
    const int sub = (EPW == 2) ? (lane >> 5) : 0;
    const int o = lane & (OUT_C - 1);
    int j = (blockIdx.x * (blockDim.x >> 6) + wid) * EPW + sub;
    if (j >= n) return;
    float xv = (o < IN_C) ? xin[j * IN_C + o] : 0.f;
    float acc = B[o];
#pragma unroll 4
    for (int i = 0; i < IN_C; ++i) {
        float xi = __shfl(xv, i, OUT_C);
        acc = fmaf(xi, R[i * OUT_C + o], acc);
    }
    float d;
    float s = csr_sum<IN_C, OUT_C>(off, y, j, o, d);
    float v = s / d + acc;
    v = (v > 0.f) ? v : expm1f(v);
    out[j * OUT_C + o] = v;
    atomicMax(&pool[(cluster[j] << LOGC) + o], enc_f(v));
}

// ---------------------------------------------------------------------------
// Fallback kernels (small-ws path only).
// ---------------------------------------------------------------------------
__global__ __launch_bounds__(256) void conv1_fused(const float* __restrict__ x,
                                                   const int* __restrict__ src,
                                                   const int* __restrict__ dst,
                                                   const float* __restrict__ pseudo,
                                                   const float* __restrict__ W,
                                                   float* __restrict__ out, int E) {
    const int lane = threadIdx.x & 63;
    const int wid = threadIdx.x >> 6;
    const int sub = lane >> 5;
    const int o = lane & 31;
    int e = (blockIdx.x * 4 + wid) * 2 + sub;
    if (e >= E) return;
    float bs[8];
    int ks[8];
    edge_basis(pseudo, e, bs, ks);
    float acc = 0.f;
#pragma unroll
    for (int s = 0; s < 8; ++s) acc = fmaf(bs[s], W[ks[s] * 32 + o], acc);
    atomicAdd(&out[(size_t)dst[e] * 32 + o], acc * x[src[e]]);
}

template <int IN_C, int OUT_C>
__global__ __launch_bounds__(256) void conv_edges_inline(
    const float* __restrict__ x, const int* __restrict__ src,
    const int* __restrict__ dst, const float* __restrict__ pseudo,
    const float* __restrict__ W, float* __restrict__ out, int E) {
    const int lane = threadIdx.x & 63;
    const int wid = threadIdx.x >> 6;
    constexpr int EPW = 64 / OUT_C;
    const int sub = (EPW == 2) ? (lane >> 5) : 0;
    const int o = lane & (OUT_C - 1);
    long e = (long)(blockIdx.x * (blockDim.x >> 6) + wid) * EPW + sub;
    if (e >= E) return;
    float bs[8];
    int ks[8];
    edge_basis(pseudo, e, bs, ks);
    const int s_ = src[e];
    const int d_ = dst[e];
    float xv = (o < IN_C) ? x[s_ * IN_C + o] : 0.f;
    float acc = 0.f;
#pragma unroll
    for (int s = 0; s < 8; ++s) {
        const float b = bs[s];
        const float* Wk = W + (long)ks[s] * IN_C * OUT_C;
#pragma unroll 4
        for (int i = 0; i < IN_C; ++i) {
            float xi = __shfl(xv, i, OUT_C);
            acc = fmaf(b * xi, Wk[i * OUT_C + o], acc);
        }
    }
    atomicAdd(&out[(long)d_ * OUT_C + o], acc);
}

__global__ void deg_kernel(const int* __restrict__ dst, float* __restrict__ deg, int E) {
    int e = blockIdx.x * blockDim.x + threadIdx.x;
    if (e >= E) return;
    atomicAdd(&deg[dst[e]], 1.0f);
}

template <int IN_C, int OUT_C>
__global__ __launch_bounds__(256) void finalize_k(
    const float* __restrict__ xin, const float* __restrict__ R,
    const float* __restrict__ B, const float* __restrict__ deg,
    float* __restrict__ out, int n) {
    const int lane = threadIdx.x & 63;
    const int wid = threadIdx.x >> 6;
    constexpr int EPW = 64 / OUT_C;
    const int sub = (EPW == 2) ? (lane >> 5) : 0;
    const int o = lane & (OUT_C - 1);
    int j = (blockIdx.x * (blockDim.x >> 6) + wid) * EPW + sub;
    if (j >= n) return;
    float xv = (o < IN_C) ? xin[j * IN_C + o] : 0.f;
    float acc = B[o];
#pragma unroll 4
    for (int i = 0; i < IN_C; ++i) {
        float xi = __shfl(xv, i, OUT_C);
        acc = fmaf(xi, R[i * OUT_C + o], acc);
    }
    float d = fmaxf(deg[j], 1.f);
    float v = out[j * OUT_C + o] / d + acc;
    out[j * OUT_C + o] = (v > 0.f) ? v : expm1f(v);
}

__global__ void pool_scatter(const float* __restrict__ h, const int* __restrict__ cluster,
                             unsigned* __restrict__ pool, int n, int logC) {
    int idx = blockIdx.x * blockDim.x + threadIdx.x;
    if (idx >= (n << logC)) return;
    int j = idx >> logC;
    int c = idx & ((1 << logC) - 1);
    atomicMax(&pool[(cluster[j] << logC) + c], enc_f(h[idx]));
}

__global__ void pool_decode(const unsigned* __restrict__ pool, float* __restrict__ out, int total) {
    int idx = blockIdx.x * blockDim.x + threadIdx.x;
    if (idx >= total) return;
    unsigned u = pool[idx];
    int b = (u & 0x80000000u) ? (int)(u & 0x7FFFFFFFu) : (int)(~u);
    out[idx] = __int_as_float(b);
}

// ---------------------------------------------------------------------------
// Head: mean(64x64) -> fc1 -> fc2 -> log_softmax
// ---------------------------------------------------------------------------
__global__ void head_kernel(const float* __restrict__ h, const float* __restrict__ fc1w,
                            const float* __restrict__ fc1b, const float* __restrict__ fc2w,
                            const float* __restrict__ fc2b, float* __restrict__ out) {
    __shared__ float m[64], t[64], u[10];
    int lane = threadIdx.x;
    float s = 0.f;
    for (int j = 0; j < 64; ++j) s += h[j * 64 + lane];
    m[lane] = s * (1.f / 64.f);
    __syncthreads();
    float a = fc1b[lane];
    for (int i = 0; i < 64; ++i) a = fmaf(m[i], fc1w[i * 64 + lane], a);
    t[lane] = a;
    __syncthreads();
    if (lane < 10) {
        float b = fc2b[lane];
        for (int i = 0; i < 64; ++i) b = fmaf(t[i], fc2w[i * 10 + lane], b);
        u[lane] = b;
    }
    __syncthreads();
    if (lane < 10) {
        float mx = u[0];
        for (int i = 1; i < 10; ++i) mx = fmaxf(mx, u[i]);
        float se = 0.f;
        for (int i = 0; i < 10; ++i) se += expf(u[i] - mx);
        out[lane] = u[lane] - mx - logf(se);
    }
}

// ---------------------------------------------------------------------------
// Host side
// ---------------------------------------------------------------------------
static inline int cdiv(int a, int b) { return (a + b - 1) / b; }

extern "C" void kernel_launch(void* const* d_in, const int* in_sizes, int n_in,
                              void* d_out, int out_size, void* d_ws, size_t ws_size,
                              hipStream_t stream) {
    const float* x = (const float*)d_in[0];
    const int* src[4] = {(const int*)d_in[1], (const int*)d_in[5], (const int*)d_in[9], (const int*)d_in[13]};
    const int* dst[4] = {(const int*)d_in[2], (const int*)d_in[6], (const int*)d_in[10], (const int*)d_in[14]};
    const float* pseudo[4] = {(const float*)d_in[3], (const float*)d_in[7], (const float*)d_in[11], (const float*)d_in[15]};
    const int* cluster[4] = {(const int*)d_in[4], (const int*)d_in[8], (const int*)d_in[12], (const int*)d_in[16]};
    const float* Wp[8], *Rp[8], *Bp[8];
    for (int l = 0; l < 8; ++l) {
        Wp[l] = (const float*)d_in[17 + 3 * l];
        Rp[l] = (const float*)d_in[18 + 3 * l];
        Bp[l] = (const float*)d_in[19 + 3 * l];
    }
    const float* fc1w = (const float*)d_in[41];
    const float* fc1b = (const float*)d_in[42];
    const float* fc2w = (const float*)d_in[43];
    const float* fc2b = (const float*)d_in[44];
    float* outp = (float*)d_out;

    const int NS[5] = {16384, 4096, 1024, 256, 64};
    const int ES[4] = {16384 * 8, 4096 * 8, 1024 * 8, 256 * 8};
    const int MT[4] = {2048 + 64, 512 + 64, 128 + 64, 32 + 64};
    const int TB_[4] = {0, 2112, 2112 + 576, 2112 + 576 + 192};
    const int TOT_TILES = 2112 + 576 + 192 + 96;  // 2976
    const int DTOT = 21760;
    const int OFF2[4] = {0, 16385, 20482, 21507};
    const int OFFTOT = 21764;
    const int EBASE[4] = {0, 131072, 163840, 172032};
    const int ETOT = 174080;
    // Wt bf16 layout offsets (shorts): L12, L2, L3..L7
    const int WT_OFF[7] = {0, 128000, 384000, 896000, 1408000, 1920000, 2432000};
    const int WT_TOT = 2944000;

    char* w = (char*)d_ws;
    auto take = [&](size_t bytes) -> char* {
        char* r = w;
        w += (bytes + 255) & ~(size_t)255;
        return r;
    };
    float* bufA = (float*)take((size_t)NS[0] * 64 * 4);
    float* bufB = (float*)take((size_t)NS[0] * 64 * 4);
    unsigned* pool = (unsigned*)take((size_t)NS[1] * 64 * 4);
    int* hist = (int*)take((size_t)4 * 64 * 4);
    int* degi = (int*)take((size_t)DTOT * 4);
    size_t fallbackNeed = (size_t)(w - (char*)d_ws);
    int* gcur = (int*)take((size_t)4 * 64 * 4);
    int* tileOf = (int*)take((size_t)TOT_TILES * 4);
    int* pack = (int*)take((size_t)TOT_TILES * 64 * 4);
    int* csr = (int*)take((size_t)OFFTOT * 4);
    int* cur = (int*)take((size_t)DTOT * 4);
    int* posArr = (int*)take((size_t)ETOT * 4);
    short* Wtb = (short*)take((size_t)WT_TOT * 2);      // 5.9 MB bf16 weights
    float* y = (float*)take((size_t)ES[0] * 32 * 4);    // 16.8 MB edge rows
    size_t need = (size_t)(w - (char*)d_ws);
    bool fast = ws_size >= need;

    const int TB = 256;

    if (fast) {
        // ---------- pre-pass: hist+deg, layouts, sorts, CSR, Wt ------------
        (void)hipMemsetAsync(hist, 0, (size_t)(4 * 64 + DTOT) * 4, stream);
        (void)hipMemsetAsync(tileOf, 0xFF, (size_t)TOT_TILES * 4, stream);
        hist_deg_all<<<680, 256, 0, stream>>>(pseudo[0], pseudo[1], pseudo[2], pseudo[3],
                                              dst[0], dst[1], dst[2], dst[3], hist, degi);
        wcvt_all<<<cdiv(WT_TOT, 256), 256, 0, stream>>>(Wp[1], Wp[2], Wp[3], Wp[4],
                                                        Wp[5], Wp[6], Wp[7], Wtb);
        scan_pad_all<<<4, 64, 0, stream>>>(hist, gcur, tileOf, pack);
        csr_scan_all<<<4, 1024, 0, stream>>>(degi, csr, cur);
        scatter_all<<<170, 256, 0, stream>>>(pseudo[0], pseudo[1], pseudo[2], pseudo[3],
                                             gcur, pack);
        pos_all<<<680, 256, 0, stream>>>(dst[0], dst[1], dst[2], dst[3], cur, posArr);

        // ---------------- Level 0: conv1 (1->32), conv12 (32->32) ----------
        {
            int E = ES[0], n = NS[0];
            const int* off = csr + OFF2[0];
            const int* pos = posArr + EBASE[0];
            conv1_y<<<cdiv(E, 8), TB, 0, stream>>>(x, src[0], pseudo[0], pos, Wp[0], y, E);
            fin_gather_k<1, 32><<<cdiv(n, 8), TB, 0, stream>>>(x, Rp[0], Bp[0], off, y, bufA, n);
            (void)hipMemsetAsync(pool, 0, (size_t)NS[1] * 32 * 4, stream);
            mfma_conv<32, 32><<<MT[0], TB, 0, stream>>>(
                bufA, src[0], pseudo[0], pack, tileOf, pos, Wtb + WT_OFF[0], y, TB_[0]);
            fin_gather_pool_k<32, 32><<<cdiv(n, 8), TB, 0, stream>>>(
                bufA, Rp[1], Bp[1], off, y, cluster[0], pool, bufB, n);
            pool_decode<<<cdiv(NS[1] * 32, TB), TB, 0, stream>>>(pool, bufA, NS[1] * 32);
        }
        // ---------------- Level 1: conv2 (32->64), conv3 (64->64) ----------
        {
            int n = NS[1];
            const int* off = csr + OFF2[1];
            const int* pos = posArr + EBASE[1];
            mfma_conv<32, 64><<<MT[1], TB, 0, stream>>>(
                bufA, src[1], pseudo[1], pack, tileOf, pos, Wtb + WT_OFF[1], y, TB_[1]);
            fin_gather_k<32, 64><<<cdiv(n, 4), TB, 0, stream>>>(bufA, Rp[2], Bp[2], off, y, bufB, n);
            (void)hipMemsetAsync(pool, 0, (size_t)NS[2] * 64 * 4, stream);
            mfma_conv<64, 64><<<MT[1], TB, 0, stream>>>(
                bufB, src[1], pseudo[1], pack, tileOf, pos, Wtb + WT_OFF[2], y, TB_[1]);
            fin_gather_pool_k<64, 64><<<cdiv(n, 4), TB, 0, stream>>>(
                bufB, Rp[3], Bp[3], off, y, cluster[1], pool, bufA, n);
            pool_decode<<<cdiv(NS[2] * 64, TB), TB, 0, stream>>>(pool, bufB, NS[2] * 64);
        }
        // ---------------- Level 2: conv4, conv5 (64->64) -------------------
        {
            int n = NS[2];
            const int* off = csr + OFF2[2];
            const int* pos = posArr + EBASE[2];
            mfma_conv<64, 64><<<MT[2], TB, 0, stream>>>(
                bufB, src[2], pseudo[2], pack, tileOf, pos, Wtb + WT_OFF[3], y, TB_[2]);
            fin_gather_k<64, 64><<<cdiv(n, 4), TB, 0, stream>>>(bufB, Rp[4], Bp[4], off, y, bufA, n);
            (void)hipMemsetAsync(pool, 0, (size_t)NS[3] * 64 * 4, stream);
            mfma_conv<64, 64><<<MT[2], TB, 0, stream>>>(
                bufA, src[2], pseudo[2], pack, tileOf, pos, Wtb + WT_OFF[4], y, TB_[2]);
            fin_gather_pool_k<64, 64><<<cdiv(n, 4), TB, 0, stream>>>(
                bufA, Rp[5], Bp[5], off, y, cluster[2], pool, bufB, n);
            pool_decode<<<cdiv(NS[3] * 64, TB), TB, 0, stream>>>(pool, bufA, NS[3] * 64);
        }
        // ---------------- Level 3: conv6, conv7 (64->64) -------------------
        {
            int n = NS[3];
            const int* off = csr + OFF2[3];
            const int* pos = posArr + EBASE[3];
            mfma_conv<64, 64><<<MT[3], TB, 0, stream>>>(
                bufA, src[3], pseudo[3], pack, tileOf, pos, Wtb + WT_OFF[5], y, TB_[3]);
            fin_gather_k<64, 64><<<cdiv(n, 4), TB, 0, stream>>>(bufA, Rp[6], Bp[6], off, y, bufB, n);
            (void)hipMemsetAsync(pool, 0, (size_t)NS[4] * 64 * 4, stream);
            mfma_conv<64, 64><<<MT[3], TB, 0, stream>>>(
                bufB, src[3], pseudo[3], pack, tileOf, pos, Wtb + WT_OFF[6], y, TB_[3]);
            fin_gather_pool_k<64, 64><<<cdiv(n, 4), TB, 0, stream>>>(
                bufB, Rp[7], Bp[7], off, y, cluster[3], pool, bufA, n);
            pool_decode<<<cdiv(NS[4] * 64, TB), TB, 0, stream>>>(pool, bufB, NS[4] * 64);
        }
        head_kernel<<<1, 64, 0, stream>>>(bufB, fc1w, fc1b, fc2w, fc2b, outp);
    } else if (ws_size >= fallbackNeed) {
        // ---------------- legacy edge-centric fallback ---------------------
        float* h0 = bufA;
        float* h1 = bufB;
        float* deg = (float*)degi;
        for (int l = 0; l < 4; ++l) {
            int E = ES[l], n = NS[l];
            (void)hipMemsetAsync(deg, 0, n * 4, stream);
            deg_kernel<<<cdiv(E, TB), TB, 0, stream>>>(dst[l], deg, E);
            for (int cc = 0; cc < 2; ++cc) {
                int li = (l == 0) ? cc : 2 * l + cc;
                if (l == 0 && cc == 0) {
                    (void)hipMemsetAsync(h0, 0, (size_t)n * 32 * 4, stream);
                    conv1_fused<<<cdiv(E, 8), TB, 0, stream>>>(x, src[0], dst[0], pseudo[0], Wp[0], h0, E);
                    finalize_k<1, 32><<<cdiv(n, 8), TB, 0, stream>>>(x, Rp[0], Bp[0], deg, h0, n);
                } else {
                    int ic = (l == 0) ? 32 : ((l == 1 && cc == 0) ? 32 : 64);
                    int oc = (l == 0) ? 32 : 64;
                    (void)hipMemsetAsync(h1, 0, (size_t)n * oc * 4, stream);
                    if (ic == 32 && oc == 32) {
                        conv_edges_inline<32, 32><<<cdiv(E, 8), TB, 0, stream>>>(h0, src[l], dst[l], pseudo[l], Wp[li], h1, E);
                        finalize_k<32, 32><<<cdiv(n, 8), TB, 0, stream>>>(h0, Rp[li], Bp[li], deg, h1, n);
                    } else if (ic == 32) {
                        conv_edges_inline<32, 64><<<cdiv(E, 4), TB, 0, stream>>>(h0, src[l], dst[l], pseudo[l], Wp[li], h1, E);
                        finalize_k<32, 64><<<cdiv(n, 4), TB, 0, stream>>>(h0, Rp[li], Bp[li], deg, h1, n);
                    } else {
                        conv_edges_inline<64, 64><<<cdiv(E, 4), TB, 0, stream>>>(h0, src[l], dst[l], pseudo[l], Wp[li], h1, E);
                        finalize_k<64, 64><<<cdiv(n, 4), TB, 0, stream>>>(h0, Rp[li], Bp[li], deg, h1, n);
                    }
                    float* tmp = h0; h0 = h1; h1 = tmp;
                }
            }
            int oc = (l == 0) ? 32 : 64;
            int logC = (l == 0) ? 5 : 6;
            (void)hipMemsetAsync(pool, 0, (size_t)NS[l + 1] * oc * 4, stream);
            pool_scatter<<<cdiv(n * oc, TB), TB, 0, stream>>>(h0, cluster[l], pool, n, logC);
            pool_decode<<<cdiv(NS[l + 1] * oc, TB), TB, 0, stream>>>(pool, h1, NS[l + 1] * oc);
            float* tmp = h0; h0 = h1; h1 = tmp;
        }
        head_kernel<<<1, 64, 0, stream>>>(h0, fc1w, fc1b, fc2w, fc2b, outp);
    }
}

// Round 15
// 434.251 us; speedup vs baseline: 1.5348x; 1.0211x over previous
//
#include <hip/hip_runtime.h>
#include <hip/hip_bf16.h>

#define KS 5
#define K3 125

typedef __attribute__((ext_vector_type(8))) short short8;
typedef __attribute__((ext_vector_type(4))) float floatx4;

__device__ inline unsigned enc_f(float f) {
    int b = __float_as_int(f);
    return (b >= 0) ? ((unsigned)b | 0x80000000u) : ~((unsigned)b);
}

__device__ inline unsigned short f2bf(float f) {
    unsigned u = __float_as_uint(f);
    u += 0x7FFFu + ((u >> 16) & 1u);  // RNE
    return (unsigned short)(u >> 16);
}
__device__ inline unsigned pack2bf(float a, float b) {
    return (unsigned)f2bf(a) | ((unsigned)f2bf(b) << 16);
}

// ---------------------------------------------------------------------------
// Inline basis helpers
// ---------------------------------------------------------------------------
__device__ inline void edge_basis(const float* __restrict__ pseudo, int e,
                                  float* bs, int* ks) {
    float fr[3];
    int bot[3];
#pragma unroll
    for (int d = 0; d < 3; ++d) {
        float v = pseudo[e * 3 + d] * (float)(KS - 1);
        float fl = fminf(floorf(v), (float)(KS - 2));
        fr[d] = v - fl;
        bot[d] = (int)fl;
    }
    const int strides[3] = {1, KS, KS * KS};
#pragma unroll
    for (int s = 0; s < 8; ++s) {
        float b = 1.f;
        int w = 0;
#pragma unroll
        for (int d = 0; d < 3; ++d) {
            int bit = (s >> d) & 1;
            b *= bit ? fr[d] : (1.f - fr[d]);
            w += (bot[d] + bit) * strides[d];
        }
        bs[s] = b;
        ks[s] = w;
    }
}

__device__ inline void edge_fracs(const float* __restrict__ pseudo, int e, float* bs) {
    float fr[3];
#pragma unroll
    for (int d = 0; d < 3; ++d) {
        float v = pseudo[e * 3 + d] * (float)(KS - 1);
        float fl = fminf(floorf(v), (float)(KS - 2));
        fr[d] = v - fl;
    }
#pragma unroll
    for (int s = 0; s < 8; ++s) {
        float b = 1.f;
#pragma unroll
        for (int d = 0; d < 3; ++d) b *= ((s >> d) & 1) ? fr[d] : (1.f - fr[d]);
        bs[s] = b;
    }
}

__device__ inline int edge_bucket(const float* __restrict__ pseudo, int e) {
    int kb = 0;
#pragma unroll
    for (int d = 0; d < 3; ++d) {
        float v = pseudo[e * 3 + d] * (float)(KS - 1);
        int fl = (int)fminf(floorf(v), (float)(KS - 2));
        kb += fl << (2 * d);
    }
    return kb;
}

// ---------------------------------------------------------------------------
// Pre-pass 1: 64-bucket histogram + int degree (all levels).
// ---------------------------------------------------------------------------
__global__ __launch_bounds__(256) void hist_deg_all(
    const float* __restrict__ p0, const float* __restrict__ p1,
    const float* __restrict__ p2, const float* __restrict__ p3,
    const int* __restrict__ d0, const int* __restrict__ d1,
    const int* __restrict__ d2, const int* __restrict__ d3,
    int* __restrict__ hist, int* __restrict__ degi) {
    int b = blockIdx.x;
    int l, lb, E, dof;
    const float* ps;
    const int* ds;
    if (b < 512)      { l = 0; lb = b;       ps = p0; ds = d0; E = 131072; dof = 0; }
    else if (b < 640) { l = 1; lb = b - 512; ps = p1; ds = d1; E = 32768;  dof = 16384; }
    else if (b < 672) { l = 2; lb = b - 640; ps = p2; ds = d2; E = 8192;   dof = 20480; }
    else              { l = 3; lb = b - 672; ps = p3; ds = d3; E = 2048;   dof = 21504; }
    __shared__ int h[64];
    int t = threadIdx.x;
    if (t < 64) h[t] = 0;
    __syncthreads();
    int e = lb * 256 + t;
    if (e < E) {
        atomicAdd(&h[edge_bucket(ps, e)], 1);
        atomicAdd(&degi[dof + ds[e]], 1);
    }
    __syncthreads();
    if (t < 64 && h[t]) atomicAdd(&hist[l * 64 + t], h[t]);
}

// ---------------------------------------------------------------------------
// Pre-pass 2: bucket layout per level (blockIdx = level).
// ---------------------------------------------------------------------------
__global__ void scan_pad_all(const int* __restrict__ hist, int* __restrict__ gcur,
                             int* __restrict__ tileOf, int* __restrict__ pack) {
    const int TBv[4] = {0, 2112, 2112 + 576, 2112 + 576 + 192};
    int l = blockIdx.x;
    int tileBase = TBv[l];
    __shared__ int sh[64];
    int t = threadIdx.x;
    int cnt = hist[l * 64 + t];
    int tiles = (cnt + 63) >> 6;
    sh[t] = tiles;
    __syncthreads();
    for (int d = 1; d < 64; d <<= 1) {
        int v = (t >= d) ? sh[t - d] : 0;
        __syncthreads();
        sh[t] += v;
        __syncthreads();
    }
    int tb = tileBase + sh[t] - tiles;
    int eb = tb * 64;
    gcur[l * 64 + t] = eb;
    for (int q = 0; q < tiles; ++q) tileOf[tb + q] = t;
    for (int idx = eb + cnt; idx < eb + tiles * 64; ++idx) pack[idx] = -1;
}

// ---------------------------------------------------------------------------
// Pre-pass 2b: per-level dst-CSR offsets from degi.
// ---------------------------------------------------------------------------
__global__ __launch_bounds__(1024) void csr_scan_all(const int* __restrict__ degi,
                                                     int* __restrict__ off,
                                                     int* __restrict__ cur) {
    const int Nv[4] = {16384, 4096, 1024, 256};
    const int DOFv[4] = {0, 16384, 20480, 21504};
    const int OFFv[4] = {0, 16385, 20482, 21507};
    int l = blockIdx.x;
    int n = Nv[l];
    const int* d = degi + DOFv[l];
    int* o = off + OFFv[l];
    int* c = cur + DOFv[l];
    __shared__ int ls[1024];
    int t = threadIdx.x;
    int per = (n + 1023) >> 10;
    int beg = t * per;
    int end = (beg + per < n) ? beg + per : n;
    int s = 0;
    for (int j = beg; j < end; ++j) s += d[j];
    ls[t] = s;
    __syncthreads();
    for (int dd = 1; dd < 1024; dd <<= 1) {
        int v = (t >= dd) ? ls[t - dd] : 0;
        __syncthreads();
        ls[t] += v;
        __syncthreads();
    }
    int base = (t == 0) ? 0 : ls[t - 1];
    for (int j = beg; j < end; ++j) {
        o[j] = base;
        c[j] = base;
        base += d[j];
    }
    if (t == 1023) o[n] = ls[1023];
}

// ---------------------------------------------------------------------------
// Pre-pass 2c: cluster member lists. Every cluster has exactly 4 members.
// clist[NODE_OFF[l] + c*4 + slot] = node j (level-l local).
// ---------------------------------------------------------------------------
__global__ __launch_bounds__(256) void clist_all(
    const int* __restrict__ c0, const int* __restrict__ c1,
    const int* __restrict__ c2, const int* __restrict__ c3,
    int* __restrict__ ccnt, int* __restrict__ clist) {
    int idx = blockIdx.x * 256 + threadIdx.x;
    int l, j, cof, nof;
    const int* cl;
    if (idx < 16384)      { l = 0; j = idx;         cl = c0; cof = 0;    nof = 0; }
    else if (idx < 20480) { l = 1; j = idx - 16384; cl = c1; cof = 4096; nof = 16384; }
    else if (idx < 21504) { l = 2; j = idx - 20480; cl = c2; cof = 5120; nof = 20480; }
    else if (idx < 21760) { l = 3; j = idx - 21504; cl = c3; cof = 5376; nof = 21504; }
    else return;
    int c = cl[j];
    int slot = atomicAdd(&ccnt[cof + c], 1);
    clist[nof + c * 4 + slot] = j;
    (void)l;
}

// ---------------------------------------------------------------------------
// Pre-pass 3 (merged): block-local counting sort of edges by cube bucket
// + pos[e] = slot within dst's CSR run (absorbed from the old pos_all pass).
// ---------------------------------------------------------------------------
__global__ __launch_bounds__(256) void scatter_pos_all(
    const float* __restrict__ p0, const float* __restrict__ p1,
    const float* __restrict__ p2, const float* __restrict__ p3,
    const int* __restrict__ d0, const int* __restrict__ d1,
    const int* __restrict__ d2, const int* __restrict__ d3,
    int* __restrict__ gcur, int* __restrict__ cur,
    int* __restrict__ pack, int* __restrict__ posArr) {
    int b = blockIdx.x;
    int l, lb, E, dof, eof_;
    const float* ps;
    const int* ds;
    if (b < 128)      { l = 0; lb = b;       ps = p0; ds = d0; E = 131072; dof = 0;     eof_ = 0; }
    else if (b < 160) { l = 1; lb = b - 128; ps = p1; ds = d1; E = 32768;  dof = 16384; eof_ = 131072; }
    else if (b < 168) { l = 2; lb = b - 160; ps = p2; ds = d2; E = 8192;   dof = 20480; eof_ = 163840; }
    else              { l = 3; lb = b - 168; ps = p3; ds = d3; E = 2048;   dof = 21504; eof_ = 172032; }
    int* gc = gcur + l * 64;
    __shared__ int h[64], lbk[64], gb[64], sh[64];
    __shared__ int sp[1024];
    __shared__ unsigned char skk[1024];
    int t = threadIdx.x;
    int ebase = lb * 1024;
    int kbv[4];
    if (t < 64) h[t] = 0;
    __syncthreads();
#pragma unroll
    for (int j = 0; j < 4; ++j) {
        int e = ebase + j * 256 + t;
        if (e < E) {
            kbv[j] = edge_bucket(ps, e);
            atomicAdd(&h[kbv[j]], 1);
            posArr[eof_ + e] = atomicAdd(&cur[dof + ds[e]], 1);
        } else
            kbv[j] = -1;
    }
    __syncthreads();
    if (t < 64) sh[t] = h[t];
    __syncthreads();
    for (int d = 1; d < 64; d <<= 1) {
        int v = (t < 64 && t >= d) ? sh[t - d] : 0;
        __syncthreads();
        if (t < 64) sh[t] += v;
        __syncthreads();
    }
    if (t < 64) {
        int c = h[t];
        lbk[t] = sh[t] - c;
        gb[t] = c ? atomicAdd(&gc[t], c) : 0;
        h[t] = 0;
    }
    __syncthreads();
#pragma unroll
    for (int j = 0; j < 4; ++j) {
        int e = ebase + j * 256 + t;
        if (kbv[j] >= 0) {
            int pos = lbk[kbv[j]] + atomicAdd(&h[kbv[j]], 1);
            sp[pos] = e;
            skk[pos] = (unsigned char)kbv[j];
        }
    }
    __syncthreads();
    int Pb = E - ebase;
    if (Pb > 1024) Pb = 1024;
    for (int j = t; j < Pb; j += 256) {
        int k = skk[j];
        pack[gb[k] + (j - lbk[k])] = sp[j];
    }
}

// ---------------------------------------------------------------------------
// Pre-pass 5: convert W (fp32 [k][i][o]) -> Wt (bf16 [k][o][i]).
// ---------------------------------------------------------------------------
__global__ __launch_bounds__(256) void wcvt_all(
    const float* __restrict__ w12, const float* __restrict__ w2,
    const float* __restrict__ w3, const float* __restrict__ w4,
    const float* __restrict__ w5, const float* __restrict__ w6,
    const float* __restrict__ w7, short* __restrict__ Wt) {
    int idx = blockIdx.x * 256 + threadIdx.x;
    if (idx >= 2944000) return;
    const float* Wsrc;
    int IC, OC, local;
    if (idx < 128000)       { Wsrc = w12; IC = 32; OC = 32; local = idx; }
    else if (idx < 384000)  { Wsrc = w2;  IC = 32; OC = 64; local = idx - 128000; }
    else if (idx < 896000)  { Wsrc = w3;  IC = 64; OC = 64; local = idx - 384000; }
    else if (idx < 1408000) { Wsrc = w4;  IC = 64; OC = 64; local = idx - 896000; }
    else if (idx < 1920000) { Wsrc = w5;  IC = 64; OC = 64; local = idx - 1408000; }
    else if (idx < 2432000) { Wsrc = w6;  IC = 64; OC = 64; local = idx - 1920000; }
    else                    { Wsrc = w7;  IC = 64; OC = 64; local = idx - 2432000; }
    int per = IC * OC;
    int k = local / per;
    int r = local % per;
    int o = r / IC;
    int i = r % IC;
    Wt[idx] = (short)f2bf(Wsrc[(size_t)(k * IC + i) * OC + o]);
}

// ---------------------------------------------------------------------------
// Fused conv1 (in_c = 1): per-edge row to y[pos[e]] (fp32, no atomics).
// ---------------------------------------------------------------------------
__global__ __launch_bounds__(256) void conv1_y(const float* __restrict__ x,
                                               const int* __restrict__ src,
                                               const float* __restrict__ pseudo,
                                               const int* __restrict__ pos,
                                               const float* __restrict__ W,
                                               float* __restrict__ y, int E) {
    const int lane = threadIdx.x & 63;
    const int wid = threadIdx.x >> 6;
    const int sub = lane >> 5;
    const int o = lane & 31;
    int e = (blockIdx.x * 4 + wid) * 2 + sub;
    if (e >= E) return;
    float bs[8];
    int ks[8];
    edge_basis(pseudo, e, bs, ks);
    float acc = 0.f;
#pragma unroll
    for (int s = 0; s < 8; ++s) acc = fmaf(bs[s], W[ks[s] * 32 + o], acc);
    y[(size_t)pos[e] * 32 + o] = acc * x[src[e]];
}

// ---------------------------------------------------------------------------
// MFMA bucket-tile conv (unchanged from R14 — verified correct).
// ---------------------------------------------------------------------------
template <int IN_C, int OUT_C>
__global__ __launch_bounds__(256) void mfma_conv(
    const float* __restrict__ x, const int* __restrict__ src,
    const float* __restrict__ pseudo, const int* __restrict__ pack,
    const int* __restrict__ tileOf, const int* __restrict__ pos,
    const short* __restrict__ Wt, float* __restrict__ y, int tileBase) {
    constexpr int K = 8 * IN_C;
    constexpr int KP = K + 8;
    constexpr int NT = OUT_C / 16;
    constexpr int IP = IN_C / 4;
    __shared__ short As[64 * KP];
    __shared__ int posL[64];
    const int tid = threadIdx.x;
    int t = tileBase + blockIdx.x;
    int kb = tileOf[t];
    if (kb < 0) return;
    kb = __builtin_amdgcn_readfirstlane(kb);
    const int kbase = (kb & 3) + 5 * ((kb >> 2) & 3) + 25 * ((kb >> 4) & 3);
    {
        const int eLoc = tid >> 2, part = tid & 3;
        int e = pack[t * 64 + eLoc];
        float bs[8];
        if (e >= 0) edge_fracs(pseudo, e, bs);
        else {
#pragma unroll
            for (int s = 0; s < 8; ++s) bs[s] = 0.f;
        }
        if (part == 0) posL[eLoc] = (e >= 0) ? pos[e] : -1;
        float4 xq[IP / 4];
#pragma unroll
        for (int g = 0; g < IP / 4; ++g)
            xq[g] = (e >= 0)
                        ? *(const float4*)(x + (size_t)src[e] * IN_C + part * IP + g * 4)
                        : make_float4(0.f, 0.f, 0.f, 0.f);
#pragma unroll
        for (int s = 0; s < 8; ++s) {
            const float b = bs[s];
            short* rowp = &As[eLoc * KP + s * IN_C + part * IP];
#pragma unroll
            for (int g = 0; g < IP / 4; ++g) {
                unsigned lo = pack2bf(b * xq[g].x, b * xq[g].y);
                unsigned hi = pack2bf(b * xq[g].z, b * xq[g].w);
                *(uint2*)(rowp + 4 * g) = make_uint2(lo, hi);
            }
        }
    }
    __syncthreads();
    const int wave = tid >> 6, lane = tid & 63;
    const int quad = lane >> 4, lm = lane & 15;
    floatx4 acc[NT];
#pragma unroll
    for (int nt = 0; nt < NT; ++nt) acc[nt] = (floatx4){0.f, 0.f, 0.f, 0.f};
    const short* myrow = &As[(wave * 16 + lm) * KP];
#pragma unroll
    for (int kstep = 0; kstep < K / 32; ++kstep) {
        const int kg = kstep * 32;
        const int s = kg / IN_C;
        const int i0 = kg % IN_C;
        const int ks = kbase + (s & 1) + 5 * ((s >> 1) & 1) + 25 * ((s >> 2) & 1);
        short8 a = *(const short8*)&myrow[kg + quad * 8];
#pragma unroll
        for (int nt = 0; nt < NT; ++nt) {
            const short* bp =
                Wt + ((size_t)ks * OUT_C + nt * 16 + lm) * IN_C + i0 + quad * 8;
            short8 bfr = *(const short8*)bp;
            acc[nt] = __builtin_amdgcn_mfma_f32_16x16x32_bf16(a, bfr, acc[nt], 0, 0, 0);
        }
    }
#pragma unroll
    for (int nt = 0; nt < NT; ++nt) {
#pragma unroll
        for (int r = 0; r < 4; ++r) {
            int row = wave * 16 + quad * 4 + r;
            int p = posL[row];
            if (p >= 0) y[(size_t)p * OUT_C + nt * 16 + lm] = acc[nt][r];
        }
    }
}

// ---------------------------------------------------------------------------
// Finalize (gather): out = (sum of dst's CSR run of y)/deg + x@R + B, ELU.
// ---------------------------------------------------------------------------
template <int IN_C, int OUT_C>
__device__ inline float csr_sum(const int* __restrict__ off,
                                const float* __restrict__ y, int j, int o,
                                float& dcount) {
    int b0 = off[j], b1 = off[j + 1];
    dcount = fmaxf((float)(b1 - b0), 1.f);
    float s0 = 0.f, s1 = 0.f, s2 = 0.f, s3 = 0.f;
    int r = b0;
    for (; r + 4 <= b1; r += 4) {
        s0 += y[(size_t)(r + 0) * OUT_C + o];
        s1 += y[(size_t)(r + 1) * OUT_C + o];
        s2 += y[(size_t)(r + 2) * OUT_C + o];
        s3 += y[(size_t)(r + 3) * OUT_C + o];
    }
    for (; r < b1; ++r) s0 += y[(size_t)r * OUT_C + o];
    return (s0 + s1) + (s2 + s3);
}

template <int IN_C, int OUT_C>
__global__ __launch_bounds__(256) void fin_gather_k(
    const float* __restrict__ xin, const float* __restrict__ R,
    const float* __restrict__ B, const int* __restrict__ off,
    const float* __restrict__ y, float* __restrict__ out, int n) {
    const int lane = threadIdx.x & 63;
    const int wid = threadIdx.x >> 6;
    constexpr int EPW = 64 / OUT_C;
    const int sub = (EPW == 2) ? (lane >> 5) : 0;
    const int o = lane & (OUT_C - 1);
    int j = (blockIdx.x * (blockDim.x >> 6) + wid) * EPW + sub;
    if (j >= n) return;
    float xv = (o < IN_C) ? xin[j * IN_C + o] : 0.f;
    float acc = B[o];
#pragma unroll 4
    for (int i = 0; i < IN_C; ++i) {
        float xi = __shfl(xv, i, OUT_C);
        acc = fmaf(xi, R[i * OUT_C + o], acc);
    }
    float d;
    float s = csr_sum<IN_C, OUT_C>(off, y, j, o, d);
    float v = s / d + acc;
    out[j * OUT_C + o] = (v > 0.f) ? v : expm1f(v);
}

// ---------------------------------------------------------------------------
// Pool gather-max: every cluster has exactly 4 members (clist).
// ---------------------------------------------------------------------------
template <int OC>
__global__ __launch_bounds__(256) void pool_gather(const float* __restrict__ h,
                                                   const int* __restrict__ clist,
                                                   float* __restrict__ out, int m) {
    int idx = blockIdx.x * 256 + threadIdx.x;
    if (idx >= m * OC) return;
    int c = idx / OC;
    int ch = idx - c * OC;
    const int* mb = &clist[c * 4];
    float v0 = h[(size_t)mb[0] * OC + ch];
    float v1 = h[(size_t)mb[1] * OC + ch];
    float v2 = h[(size_t)mb[2] * OC + ch];
    float v3 = h[(size_t)mb[3] * OC + ch];
    out[idx] = fmaxf(fmaxf(v0, v1), fmaxf(v2, v3));
}

// ---------------------------------------------------------------------------
// Fallback kernels (small-ws path only).
// ---------------------------------------------------------------------------
__global__ __launch_bounds__(256) void conv1_fused(const float* __restrict__ x,
                                                   const int* __restrict__ src,
                                                   const int* __restrict__ dst,
                                                   const float* __restrict__ pseudo,
                                                   const float* __restrict__ W,
                                                   float* __restrict__ out, int E) {
    const int lane = threadIdx.x & 63;
    const int wid = threadIdx.x >> 6;
    const int sub = lane >> 5;
    const int o = lane & 31;
    int e = (blockIdx.x * 4 + wid) * 2 + sub;
    if (e >= E) return;
    float bs[8];
    int ks[8];
    edge_basis(pseudo, e, bs, ks);
    float acc = 0.f;
#pragma unroll
    for (int s = 0; s < 8; ++s) acc = fmaf(bs[s], W[ks[s] * 32 + o], acc);
    atomicAdd(&out[(size_t)dst[e] * 32 + o], acc * x[src[e]]);
}

template <int IN_C, int OUT_C>
__global__ __launch_bounds__(256) void conv_edges_inline(
    const float* __restrict__ x, const int* __restrict__ src,
    const int* __restrict__ dst, const float* __restrict__ pseudo,
    const float* __restrict__ W, float* __restrict__ out, int E) {
    const int lane = threadIdx.x & 63;
    const int wid = threadIdx.x >> 6;
    constexpr int EPW = 64 / OUT_C;
    const int sub = (EPW == 2) ? (lane >> 5) : 0;
    const int o = lane & (OUT_C - 1);
    long e = (long)(blockIdx.x * (blockDim.x >> 6) + wid) * EPW + sub;
    if (e >= E) return;
    float bs[8];
    int ks[8];
    edge_basis(pseudo, e, bs, ks);
    const int s_ = src[e];
    const int d_ = dst[e];
    float xv = (o < IN_C) ? x[s_ * IN_C + o] : 0.f;
    float acc = 0.f;
#pragma unroll
    for (int s = 0; s < 8; ++s) {
        const float b = bs[s];
        const float* Wk = W + (long)ks[s] * IN_C * OUT_C;
#pragma unroll 4
        for (int i = 0; i < IN_C; ++i) {
            float xi = __shfl(xv, i, OUT_C);
            acc = fmaf(b * xi, Wk[i * OUT_C + o], acc);
        }
    }
    atomicAdd(&out[(long)d_ * OUT_C + o], acc);
}

__global__ void deg_kernel(const int* __restrict__ dst, float* __restrict__ deg, int E) {
    int e = blockIdx.x * blockDim.x + threadIdx.x;
    if (e >= E) return;
    atomicAdd(&deg[dst[e]], 1.0f);
}

template <int IN_C, int OUT_C>
__global__ __launch_bounds__(256) void finalize_k(
    const float* __restrict__ xin, const float* __restrict__ R,
    const float* __restrict__ B, const float* __restrict__ deg,
    float* __restrict__ out, int n) {
    const int lane = threadIdx.x & 63;
    const int wid = threadIdx.x >> 6;
    constexpr int EPW = 64 / OUT_C;
    const int sub = (EPW == 2) ? (lane >> 5) : 0;
    const int o = lane & (OUT_C - 1);
    int j = (blockIdx.x * (blockDim.x >> 6) + wid) * EPW + sub;
    if (j >= n) return;
    float xv = (o < IN_C) ? xin[j * IN_C + o] : 0.f;
    float acc = B[o];
#pragma unroll 4
    for (int i = 0; i < IN_C; ++i) {
        float xi = __shfl(xv, i, OUT_C);
        acc = fmaf(xi, R[i * OUT_C + o], acc);
    }
    float d = fmaxf(deg[j], 1.f);
    float v = out[j * OUT_C + o] / d + acc;
    out[j * OUT_C + o] = (v > 0.f) ? v : expm1f(v);
}

__global__ void pool_scatter(const float* __restrict__ h, const int* __restrict__ cluster,
                             unsigned* __restrict__ pool, int n, int logC) {
    int idx = blockIdx.x * blockDim.x + threadIdx.x;
    if (idx >= (n << logC)) return;
    int j = idx >> logC;
    int c = idx & ((1 << logC) - 1);
    atomicMax(&pool[(cluster[j] << logC) + c], enc_f(h[idx]));
}

__global__ void pool_decode(const unsigned* __restrict__ pool, float* __restrict__ out, int total) {
    int idx = blockIdx.x * blockDim.x + threadIdx.x;
    if (idx >= total) return;
    unsigned u = pool[idx];
    int b = (u & 0x80000000u) ? (int)(u & 0x7FFFFFFFu) : (int)(~u);
    out[idx] = __int_as_float(b);
}

// ---------------------------------------------------------------------------
// Head: mean(64x64) -> fc1 -> fc2 -> log_softmax
// ---------------------------------------------------------------------------
__global__ void head_kernel(const float* __restrict__ h, const float* __restrict__ fc1w,
                            const float* __restrict__ fc1b, const float* __restrict__ fc2w,
                            const float* __restrict__ fc2b, float* __restrict__ out) {
    __shared__ float m[64], t[64], u[10];
    int lane = threadIdx.x;
    float s = 0.f;
    for (int j = 0; j < 64; ++j) s += h[j * 64 + lane];
    m[lane] = s * (1.f / 64.f);
    __syncthreads();
    float a = fc1b[lane];
    for (int i = 0; i < 64; ++i) a = fmaf(m[i], fc1w[i * 64 + lane], a);
    t[lane] = a;
    __syncthreads();
    if (lane < 10) {
        float b = fc2b[lane];
        for (int i = 0; i < 64; ++i) b = fmaf(t[i], fc2w[i * 10 + lane], b);
        u[lane] = b;
    }
    __syncthreads();
    if (lane < 10) {
        float mx = u[0];
        for (int i = 1; i < 10; ++i) mx = fmaxf(mx, u[i]);
        float se = 0.f;
        for (int i = 0; i < 10; ++i) se += expf(u[i] - mx);
        out[lane] = u[lane] - mx - logf(se);
    }
}

// ---------------------------------------------------------------------------
// Host side
// ---------------------------------------------------------------------------
static inline int cdiv(int a, int b) { return (a + b - 1) / b; }

extern "C" void kernel_launch(void* const* d_in, const int* in_sizes, int n_in,
                              void* d_out, int out_size, void* d_ws, size_t ws_size,
                              hipStream_t stream) {
    const float* x = (const float*)d_in[0];
    const int* src[4] = {(const int*)d_in[1], (const int*)d_in[5], (const int*)d_in[9], (const int*)d_in[13]};
    const int* dst[4] = {(const int*)d_in[2], (const int*)d_in[6], (const int*)d_in[10], (const int*)d_in[14]};
    const float* pseudo[4] = {(const float*)d_in[3], (const float*)d_in[7], (const float*)d_in[11], (const float*)d_in[15]};
    const int* cluster[4] = {(const int*)d_in[4], (const int*)d_in[8], (const int*)d_in[12], (const int*)d_in[16]};
    const float* Wp[8], *Rp[8], *Bp[8];
    for (int l = 0; l < 8; ++l) {
        Wp[l] = (const float*)d_in[17 + 3 * l];
        Rp[l] = (const float*)d_in[18 + 3 * l];
        Bp[l] = (const float*)d_in[19 + 3 * l];
    }
    const float* fc1w = (const float*)d_in[41];
    const float* fc1b = (const float*)d_in[42];
    const float* fc2w = (const float*)d_in[43];
    const float* fc2b = (const float*)d_in[44];
    float* outp = (float*)d_out;

    const int NS[5] = {16384, 4096, 1024, 256, 64};
    const int ES[4] = {16384 * 8, 4096 * 8, 1024 * 8, 256 * 8};
    const int MT[4] = {2048 + 64, 512 + 64, 128 + 64, 32 + 64};
    const int TB_[4] = {0, 2112, 2112 + 576, 2112 + 576 + 192};
    const int TOT_TILES = 2112 + 576 + 192 + 96;  // 2976
    const int DTOT = 21760;
    const int OFF2[4] = {0, 16385, 20482, 21507};
    const int OFFTOT = 21764;
    const int EBASE[4] = {0, 131072, 163840, 172032};
    const int ETOT = 174080;
    const int NODE_OFF[4] = {0, 16384, 20480, 21504};
    const int CCTOT = 4096 + 1024 + 256 + 64;  // 5440
    const int WT_OFF[7] = {0, 128000, 384000, 896000, 1408000, 1920000, 2432000};
    const int WT_TOT = 2944000;

    char* w = (char*)d_ws;
    auto take = [&](size_t bytes) -> char* {
        char* r = w;
        w += (bytes + 255) & ~(size_t)255;
        return r;
    };
    float* bufA = (float*)take((size_t)NS[0] * 64 * 4);
    float* bufB = (float*)take((size_t)NS[0] * 64 * 4);
    unsigned* pool = (unsigned*)take((size_t)NS[1] * 64 * 4);  // fallback only
    // ---- contiguous zero-init region: hist | ccnt | degi | tileOf ----
    char* zbase = w;
    int* hist = (int*)take((size_t)4 * 64 * 4);
    int* ccnt = (int*)take((size_t)CCTOT * 4);
    int* degi = (int*)take((size_t)DTOT * 4);
    int* tileOf = (int*)take((size_t)TOT_TILES * 4);
    size_t zbytes = (size_t)(w - zbase);
    size_t fallbackNeed = (size_t)(w - (char*)d_ws);
    int* gcur = (int*)take((size_t)4 * 64 * 4);
    int* pack = (int*)take((size_t)TOT_TILES * 64 * 4);
    int* csr = (int*)take((size_t)OFFTOT * 4);
    int* cur = (int*)take((size_t)DTOT * 4);
    int* posArr = (int*)take((size_t)ETOT * 4);
    int* clist = (int*)take((size_t)DTOT * 4);
    short* Wtb = (short*)take((size_t)WT_TOT * 2);
    float* y = (float*)take((size_t)ES[0] * 32 * 4);
    size_t need = (size_t)(w - (char*)d_ws);
    bool fast = ws_size >= need;

    const int TB = 256;

    if (fast) {
        // ---------- pre-pass: 1 memset + 6 kernels -------------------------
        (void)hipMemsetAsync(zbase, 0, zbytes, stream);
        hist_deg_all<<<680, 256, 0, stream>>>(pseudo[0], pseudo[1], pseudo[2], pseudo[3],
                                              dst[0], dst[1], dst[2], dst[3], hist, degi);
        wcvt_all<<<cdiv(WT_TOT, 256), 256, 0, stream>>>(Wp[1], Wp[2], Wp[3], Wp[4],
                                                        Wp[5], Wp[6], Wp[7], Wtb);
        clist_all<<<cdiv(DTOT, 256), 256, 0, stream>>>(cluster[0], cluster[1], cluster[2],
                                                       cluster[3], ccnt, clist);
        scan_pad_all<<<4, 64, 0, stream>>>(hist, gcur, tileOf, pack);
        csr_scan_all<<<4, 1024, 0, stream>>>(degi, csr, cur);
        scatter_pos_all<<<170, 256, 0, stream>>>(pseudo[0], pseudo[1], pseudo[2], pseudo[3],
                                                 dst[0], dst[1], dst[2], dst[3],
                                                 gcur, cur, pack, posArr);

        // ---------------- Level 0: conv1 (1->32), conv12 (32->32) ----------
        {
            int E = ES[0], n = NS[0];
            const int* off = csr + OFF2[0];
            const int* pos = posArr + EBASE[0];
            conv1_y<<<cdiv(E, 8), TB, 0, stream>>>(x, src[0], pseudo[0], pos, Wp[0], y, E);
            fin_gather_k<1, 32><<<cdiv(n, 8), TB, 0, stream>>>(x, Rp[0], Bp[0], off, y, bufA, n);
            mfma_conv<32, 32><<<MT[0], TB, 0, stream>>>(
                bufA, src[0], pseudo[0], pack, tileOf, pos, Wtb + WT_OFF[0], y, TB_[0]);
            fin_gather_k<32, 32><<<cdiv(n, 8), TB, 0, stream>>>(bufA, Rp[1], Bp[1], off, y, bufB, n);
            pool_gather<32><<<cdiv(NS[1] * 32, 256), 256, 0, stream>>>(
                bufB, clist + NODE_OFF[0], bufA, NS[1]);
        }
        // ---------------- Level 1: conv2 (32->64), conv3 (64->64) ----------
        {
            int n = NS[1];
            const int* off = csr + OFF2[1];
            const int* pos = posArr + EBASE[1];
            mfma_conv<32, 64><<<MT[1], TB, 0, stream>>>(
                bufA, src[1], pseudo[1], pack, tileOf, pos, Wtb + WT_OFF[1], y, TB_[1]);
            fin_gather_k<32, 64><<<cdiv(n, 4), TB, 0, stream>>>(bufA, Rp[2], Bp[2], off, y, bufB, n);
            mfma_conv<64, 64><<<MT[1], TB, 0, stream>>>(
                bufB, src[1], pseudo[1], pack, tileOf, pos, Wtb + WT_OFF[2], y, TB_[1]);
            fin_gather_k<64, 64><<<cdiv(n, 4), TB, 0, stream>>>(bufB, Rp[3], Bp[3], off, y, bufA, n);
            pool_gather<64><<<cdiv(NS[2] * 64, 256), 256, 0, stream>>>(
                bufA, clist + NODE_OFF[1], bufB, NS[2]);
        }
        // ---------------- Level 2: conv4, conv5 (64->64) -------------------
        {
            int n = NS[2];
            const int* off = csr + OFF2[2];
            const int* pos = posArr + EBASE[2];
            mfma_conv<64, 64><<<MT[2], TB, 0, stream>>>(
                bufB, src[2], pseudo[2], pack, tileOf, pos, Wtb + WT_OFF[3], y, TB_[2]);
            fin_gather_k<64, 64><<<cdiv(n, 4), TB, 0, stream>>>(bufB, Rp[4], Bp[4], off, y, bufA, n);
            mfma_conv<64, 64><<<MT[2], TB, 0, stream>>>(
                bufA, src[2], pseudo[2], pack, tileOf, pos, Wtb + WT_OFF[4], y, TB_[2]);
            fin_gather_k<64, 64><<<cdiv(n, 4), TB, 0, stream>>>(bufA, Rp[5], Bp[5], off, y, bufB, n);
            pool_gather<64><<<cdiv(NS[3] * 64, 256), 256, 0, stream>>>(
                bufB, clist + NODE_OFF[2], bufA, NS[3]);
        }
        // ---------------- Level 3: conv6, conv7 (64->64) -------------------
        {
            int n = NS[3];
            const int* off = csr + OFF2[3];
            const int* pos = posArr + EBASE[3];
            mfma_conv<64, 64><<<MT[3], TB, 0, stream>>>(
                bufA, src[3], pseudo[3], pack, tileOf, pos, Wtb + WT_OFF[5], y, TB_[3]);
            fin_gather_k<64, 64><<<cdiv(n, 4), TB, 0, stream>>>(bufA, Rp[6], Bp[6], off, y, bufB, n);
            mfma_conv<64, 64><<<MT[3], TB, 0, stream>>>(
                bufB, src[3], pseudo[3], pack, tileOf, pos, Wtb + WT_OFF[6], y, TB_[3]);
            fin_gather_k<64, 64><<<cdiv(n, 4), TB, 0, stream>>>(bufB, Rp[7], Bp[7], off, y, bufA, n);
            pool_gather<64><<<cdiv(NS[4] * 64, 256), 256, 0, stream>>>(
                bufA, clist + NODE_OFF[3], bufB, NS[4]);
        }
        head_kernel<<<1, 64, 0, stream>>>(bufB, fc1w, fc1b, fc2w, fc2b, outp);
    } else if (ws_size >= fallbackNeed) {
        // ---------------- legacy edge-centric fallback ---------------------
        float* h0 = bufA;
        float* h1 = bufB;
        float* deg = (float*)degi;
        for (int l = 0; l < 4; ++l) {
            int E = ES[l], n = NS[l];
            (void)hipMemsetAsync(deg, 0, n * 4, stream);
            deg_kernel<<<cdiv(E, TB), TB, 0, stream>>>(dst[l], deg, E);
            for (int cc = 0; cc < 2; ++cc) {
                int li = (l == 0) ? cc : 2 * l + cc;
                if (l == 0 && cc == 0) {
                    (void)hipMemsetAsync(h0, 0, (size_t)n * 32 * 4, stream);
                    conv1_fused<<<cdiv(E, 8), TB, 0, stream>>>(x, src[0], dst[0], pseudo[0], Wp[0], h0, E);
                    finalize_k<1, 32><<<cdiv(n, 8), TB, 0, stream>>>(x, Rp[0], Bp[0], deg, h0, n);
                } else {
                    int ic = (l == 0) ? 32 : ((l == 1 && cc == 0) ? 32 : 64);
                    int oc = (l == 0) ? 32 : 64;
                    (void)hipMemsetAsync(h1, 0, (size_t)n * oc * 4, stream);
                    if (ic == 32 && oc == 32) {
                        conv_edges_inline<32, 32><<<cdiv(E, 8), TB, 0, stream>>>(h0, src[l], dst[l], pseudo[l], Wp[li], h1, E);
                        finalize_k<32, 32><<<cdiv(n, 8), TB, 0, stream>>>(h0, Rp[li], Bp[li], deg, h1, n);
                    } else if (ic == 32) {
                        conv_edges_inline<32, 64><<<cdiv(E, 4), TB, 0, stream>>>(h0, src[l], dst[l], pseudo[l], Wp[li], h1, E);
                        finalize_k<32, 64><<<cdiv(n, 4), TB, 0, stream>>>(h0, Rp[li], Bp[li], deg, h1, n);
                    } else {
                        conv_edges_inline<64, 64><<<cdiv(E, 4), TB, 0, stream>>>(h0, src[l], dst[l], pseudo[l], Wp[li], h1, E);
                        finalize_k<64, 64><<<cdiv(n, 4), TB, 0, stream>>>(h0, Rp[li], Bp[li], deg, h1, n);
                    }
                    float* tmp = h0; h0 = h1; h1 = tmp;
                }
            }
            int oc = (l == 0) ? 32 : 64;
            int logC = (l == 0) ? 5 : 6;
            (void)hipMemsetAsync(pool, 0, (size_t)NS[l + 1] * oc * 4, stream);
            pool_scatter<<<cdiv(n * oc, TB), TB, 0, stream>>>(h0, cluster[l], pool, n, logC);
            pool_decode<<<cdiv(NS[l + 1] * oc, TB), TB, 0, stream>>>(pool, h1, NS[l + 1] * oc);
            float* tmp = h0; h0 = h1; h1 = tmp;
        }
        head_kernel<<<1, 64, 0, stream>>>(h0, fc1w, fc1b, fc2w, fc2b, outp);
    }
}

// Round 16
// 427.756 us; speedup vs baseline: 1.5582x; 1.0152x over previous
//
#include <hip/hip_runtime.h>
#include <hip/hip_bf16.h>

#define KS 5
#define K3 125

typedef __attribute__((ext_vector_type(8))) short short8;
typedef __attribute__((ext_vector_type(4))) float floatx4;

__device__ inline unsigned enc_f(float f) {
    int b = __float_as_int(f);
    return (b >= 0) ? ((unsigned)b | 0x80000000u) : ~((unsigned)b);
}

__device__ inline unsigned short f2bf(float f) {
    unsigned u = __float_as_uint(f);
    u += 0x7FFFu + ((u >> 16) & 1u);  // RNE
    return (unsigned short)(u >> 16);
}
__device__ inline float bf2f(unsigned short h) {
    return __uint_as_float((unsigned)h << 16);
}
__device__ inline unsigned pack2bf(float a, float b) {
    return (unsigned)f2bf(a) | ((unsigned)f2bf(b) << 16);
}

// ---------------------------------------------------------------------------
// Inline basis helpers
// ---------------------------------------------------------------------------
__device__ inline void edge_basis(const float* __restrict__ pseudo, int e,
                                  float* bs, int* ks) {
    float fr[3];
    int bot[3];
#pragma unroll
    for (int d = 0; d < 3; ++d) {
        float v = pseudo[e * 3 + d] * (float)(KS - 1);
        float fl = fminf(floorf(v), (float)(KS - 2));
        fr[d] = v - fl;
        bot[d] = (int)fl;
    }
    const int strides[3] = {1, KS, KS * KS};
#pragma unroll
    for (int s = 0; s < 8; ++s) {
        float b = 1.f;
        int w = 0;
#pragma unroll
        for (int d = 0; d < 3; ++d) {
            int bit = (s >> d) & 1;
            b *= bit ? fr[d] : (1.f - fr[d]);
            w += (bot[d] + bit) * strides[d];
        }
        bs[s] = b;
        ks[s] = w;
    }
}

__device__ inline void edge_fracs(const float* __restrict__ pseudo, int e, float* bs) {
    float fr[3];
#pragma unroll
    for (int d = 0; d < 3; ++d) {
        float v = pseudo[e * 3 + d] * (float)(KS - 1);
        float fl = fminf(floorf(v), (float)(KS - 2));
        fr[d] = v - fl;
    }
#pragma unroll
    for (int s = 0; s < 8; ++s) {
        float b = 1.f;
#pragma unroll
        for (int d = 0; d < 3; ++d) b *= ((s >> d) & 1) ? fr[d] : (1.f - fr[d]);
        bs[s] = b;
    }
}

__device__ inline int edge_bucket(const float* __restrict__ pseudo, int e) {
    int kb = 0;
#pragma unroll
    for (int d = 0; d < 3; ++d) {
        float v = pseudo[e * 3 + d] * (float)(KS - 1);
        int fl = (int)fminf(floorf(v), (float)(KS - 2));
        kb += fl << (2 * d);
    }
    return kb;
}

// ---------------------------------------------------------------------------
// Pre-pass 1 (merged): 64-bucket histogram + int degree (blocks 0..679)
// + cluster member lists (blocks 680..764; every cluster has 4 members).
// ---------------------------------------------------------------------------
__global__ __launch_bounds__(256) void hist_deg_clist_all(
    const float* __restrict__ p0, const float* __restrict__ p1,
    const float* __restrict__ p2, const float* __restrict__ p3,
    const int* __restrict__ d0, const int* __restrict__ d1,
    const int* __restrict__ d2, const int* __restrict__ d3,
    const int* __restrict__ c0, const int* __restrict__ c1,
    const int* __restrict__ c2, const int* __restrict__ c3,
    int* __restrict__ hist, int* __restrict__ degi,
    int* __restrict__ ccnt, int* __restrict__ clist) {
    int b = blockIdx.x;
    if (b >= 680) {  // ---- clist part ----
        int idx = (b - 680) * 256 + threadIdx.x;
        int j, cof, nof;
        const int* cl;
        if (idx < 16384)      { j = idx;         cl = c0; cof = 0;    nof = 0; }
        else if (idx < 20480) { j = idx - 16384; cl = c1; cof = 4096; nof = 16384; }
        else if (idx < 21504) { j = idx - 20480; cl = c2; cof = 5120; nof = 20480; }
        else if (idx < 21760) { j = idx - 21504; cl = c3; cof = 5376; nof = 21504; }
        else return;
        int c = cl[j];
        int slot = atomicAdd(&ccnt[cof + c], 1);
        clist[nof + c * 4 + slot] = j;
        return;
    }
    int l, lb, E, dof;
    const float* ps;
    const int* ds;
    if (b < 512)      { l = 0; lb = b;       ps = p0; ds = d0; E = 131072; dof = 0; }
    else if (b < 640) { l = 1; lb = b - 512; ps = p1; ds = d1; E = 32768;  dof = 16384; }
    else if (b < 672) { l = 2; lb = b - 640; ps = p2; ds = d2; E = 8192;   dof = 20480; }
    else              { l = 3; lb = b - 672; ps = p3; ds = d3; E = 2048;   dof = 21504; }
    __shared__ int h[64];
    int t = threadIdx.x;
    if (t < 64) h[t] = 0;
    __syncthreads();
    int e = lb * 256 + t;
    if (e < E) {
        atomicAdd(&h[edge_bucket(ps, e)], 1);
        atomicAdd(&degi[dof + ds[e]], 1);
    }
    __syncthreads();
    if (t < 64 && h[t]) atomicAdd(&hist[l * 64 + t], h[t]);
}

// ---------------------------------------------------------------------------
// Pre-pass 2: bucket layout per level (blockIdx = level).
// ---------------------------------------------------------------------------
__global__ void scan_pad_all(const int* __restrict__ hist, int* __restrict__ gcur,
                             int* __restrict__ tileOf, int* __restrict__ pack) {
    const int TBv[4] = {0, 2112, 2112 + 576, 2112 + 576 + 192};
    int l = blockIdx.x;
    int tileBase = TBv[l];
    __shared__ int sh[64];
    int t = threadIdx.x;
    int cnt = hist[l * 64 + t];
    int tiles = (cnt + 63) >> 6;
    sh[t] = tiles;
    __syncthreads();
    for (int d = 1; d < 64; d <<= 1) {
        int v = (t >= d) ? sh[t - d] : 0;
        __syncthreads();
        sh[t] += v;
        __syncthreads();
    }
    int tb = tileBase + sh[t] - tiles;
    int eb = tb * 64;
    gcur[l * 64 + t] = eb;
    for (int q = 0; q < tiles; ++q) tileOf[tb + q] = t;
    for (int idx = eb + cnt; idx < eb + tiles * 64; ++idx) pack[idx] = -1;
}

// ---------------------------------------------------------------------------
// Pre-pass 2b: per-level dst-CSR offsets from degi.
// ---------------------------------------------------------------------------
__global__ __launch_bounds__(1024) void csr_scan_all(const int* __restrict__ degi,
                                                     int* __restrict__ off,
                                                     int* __restrict__ cur) {
    const int Nv[4] = {16384, 4096, 1024, 256};
    const int DOFv[4] = {0, 16384, 20480, 21504};
    const int OFFv[4] = {0, 16385, 20482, 21507};
    int l = blockIdx.x;
    int n = Nv[l];
    const int* d = degi + DOFv[l];
    int* o = off + OFFv[l];
    int* c = cur + DOFv[l];
    __shared__ int ls[1024];
    int t = threadIdx.x;
    int per = (n + 1023) >> 10;
    int beg = t * per;
    int end = (beg + per < n) ? beg + per : n;
    int s = 0;
    for (int j = beg; j < end; ++j) s += d[j];
    ls[t] = s;
    __syncthreads();
    for (int dd = 1; dd < 1024; dd <<= 1) {
        int v = (t >= dd) ? ls[t - dd] : 0;
        __syncthreads();
        ls[t] += v;
        __syncthreads();
    }
    int base = (t == 0) ? 0 : ls[t - 1];
    for (int j = beg; j < end; ++j) {
        o[j] = base;
        c[j] = base;
        base += d[j];
    }
    if (t == 1023) o[n] = ls[1023];
}

// ---------------------------------------------------------------------------
// Pre-pass 3 (merged): counting sort of edges by cube bucket + pos[e].
// ---------------------------------------------------------------------------
__global__ __launch_bounds__(256) void scatter_pos_all(
    const float* __restrict__ p0, const float* __restrict__ p1,
    const float* __restrict__ p2, const float* __restrict__ p3,
    const int* __restrict__ d0, const int* __restrict__ d1,
    const int* __restrict__ d2, const int* __restrict__ d3,
    int* __restrict__ gcur, int* __restrict__ cur,
    int* __restrict__ pack, int* __restrict__ posArr) {
    int b = blockIdx.x;
    int l, lb, E, dof, eof_;
    const float* ps;
    const int* ds;
    if (b < 128)      { l = 0; lb = b;       ps = p0; ds = d0; E = 131072; dof = 0;     eof_ = 0; }
    else if (b < 160) { l = 1; lb = b - 128; ps = p1; ds = d1; E = 32768;  dof = 16384; eof_ = 131072; }
    else if (b < 168) { l = 2; lb = b - 160; ps = p2; ds = d2; E = 8192;   dof = 20480; eof_ = 163840; }
    else              { l = 3; lb = b - 168; ps = p3; ds = d3; E = 2048;   dof = 21504; eof_ = 172032; }
    int* gc = gcur + l * 64;
    __shared__ int h[64], lbk[64], gb[64], sh[64];
    __shared__ int sp[1024];
    __shared__ unsigned char skk[1024];
    int t = threadIdx.x;
    int ebase = lb * 1024;
    int kbv[4];
    if (t < 64) h[t] = 0;
    __syncthreads();
#pragma unroll
    for (int j = 0; j < 4; ++j) {
        int e = ebase + j * 256 + t;
        if (e < E) {
            kbv[j] = edge_bucket(ps, e);
            atomicAdd(&h[kbv[j]], 1);
            posArr[eof_ + e] = atomicAdd(&cur[dof + ds[e]], 1);
        } else
            kbv[j] = -1;
    }
    __syncthreads();
    if (t < 64) sh[t] = h[t];
    __syncthreads();
    for (int d = 1; d < 64; d <<= 1) {
        int v = (t < 64 && t >= d) ? sh[t - d] : 0;
        __syncthreads();
        if (t < 64) sh[t] += v;
        __syncthreads();
    }
    if (t < 64) {
        int c = h[t];
        lbk[t] = sh[t] - c;
        gb[t] = c ? atomicAdd(&gc[t], c) : 0;
        h[t] = 0;
    }
    __syncthreads();
#pragma unroll
    for (int j = 0; j < 4; ++j) {
        int e = ebase + j * 256 + t;
        if (kbv[j] >= 0) {
            int pos = lbk[kbv[j]] + atomicAdd(&h[kbv[j]], 1);
            sp[pos] = e;
            skk[pos] = (unsigned char)kbv[j];
        }
    }
    __syncthreads();
    int Pb = E - ebase;
    if (Pb > 1024) Pb = 1024;
    for (int j = t; j < Pb; j += 256) {
        int k = skk[j];
        pack[gb[k] + (j - lbk[k])] = sp[j];
    }
}

// ---------------------------------------------------------------------------
// Pre-pass 5: convert W (fp32 [k][i][o]) -> Wt (bf16 [k][o][i]).
// ---------------------------------------------------------------------------
__global__ __launch_bounds__(256) void wcvt_all(
    const float* __restrict__ w12, const float* __restrict__ w2,
    const float* __restrict__ w3, const float* __restrict__ w4,
    const float* __restrict__ w5, const float* __restrict__ w6,
    const float* __restrict__ w7, short* __restrict__ Wt) {
    int idx = blockIdx.x * 256 + threadIdx.x;
    if (idx >= 2944000) return;
    const float* Wsrc;
    int IC, OC, local;
    if (idx < 128000)       { Wsrc = w12; IC = 32; OC = 32; local = idx; }
    else if (idx < 384000)  { Wsrc = w2;  IC = 32; OC = 64; local = idx - 128000; }
    else if (idx < 896000)  { Wsrc = w3;  IC = 64; OC = 64; local = idx - 384000; }
    else if (idx < 1408000) { Wsrc = w4;  IC = 64; OC = 64; local = idx - 896000; }
    else if (idx < 1920000) { Wsrc = w5;  IC = 64; OC = 64; local = idx - 1408000; }
    else if (idx < 2432000) { Wsrc = w6;  IC = 64; OC = 64; local = idx - 1920000; }
    else                    { Wsrc = w7;  IC = 64; OC = 64; local = idx - 2432000; }
    int per = IC * OC;
    int k = local / per;
    int r = local % per;
    int o = r / IC;
    int i = r % IC;
    Wt[idx] = (short)f2bf(Wsrc[(size_t)(k * IC + i) * OC + o]);
}

// ---------------------------------------------------------------------------
// Fused conv1 (in_c = 1): per-edge row to y[pos[e]] (bf16, no atomics).
// ---------------------------------------------------------------------------
__global__ __launch_bounds__(256) void conv1_y(const float* __restrict__ x,
                                               const int* __restrict__ src,
                                               const float* __restrict__ pseudo,
                                               const int* __restrict__ pos,
                                               const float* __restrict__ W,
                                               unsigned short* __restrict__ y, int E) {
    const int lane = threadIdx.x & 63;
    const int wid = threadIdx.x >> 6;
    const int sub = lane >> 5;
    const int o = lane & 31;
    int e = (blockIdx.x * 4 + wid) * 2 + sub;
    if (e >= E) return;
    float bs[8];
    int ks[8];
    edge_basis(pseudo, e, bs, ks);
    float acc = 0.f;
#pragma unroll
    for (int s = 0; s < 8; ++s) acc = fmaf(bs[s], W[ks[s] * 32 + o], acc);
    y[(size_t)pos[e] * 32 + o] = f2bf(acc * x[src[e]]);
}

// ---------------------------------------------------------------------------
// MFMA bucket-tile conv (R14-verified structure); epilogue stores bf16 y.
// ---------------------------------------------------------------------------
template <int IN_C, int OUT_C>
__global__ __launch_bounds__(256) void mfma_conv(
    const float* __restrict__ x, const int* __restrict__ src,
    const float* __restrict__ pseudo, const int* __restrict__ pack,
    const int* __restrict__ tileOf, const int* __restrict__ pos,
    const short* __restrict__ Wt, unsigned short* __restrict__ y, int tileBase) {
    constexpr int K = 8 * IN_C;
    constexpr int KP = K + 8;
    constexpr int NT = OUT_C / 16;
    constexpr int IP = IN_C / 4;
    __shared__ short As[64 * KP];
    __shared__ int posL[64];
    const int tid = threadIdx.x;
    int t = tileBase + blockIdx.x;
    int kb = tileOf[t];
    if (kb < 0) return;
    kb = __builtin_amdgcn_readfirstlane(kb);
    const int kbase = (kb & 3) + 5 * ((kb >> 2) & 3) + 25 * ((kb >> 4) & 3);
    {
        const int eLoc = tid >> 2, part = tid & 3;
        int e = pack[t * 64 + eLoc];
        float bs[8];
        if (e >= 0) edge_fracs(pseudo, e, bs);
        else {
#pragma unroll
            for (int s = 0; s < 8; ++s) bs[s] = 0.f;
        }
        if (part == 0) posL[eLoc] = (e >= 0) ? pos[e] : -1;
        float4 xq[IP / 4];
#pragma unroll
        for (int g = 0; g < IP / 4; ++g)
            xq[g] = (e >= 0)
                        ? *(const float4*)(x + (size_t)src[e] * IN_C + part * IP + g * 4)
                        : make_float4(0.f, 0.f, 0.f, 0.f);
#pragma unroll
        for (int s = 0; s < 8; ++s) {
            const float b = bs[s];
            short* rowp = &As[eLoc * KP + s * IN_C + part * IP];
#pragma unroll
            for (int g = 0; g < IP / 4; ++g) {
                unsigned lo = pack2bf(b * xq[g].x, b * xq[g].y);
                unsigned hi = pack2bf(b * xq[g].z, b * xq[g].w);
                *(uint2*)(rowp + 4 * g) = make_uint2(lo, hi);
            }
        }
    }
    __syncthreads();
    const int wave = tid >> 6, lane = tid & 63;
    const int quad = lane >> 4, lm = lane & 15;
    floatx4 acc[NT];
#pragma unroll
    for (int nt = 0; nt < NT; ++nt) acc[nt] = (floatx4){0.f, 0.f, 0.f, 0.f};
    const short* myrow = &As[(wave * 16 + lm) * KP];
#pragma unroll
    for (int kstep = 0; kstep < K / 32; ++kstep) {
        const int kg = kstep * 32;
        const int s = kg / IN_C;
        const int i0 = kg % IN_C;
        const int ks = kbase + (s & 1) + 5 * ((s >> 1) & 1) + 25 * ((s >> 2) & 1);
        short8 a = *(const short8*)&myrow[kg + quad * 8];
#pragma unroll
        for (int nt = 0; nt < NT; ++nt) {
            const short* bp =
                Wt + ((size_t)ks * OUT_C + nt * 16 + lm) * IN_C + i0 + quad * 8;
            short8 bfr = *(const short8*)bp;
            acc[nt] = __builtin_amdgcn_mfma_f32_16x16x32_bf16(a, bfr, acc[nt], 0, 0, 0);
        }
    }
#pragma unroll
    for (int nt = 0; nt < NT; ++nt) {
#pragma unroll
        for (int r = 0; r < 4; ++r) {
            int row = wave * 16 + quad * 4 + r;
            int p = posL[row];
            if (p >= 0) y[(size_t)p * OUT_C + nt * 16 + lm] = f2bf(acc[nt][r]);
        }
    }
}

// ---------------------------------------------------------------------------
// Finalize (gather): out = (sum of dst's CSR run of bf16 y)/deg + x@R + B, ELU.
// ---------------------------------------------------------------------------
template <int OUT_C>
__device__ inline float csr_sum(const int* __restrict__ off,
                                const unsigned short* __restrict__ y, int j, int o,
                                float& dcount) {
    int b0 = off[j], b1 = off[j + 1];
    dcount = fmaxf((float)(b1 - b0), 1.f);
    float s0 = 0.f, s1 = 0.f, s2 = 0.f, s3 = 0.f;
    int r = b0;
    for (; r + 4 <= b1; r += 4) {
        s0 += bf2f(y[(size_t)(r + 0) * OUT_C + o]);
        s1 += bf2f(y[(size_t)(r + 1) * OUT_C + o]);
        s2 += bf2f(y[(size_t)(r + 2) * OUT_C + o]);
        s3 += bf2f(y[(size_t)(r + 3) * OUT_C + o]);
    }
    for (; r < b1; ++r) s0 += bf2f(y[(size_t)r * OUT_C + o]);
    return (s0 + s1) + (s2 + s3);
}

template <int IN_C, int OUT_C>
__global__ __launch_bounds__(256) void fin_gather_k(
    const float* __restrict__ xin, const float* __restrict__ R,
    const float* __restrict__ B, const int* __restrict__ off,
    const unsigned short* __restrict__ y, float* __restrict__ out, int n) {
    const int lane = threadIdx.x & 63;
    const int wid = threadIdx.x >> 6;
    constexpr int EPW = 64 / OUT_C;
    const int sub = (EPW == 2) ? (lane >> 5) : 0;
    const int o = lane & (OUT_C - 1);
    int j = (blockIdx.x * (blockDim.x >> 6) + wid) * EPW + sub;
    if (j >= n) return;
    float xv = (o < IN_C) ? xin[j * IN_C + o] : 0.f;
    float acc = B[o];
#pragma unroll 4
    for (int i = 0; i < IN_C; ++i) {
        float xi = __shfl(xv, i, OUT_C);
        acc = fmaf(xi, R[i * OUT_C + o], acc);
    }
    float d;
    float s = csr_sum<OUT_C>(off, y, j, o, d);
    float v = s / d + acc;
    out[j * OUT_C + o] = (v > 0.f) ? v : expm1f(v);
}

// ---------------------------------------------------------------------------
// Pool gather-max: every cluster has exactly 4 members (clist).
// ---------------------------------------------------------------------------
template <int OC>
__global__ __launch_bounds__(256) void pool_gather(const float* __restrict__ h,
                                                   const int* __restrict__ clist,
                                                   float* __restrict__ out, int m) {
    int idx = blockIdx.x * 256 + threadIdx.x;
    if (idx >= m * OC) return;
    int c = idx / OC;
    int ch = idx - c * OC;
    const int* mb = &clist[c * 4];
    float v0 = h[(size_t)mb[0] * OC + ch];
    float v1 = h[(size_t)mb[1] * OC + ch];
    float v2 = h[(size_t)mb[2] * OC + ch];
    float v3 = h[(size_t)mb[3] * OC + ch];
    out[idx] = fmaxf(fmaxf(v0, v1), fmaxf(v2, v3));
}

// ---------------------------------------------------------------------------
// Fallback kernels (small-ws path only).
// ---------------------------------------------------------------------------
__global__ __launch_bounds__(256) void conv1_fused(const float* __restrict__ x,
                                                   const int* __restrict__ src,
                                                   const int* __restrict__ dst,
                                                   const float* __restrict__ pseudo,
                                                   const float* __restrict__ W,
                                                   float* __restrict__ out, int E) {
    const int lane = threadIdx.x & 63;
    const int wid = threadIdx.x >> 6;
    const int sub = lane >> 5;
    const int o = lane & 31;
    int e = (blockIdx.x * 4 + wid) * 2 + sub;
    if (e >= E) return;
    float bs[8];
    int ks[8];
    edge_basis(pseudo, e, bs, ks);
    float acc = 0.f;
#pragma unroll
    for (int s = 0; s < 8; ++s) acc = fmaf(bs[s], W[ks[s] * 32 + o], acc);
    atomicAdd(&out[(size_t)dst[e] * 32 + o], acc * x[src[e]]);
}

template <int IN_C, int OUT_C>
__global__ __launch_bounds__(256) void conv_edges_inline(
    const float* __restrict__ x, const int* __restrict__ src,
    const int* __restrict__ dst, const float* __restrict__ pseudo,
    const float* __restrict__ W, float* __restrict__ out, int E) {
    const int lane = threadIdx.x & 63;
    const int wid = threadIdx.x >> 6;
    constexpr int EPW = 64 / OUT_C;
    const int sub = (EPW == 2) ? (lane >> 5) : 0;
    const int o = lane & (OUT_C - 1);
    long e = (long)(blockIdx.x * (blockDim.x >> 6) + wid) * EPW + sub;
    if (e >= E) return;
    float bs[8];
    int ks[8];
    edge_basis(pseudo, e, bs, ks);
    const int s_ = src[e];
    const int d_ = dst[e];
    float xv = (o < IN_C) ? x[s_ * IN_C + o] : 0.f;
    float acc = 0.f;
#pragma unroll
    for (int s = 0; s < 8; ++s) {
        const float b = bs[s];
        const float* Wk = W + (long)ks[s] * IN_C * OUT_C;
#pragma unroll 4
        for (int i = 0; i < IN_C; ++i) {
            float xi = __shfl(xv, i, OUT_C);
            acc = fmaf(b * xi, Wk[i * OUT_C + o], acc);
        }
    }
    atomicAdd(&out[(long)d_ * OUT_C + o], acc);
}

__global__ void deg_kernel(const int* __restrict__ dst, float* __restrict__ deg, int E) {
    int e = blockIdx.x * blockDim.x + threadIdx.x;
    if (e >= E) return;
    atomicAdd(&deg[dst[e]], 1.0f);
}

template <int IN_C, int OUT_C>
__global__ __launch_bounds__(256) void finalize_k(
    const float* __restrict__ xin, const float* __restrict__ R,
    const float* __restrict__ B, const float* __restrict__ deg,
    float* __restrict__ out, int n) {
    const int lane = threadIdx.x & 63;
    const int wid = threadIdx.x >> 6;
    constexpr int EPW = 64 / OUT_C;
    const int sub = (EPW == 2) ? (lane >> 5) : 0;
    const int o = lane & (OUT_C - 1);
    int j = (blockIdx.x * (blockDim.x >> 6) + wid) * EPW + sub;
    if (j >= n) return;
    float xv = (o < IN_C) ? xin[j * IN_C + o] : 0.f;
    float acc = B[o];
#pragma unroll 4
    for (int i = 0; i < IN_C; ++i) {
        float xi = __shfl(xv, i, OUT_C);
        acc = fmaf(xi, R[i * OUT_C + o], acc);
    }
    float d = fmaxf(deg[j], 1.f);
    float v = out[j * OUT_C + o] / d + acc;
    out[j * OUT_C + o] = (v > 0.f) ? v : expm1f(v);
}

__global__ void pool_scatter(const float* __restrict__ h, const int* __restrict__ cluster,
                             unsigned* __restrict__ pool, int n, int logC) {
    int idx = blockIdx.x * blockDim.x + threadIdx.x;
    if (idx >= (n << logC)) return;
    int j = idx >> logC;
    int c = idx & ((1 << logC) - 1);
    atomicMax(&pool[(cluster[j] << logC) + c], enc_f(h[idx]));
}

__global__ void pool_decode(const unsigned* __restrict__ pool, float* __restrict__ out, int total) {
    int idx = blockIdx.x * blockDim.x + threadIdx.x;
    if (idx >= total) return;
    unsigned u = pool[idx];
    int b = (u & 0x80000000u) ? (int)(u & 0x7FFFFFFFu) : (int)(~u);
    out[idx] = __int_as_float(b);
}

// ---------------------------------------------------------------------------
// Head: mean(64x64) -> fc1 -> fc2 -> log_softmax
// ---------------------------------------------------------------------------
__global__ void head_kernel(const float* __restrict__ h, const float* __restrict__ fc1w,
                            const float* __restrict__ fc1b, const float* __restrict__ fc2w,
                            const float* __restrict__ fc2b, float* __restrict__ out) {
    __shared__ float m[64], t[64], u[10];
    int lane = threadIdx.x;
    float s = 0.f;
    for (int j = 0; j < 64; ++j) s += h[j * 64 + lane];
    m[lane] = s * (1.f / 64.f);
    __syncthreads();
    float a = fc1b[lane];
    for (int i = 0; i < 64; ++i) a = fmaf(m[i], fc1w[i * 64 + lane], a);
    t[lane] = a;
    __syncthreads();
    if (lane < 10) {
        float b = fc2b[lane];
        for (int i = 0; i < 64; ++i) b = fmaf(t[i], fc2w[i * 10 + lane], b);
        u[lane] = b;
    }
    __syncthreads();
    if (lane < 10) {
        float mx = u[0];
        for (int i = 1; i < 10; ++i) mx = fmaxf(mx, u[i]);
        float se = 0.f;
        for (int i = 0; i < 10; ++i) se += expf(u[i] - mx);
        out[lane] = u[lane] - mx - logf(se);
    }
}

// ---------------------------------------------------------------------------
// Host side
// ---------------------------------------------------------------------------
static inline int cdiv(int a, int b) { return (a + b - 1) / b; }

extern "C" void kernel_launch(void* const* d_in, const int* in_sizes, int n_in,
                              void* d_out, int out_size, void* d_ws, size_t ws_size,
                              hipStream_t stream) {
    const float* x = (const float*)d_in[0];
    const int* src[4] = {(const int*)d_in[1], (const int*)d_in[5], (const int*)d_in[9], (const int*)d_in[13]};
    const int* dst[4] = {(const int*)d_in[2], (const int*)d_in[6], (const int*)d_in[10], (const int*)d_in[14]};
    const float* pseudo[4] = {(const float*)d_in[3], (const float*)d_in[7], (const float*)d_in[11], (const float*)d_in[15]};
    const int* cluster[4] = {(const int*)d_in[4], (const int*)d_in[8], (const int*)d_in[12], (const int*)d_in[16]};
    const float* Wp[8], *Rp[8], *Bp[8];
    for (int l = 0; l < 8; ++l) {
        Wp[l] = (const float*)d_in[17 + 3 * l];
        Rp[l] = (const float*)d_in[18 + 3 * l];
        Bp[l] = (const float*)d_in[19 + 3 * l];
    }
    const float* fc1w = (const float*)d_in[41];
    const float* fc1b = (const float*)d_in[42];
    const float* fc2w = (const float*)d_in[43];
    const float* fc2b = (const float*)d_in[44];
    float* outp = (float*)d_out;

    const int NS[5] = {16384, 4096, 1024, 256, 64};
    const int ES[4] = {16384 * 8, 4096 * 8, 1024 * 8, 256 * 8};
    const int MT[4] = {2048 + 64, 512 + 64, 128 + 64, 32 + 64};
    const int TB_[4] = {0, 2112, 2112 + 576, 2112 + 576 + 192};
    const int TOT_TILES = 2112 + 576 + 192 + 96;  // 2976
    const int DTOT = 21760;
    const int OFF2[4] = {0, 16385, 20482, 21507};
    const int OFFTOT = 21764;
    const int EBASE[4] = {0, 131072, 163840, 172032};
    const int ETOT = 174080;
    const int NODE_OFF[4] = {0, 16384, 20480, 21504};
    const int CCTOT = 4096 + 1024 + 256 + 64;  // 5440
    const int WT_OFF[7] = {0, 128000, 384000, 896000, 1408000, 1920000, 2432000};
    const int WT_TOT = 2944000;

    char* w = (char*)d_ws;
    auto take = [&](size_t bytes) -> char* {
        char* r = w;
        w += (bytes + 255) & ~(size_t)255;
        return r;
    };
    float* bufA = (float*)take((size_t)NS[0] * 64 * 4);
    float* bufB = (float*)take((size_t)NS[0] * 64 * 4);
    unsigned* pool = (unsigned*)take((size_t)NS[1] * 64 * 4);  // fallback only
    // ---- contiguous zero-init region: hist | ccnt | degi | tileOf ----
    char* zbase = w;
    int* hist = (int*)take((size_t)4 * 64 * 4);
    int* ccnt = (int*)take((size_t)CCTOT * 4);
    int* degi = (int*)take((size_t)DTOT * 4);
    int* tileOf = (int*)take((size_t)TOT_TILES * 4);
    size_t zbytes = (size_t)(w - zbase);
    size_t fallbackNeed = (size_t)(w - (char*)d_ws);
    int* gcur = (int*)take((size_t)4 * 64 * 4);
    int* pack = (int*)take((size_t)TOT_TILES * 64 * 4);
    int* csr = (int*)take((size_t)OFFTOT * 4);
    int* cur = (int*)take((size_t)DTOT * 4);
    int* posArr = (int*)take((size_t)ETOT * 4);
    int* clist = (int*)take((size_t)DTOT * 4);
    short* Wtb = (short*)take((size_t)WT_TOT * 2);
    unsigned short* y = (unsigned short*)take((size_t)ES[0] * 32 * 2);  // 8.4 MB bf16
    size_t need = (size_t)(w - (char*)d_ws);
    bool fast = ws_size >= need;

    const int TB = 256;

    if (fast) {
        // ---------- pre-pass: 1 memset + 5 kernels -------------------------
        (void)hipMemsetAsync(zbase, 0, zbytes, stream);
        hist_deg_clist_all<<<765, 256, 0, stream>>>(
            pseudo[0], pseudo[1], pseudo[2], pseudo[3],
            dst[0], dst[1], dst[2], dst[3],
            cluster[0], cluster[1], cluster[2], cluster[3], hist, degi, ccnt, clist);
        wcvt_all<<<cdiv(WT_TOT, 256), 256, 0, stream>>>(Wp[1], Wp[2], Wp[3], Wp[4],
                                                        Wp[5], Wp[6], Wp[7], Wtb);
        scan_pad_all<<<4, 64, 0, stream>>>(hist, gcur, tileOf, pack);
        csr_scan_all<<<4, 1024, 0, stream>>>(degi, csr, cur);
        scatter_pos_all<<<170, 256, 0, stream>>>(pseudo[0], pseudo[1], pseudo[2], pseudo[3],
                                                 dst[0], dst[1], dst[2], dst[3],
                                                 gcur, cur, pack, posArr);

        // ---------------- Level 0: conv1 (1->32), conv12 (32->32) ----------
        {
            int E = ES[0], n = NS[0];
            const int* off = csr + OFF2[0];
            const int* pos = posArr + EBASE[0];
            conv1_y<<<cdiv(E, 8), TB, 0, stream>>>(x, src[0], pseudo[0], pos, Wp[0], y, E);
            fin_gather_k<1, 32><<<cdiv(n, 8), TB, 0, stream>>>(x, Rp[0], Bp[0], off, y, bufA, n);
            mfma_conv<32, 32><<<MT[0], TB, 0, stream>>>(
                bufA, src[0], pseudo[0], pack, tileOf, pos, Wtb + WT_OFF[0], y, TB_[0]);
            fin_gather_k<32, 32><<<cdiv(n, 8), TB, 0, stream>>>(bufA, Rp[1], Bp[1], off, y, bufB, n);
            pool_gather<32><<<cdiv(NS[1] * 32, 256), 256, 0, stream>>>(
                bufB, clist + NODE_OFF[0], bufA, NS[1]);
        }
        // ---------------- Level 1: conv2 (32->64), conv3 (64->64) ----------
        {
            int n = NS[1];
            const int* off = csr + OFF2[1];
            const int* pos = posArr + EBASE[1];
            mfma_conv<32, 64><<<MT[1], TB, 0, stream>>>(
                bufA, src[1], pseudo[1], pack, tileOf, pos, Wtb + WT_OFF[1], y, TB_[1]);
            fin_gather_k<32, 64><<<cdiv(n, 4), TB, 0, stream>>>(bufA, Rp[2], Bp[2], off, y, bufB, n);
            mfma_conv<64, 64><<<MT[1], TB, 0, stream>>>(
                bufB, src[1], pseudo[1], pack, tileOf, pos, Wtb + WT_OFF[2], y, TB_[1]);
            fin_gather_k<64, 64><<<cdiv(n, 4), TB, 0, stream>>>(bufB, Rp[3], Bp[3], off, y, bufA, n);
            pool_gather<64><<<cdiv(NS[2] * 64, 256), 256, 0, stream>>>(
                bufA, clist + NODE_OFF[1], bufB, NS[2]);
        }
        // ---------------- Level 2: conv4, conv5 (64->64) -------------------
        {
            int n = NS[2];
            const int* off = csr + OFF2[2];
            const int* pos = posArr + EBASE[2];
            mfma_conv<64, 64><<<MT[2], TB, 0, stream>>>(
                bufB, src[2], pseudo[2], pack, tileOf, pos, Wtb + WT_OFF[3], y, TB_[2]);
            fin_gather_k<64, 64><<<cdiv(n, 4), TB, 0, stream>>>(bufB, Rp[4], Bp[4], off, y, bufA, n);
            mfma_conv<64, 64><<<MT[2], TB, 0, stream>>>(
                bufA, src[2], pseudo[2], pack, tileOf, pos, Wtb + WT_OFF[4], y, TB_[2]);
            fin_gather_k<64, 64><<<cdiv(n, 4), TB, 0, stream>>>(bufA, Rp[5], Bp[5], off, y, bufB, n);
            pool_gather<64><<<cdiv(NS[3] * 64, 256), 256, 0, stream>>>(
                bufB, clist + NODE_OFF[2], bufA, NS[3]);
        }
        // ---------------- Level 3: conv6, conv7 (64->64) -------------------
        {
            int n = NS[3];
            const int* off = csr + OFF2[3];
            const int* pos = posArr + EBASE[3];
            mfma_conv<64, 64><<<MT[3], TB, 0, stream>>>(
                bufA, src[3], pseudo[3], pack, tileOf, pos, Wtb + WT_OFF[5], y, TB_[3]);
            fin_gather_k<64, 64><<<cdiv(n, 4), TB, 0, stream>>>(bufA, Rp[6], Bp[6], off, y, bufB, n);
            mfma_conv<64, 64><<<MT[3], TB, 0, stream>>>(
                bufB, src[3], pseudo[3], pack, tileOf, pos, Wtb + WT_OFF[6], y, TB_[3]);
            fin_gather_k<64, 64><<<cdiv(n, 4), TB, 0, stream>>>(bufB, Rp[7], Bp[7], off, y, bufA, n);
            pool_gather<64><<<cdiv(NS[4] * 64, 256), 256, 0, stream>>>(
                bufA, clist + NODE_OFF[3], bufB, NS[4]);
        }
        head_kernel<<<1, 64, 0, stream>>>(bufB, fc1w, fc1b, fc2w, fc2b, outp);
    } else if (ws_size >= fallbackNeed) {
        // ---------------- legacy edge-centric fallback ---------------------
        float* h0 = bufA;
        float* h1 = bufB;
        float* deg = (float*)degi;
        for (int l = 0; l < 4; ++l) {
            int E = ES[l], n = NS[l];
            (void)hipMemsetAsync(deg, 0, n * 4, stream);
            deg_kernel<<<cdiv(E, TB), TB, 0, stream>>>(dst[l], deg, E);
            for (int cc = 0; cc < 2; ++cc) {
                int li = (l == 0) ? cc : 2 * l + cc;
                if (l == 0 && cc == 0) {
                    (void)hipMemsetAsync(h0, 0, (size_t)n * 32 * 4, stream);
                    conv1_fused<<<cdiv(E, 8), TB, 0, stream>>>(x, src[0], dst[0], pseudo[0], Wp[0], h0, E);
                    finalize_k<1, 32><<<cdiv(n, 8), TB, 0, stream>>>(x, Rp[0], Bp[0], deg, h0, n);
                } else {
                    int ic = (l == 0) ? 32 : ((l == 1 && cc == 0) ? 32 : 64);
                    int oc = (l == 0) ? 32 : 64;
                    (void)hipMemsetAsync(h1, 0, (size_t)n * oc * 4, stream);
                    if (ic == 32 && oc == 32) {
                        conv_edges_inline<32, 32><<<cdiv(E, 8), TB, 0, stream>>>(h0, src[l], dst[l], pseudo[l], Wp[li], h1, E);
                        finalize_k<32, 32><<<cdiv(n, 8), TB, 0, stream>>>(h0, Rp[li], Bp[li], deg, h1, n);
                    } else if (ic == 32) {
                        conv_edges_inline<32, 64><<<cdiv(E, 4), TB, 0, stream>>>(h0, src[l], dst[l], pseudo[l], Wp[li], h1, E);
                        finalize_k<32, 64><<<cdiv(n, 4), TB, 0, stream>>>(h0, Rp[li], Bp[li], deg, h1, n);
                    } else {
                        conv_edges_inline<64, 64><<<cdiv(E, 4), TB, 0, stream>>>(h0, src[l], dst[l], pseudo[l], Wp[li], h1, E);
                        finalize_k<64, 64><<<cdiv(n, 4), TB, 0, stream>>>(h0, Rp[li], Bp[li], deg, h1, n);
                    }
                    float* tmp = h0; h0 = h1; h1 = tmp;
                }
            }
            int oc = (l == 0) ? 32 : 64;
            int logC = (l == 0) ? 5 : 6;
            (void)hipMemsetAsync(pool, 0, (size_t)NS[l + 1] * oc * 4, stream);
            pool_scatter<<<cdiv(n * oc, TB), TB, 0, stream>>>(h0, cluster[l], pool, n, logC);
            pool_decode<<<cdiv(NS[l + 1] * oc, TB), TB, 0, stream>>>(pool, h1, NS[l + 1] * oc);
            float* tmp = h0; h0 = h1; h1 = tmp;
        }
        head_kernel<<<1, 64, 0, stream>>>(h0, fc1w, fc1b, fc2w, fc2b, outp);
    }
}

// Round 17
// 421.310 us; speedup vs baseline: 1.5820x; 1.0153x over previous
//
#include <hip/hip_runtime.h>
#include <hip/hip_bf16.h>

#define KS 5
#define K3 125

typedef __attribute__((ext_vector_type(8))) short short8;
typedef __attribute__((ext_vector_type(4))) float floatx4;

__device__ inline unsigned enc_f(float f) {
    int b = __float_as_int(f);
    return (b >= 0) ? ((unsigned)b | 0x80000000u) : ~((unsigned)b);
}

__device__ inline unsigned short f2bf(float f) {
    unsigned u = __float_as_uint(f);
    u += 0x7FFFu + ((u >> 16) & 1u);  // RNE
    return (unsigned short)(u >> 16);
}
__device__ inline float bf2f(unsigned short h) {
    return __uint_as_float((unsigned)h << 16);
}
__device__ inline unsigned pack2bf(float a, float b) {
    return (unsigned)f2bf(a) | ((unsigned)f2bf(b) << 16);
}

// ---------------------------------------------------------------------------
// Inline basis helpers
// ---------------------------------------------------------------------------
__device__ inline void edge_basis(const float* __restrict__ pseudo, int e,
                                  float* bs, int* ks) {
    float fr[3];
    int bot[3];
#pragma unroll
    for (int d = 0; d < 3; ++d) {
        float v = pseudo[e * 3 + d] * (float)(KS - 1);
        float fl = fminf(floorf(v), (float)(KS - 2));
        fr[d] = v - fl;
        bot[d] = (int)fl;
    }
    const int strides[3] = {1, KS, KS * KS};
#pragma unroll
    for (int s = 0; s < 8; ++s) {
        float b = 1.f;
        int w = 0;
#pragma unroll
        for (int d = 0; d < 3; ++d) {
            int bit = (s >> d) & 1;
            b *= bit ? fr[d] : (1.f - fr[d]);
            w += (bot[d] + bit) * strides[d];
        }
        bs[s] = b;
        ks[s] = w;
    }
}

__device__ inline void edge_fracs(const float* __restrict__ pseudo, int e, float* bs) {
    float fr[3];
#pragma unroll
    for (int d = 0; d < 3; ++d) {
        float v = pseudo[e * 3 + d] * (float)(KS - 1);
        float fl = fminf(floorf(v), (float)(KS - 2));
        fr[d] = v - fl;
    }
#pragma unroll
    for (int s = 0; s < 8; ++s) {
        float b = 1.f;
#pragma unroll
        for (int d = 0; d < 3; ++d) b *= ((s >> d) & 1) ? fr[d] : (1.f - fr[d]);
        bs[s] = b;
    }
}

__device__ inline int edge_bucket(const float* __restrict__ pseudo, int e) {
    int kb = 0;
#pragma unroll
    for (int d = 0; d < 3; ++d) {
        float v = pseudo[e * 3 + d] * (float)(KS - 1);
        int fl = (int)fminf(floorf(v), (float)(KS - 2));
        kb += fl << (2 * d);
    }
    return kb;
}

// ---------------------------------------------------------------------------
// Pre-pass 1 (merged): 64-bucket histogram + int degree (blocks 0..679)
// + cluster member lists (blocks 680..764; every cluster has 4 members).
// ---------------------------------------------------------------------------
__global__ __launch_bounds__(256) void hist_deg_clist_all(
    const float* __restrict__ p0, const float* __restrict__ p1,
    const float* __restrict__ p2, const float* __restrict__ p3,
    const int* __restrict__ d0, const int* __restrict__ d1,
    const int* __restrict__ d2, const int* __restrict__ d3,
    const int* __restrict__ c0, const int* __restrict__ c1,
    const int* __restrict__ c2, const int* __restrict__ c3,
    int* __restrict__ hist, int* __restrict__ degi,
    int* __restrict__ ccnt, int* __restrict__ clist) {
    int b = blockIdx.x;
    if (b >= 680) {  // ---- clist part ----
        int idx = (b - 680) * 256 + threadIdx.x;
        int j, cof, nof;
        const int* cl;
        if (idx < 16384)      { j = idx;         cl = c0; cof = 0;    nof = 0; }
        else if (idx < 20480) { j = idx - 16384; cl = c1; cof = 4096; nof = 16384; }
        else if (idx < 21504) { j = idx - 20480; cl = c2; cof = 5120; nof = 20480; }
        else if (idx < 21760) { j = idx - 21504; cl = c3; cof = 5376; nof = 21504; }
        else return;
        int c = cl[j];
        int slot = atomicAdd(&ccnt[cof + c], 1);
        clist[nof + c * 4 + slot] = j;
        return;
    }
    int l, lb, E, dof;
    const float* ps;
    const int* ds;
    if (b < 512)      { l = 0; lb = b;       ps = p0; ds = d0; E = 131072; dof = 0; }
    else if (b < 640) { l = 1; lb = b - 512; ps = p1; ds = d1; E = 32768;  dof = 16384; }
    else if (b < 672) { l = 2; lb = b - 640; ps = p2; ds = d2; E = 8192;   dof = 20480; }
    else              { l = 3; lb = b - 672; ps = p3; ds = d3; E = 2048;   dof = 21504; }
    __shared__ int h[64];
    int t = threadIdx.x;
    if (t < 64) h[t] = 0;
    __syncthreads();
    int e = lb * 256 + t;
    if (e < E) {
        atomicAdd(&h[edge_bucket(ps, e)], 1);
        atomicAdd(&degi[dof + ds[e]], 1);
    }
    __syncthreads();
    if (t < 64 && h[t]) atomicAdd(&hist[l * 64 + t], h[t]);
}

// ---------------------------------------------------------------------------
// Pre-pass 2: bucket layout per level (blockIdx = level).
// ---------------------------------------------------------------------------
__global__ void scan_pad_all(const int* __restrict__ hist, int* __restrict__ gcur,
                             int* __restrict__ tileOf, int* __restrict__ pack) {
    const int TBv[4] = {0, 2112, 2112 + 576, 2112 + 576 + 192};
    int l = blockIdx.x;
    int tileBase = TBv[l];
    __shared__ int sh[64];
    int t = threadIdx.x;
    int cnt = hist[l * 64 + t];
    int tiles = (cnt + 63) >> 6;
    sh[t] = tiles;
    __syncthreads();
    for (int d = 1; d < 64; d <<= 1) {
        int v = (t >= d) ? sh[t - d] : 0;
        __syncthreads();
        sh[t] += v;
        __syncthreads();
    }
    int tb = tileBase + sh[t] - tiles;
    int eb = tb * 64;
    gcur[l * 64 + t] = eb;
    for (int q = 0; q < tiles; ++q) tileOf[tb + q] = t;
    for (int idx = eb + cnt; idx < eb + tiles * 64; ++idx) pack[idx] = -1;
}

// ---------------------------------------------------------------------------
// Pre-pass 2b: per-level dst-CSR offsets from degi.
// ---------------------------------------------------------------------------
__global__ __launch_bounds__(1024) void csr_scan_all(const int* __restrict__ degi,
                                                     int* __restrict__ off,
                                                     int* __restrict__ cur) {
    const int Nv[4] = {16384, 4096, 1024, 256};
    const int DOFv[4] = {0, 16384, 20480, 21504};
    const int OFFv[4] = {0, 16385, 20482, 21507};
    int l = blockIdx.x;
    int n = Nv[l];
    const int* d = degi + DOFv[l];
    int* o = off + OFFv[l];
    int* c = cur + DOFv[l];
    __shared__ int ls[1024];
    int t = threadIdx.x;
    int per = (n + 1023) >> 10;
    int beg = t * per;
    int end = (beg + per < n) ? beg + per : n;
    int s = 0;
    for (int j = beg; j < end; ++j) s += d[j];
    ls[t] = s;
    __syncthreads();
    for (int dd = 1; dd < 1024; dd <<= 1) {
        int v = (t >= dd) ? ls[t - dd] : 0;
        __syncthreads();
        ls[t] += v;
        __syncthreads();
    }
    int base = (t == 0) ? 0 : ls[t - 1];
    for (int j = beg; j < end; ++j) {
        o[j] = base;
        c[j] = base;
        base += d[j];
    }
    if (t == 1023) o[n] = ls[1023];
}

// ---------------------------------------------------------------------------
// Pre-pass 3 (merged): counting sort of edges by cube bucket + pos[e].
// ---------------------------------------------------------------------------
__global__ __launch_bounds__(256) void scatter_pos_all(
    const float* __restrict__ p0, const float* __restrict__ p1,
    const float* __restrict__ p2, const float* __restrict__ p3,
    const int* __restrict__ d0, const int* __restrict__ d1,
    const int* __restrict__ d2, const int* __restrict__ d3,
    int* __restrict__ gcur, int* __restrict__ cur,
    int* __restrict__ pack, int* __restrict__ posArr) {
    int b = blockIdx.x;
    int l, lb, E, dof, eof_;
    const float* ps;
    const int* ds;
    if (b < 128)      { l = 0; lb = b;       ps = p0; ds = d0; E = 131072; dof = 0;     eof_ = 0; }
    else if (b < 160) { l = 1; lb = b - 128; ps = p1; ds = d1; E = 32768;  dof = 16384; eof_ = 131072; }
    else if (b < 168) { l = 2; lb = b - 160; ps = p2; ds = d2; E = 8192;   dof = 20480; eof_ = 163840; }
    else              { l = 3; lb = b - 168; ps = p3; ds = d3; E = 2048;   dof = 21504; eof_ = 172032; }
    int* gc = gcur + l * 64;
    __shared__ int h[64], lbk[64], gb[64], sh[64];
    __shared__ int sp[1024];
    __shared__ unsigned char skk[1024];
    int t = threadIdx.x;
    int ebase = lb * 1024;
    int kbv[4];
    if (t < 64) h[t] = 0;
    __syncthreads();
#pragma unroll
    for (int j = 0; j < 4; ++j) {
        int e = ebase + j * 256 + t;
        if (e < E) {
            kbv[j] = edge_bucket(ps, e);
            atomicAdd(&h[kbv[j]], 1);
            posArr[eof_ + e] = atomicAdd(&cur[dof + ds[e]], 1);
        } else
            kbv[j] = -1;
    }
    __syncthreads();
    if (t < 64) sh[t] = h[t];
    __syncthreads();
    for (int d = 1; d < 64; d <<= 1) {
        int v = (t < 64 && t >= d) ? sh[t - d] : 0;
        __syncthreads();
        if (t < 64) sh[t] += v;
        __syncthreads();
    }
    if (t < 64) {
        int c = h[t];
        lbk[t] = sh[t] - c;
        gb[t] = c ? atomicAdd(&gc[t], c) : 0;
        h[t] = 0;
    }
    __syncthreads();
#pragma unroll
    for (int j = 0; j < 4; ++j) {
        int e = ebase + j * 256 + t;
        if (kbv[j] >= 0) {
            int pos = lbk[kbv[j]] + atomicAdd(&h[kbv[j]], 1);
            sp[pos] = e;
            skk[pos] = (unsigned char)kbv[j];
        }
    }
    __syncthreads();
    int Pb = E - ebase;
    if (Pb > 1024) Pb = 1024;
    for (int j = t; j < Pb; j += 256) {
        int k = skk[j];
        pack[gb[k] + (j - lbk[k])] = sp[j];
    }
}

// ---------------------------------------------------------------------------
// Pre-pass 5: convert W (fp32 [k][i][o]) -> Wt (bf16 [k][o][i]).
// ---------------------------------------------------------------------------
__global__ __launch_bounds__(256) void wcvt_all(
    const float* __restrict__ w12, const float* __restrict__ w2,
    const float* __restrict__ w3, const float* __restrict__ w4,
    const float* __restrict__ w5, const float* __restrict__ w6,
    const float* __restrict__ w7, short* __restrict__ Wt) {
    int idx = blockIdx.x * 256 + threadIdx.x;
    if (idx >= 2944000) return;
    const float* Wsrc;
    int IC, OC, local;
    if (idx < 128000)       { Wsrc = w12; IC = 32; OC = 32; local = idx; }
    else if (idx < 384000)  { Wsrc = w2;  IC = 32; OC = 64; local = idx - 128000; }
    else if (idx < 896000)  { Wsrc = w3;  IC = 64; OC = 64; local = idx - 384000; }
    else if (idx < 1408000) { Wsrc = w4;  IC = 64; OC = 64; local = idx - 896000; }
    else if (idx < 1920000) { Wsrc = w5;  IC = 64; OC = 64; local = idx - 1408000; }
    else if (idx < 2432000) { Wsrc = w6;  IC = 64; OC = 64; local = idx - 1920000; }
    else                    { Wsrc = w7;  IC = 64; OC = 64; local = idx - 2432000; }
    int per = IC * OC;
    int k = local / per;
    int r = local % per;
    int o = r / IC;
    int i = r % IC;
    Wt[idx] = (short)f2bf(Wsrc[(size_t)(k * IC + i) * OC + o]);
}

// ---------------------------------------------------------------------------
// Fused conv1 (in_c = 1): per-edge row to y[pos[e]] (bf16, no atomics).
// ---------------------------------------------------------------------------
__global__ __launch_bounds__(256) void conv1_y(const float* __restrict__ x,
                                               const int* __restrict__ src,
                                               const float* __restrict__ pseudo,
                                               const int* __restrict__ pos,
                                               const float* __restrict__ W,
                                               unsigned short* __restrict__ y, int E) {
    const int lane = threadIdx.x & 63;
    const int wid = threadIdx.x >> 6;
    const int sub = lane >> 5;
    const int o = lane & 31;
    int e = (blockIdx.x * 4 + wid) * 2 + sub;
    if (e >= E) return;
    float bs[8];
    int ks[8];
    edge_basis(pseudo, e, bs, ks);
    float acc = 0.f;
#pragma unroll
    for (int s = 0; s < 8; ++s) acc = fmaf(bs[s], W[ks[s] * 32 + o], acc);
    y[(size_t)pos[e] * 32 + o] = f2bf(acc * x[src[e]]);
}

// ---------------------------------------------------------------------------
// MFMA bucket-tile conv, phased staging. For IN_C=64 the A-tile (64x512 bf16
// = 66 KB) capped residency at 2 blocks/CU (R16: Occupancy 11%, MfmaUtil 2%).
// Split K into PH phases: stage 8/PH slots, MFMA, re-stage. LDS -> 33.8 KB,
// 4 blocks/CU, 2x latency hiding. bs/xq persist in registers across phases.
// ---------------------------------------------------------------------------
template <int IN_C, int OUT_C>
__global__ __launch_bounds__(256, 4) void mfma_conv(
    const float* __restrict__ x, const int* __restrict__ src,
    const float* __restrict__ pseudo, const int* __restrict__ pack,
    const int* __restrict__ tileOf, const int* __restrict__ pos,
    const short* __restrict__ Wt, unsigned short* __restrict__ y, int tileBase) {
    constexpr int PH = (IN_C == 64) ? 2 : 1;  // staging phases
    constexpr int SPP = 8 / PH;               // slots per phase
    constexpr int KPH = SPP * IN_C;           // K per phase
    constexpr int KP = KPH + 8;               // padded row (shorts)
    constexpr int NT = OUT_C / 16;
    constexpr int IP = IN_C / 4;
    __shared__ short As[64 * KP];
    __shared__ int posL[64];
    const int tid = threadIdx.x;
    int t = tileBase + blockIdx.x;
    int kb = tileOf[t];
    if (kb < 0) return;
    kb = __builtin_amdgcn_readfirstlane(kb);
    const int kbase = (kb & 3) + 5 * ((kb >> 2) & 3) + 25 * ((kb >> 4) & 3);
    // per-thread staging context (persists across phases)
    const int eLoc = tid >> 2, part = tid & 3;
    int e = pack[t * 64 + eLoc];
    float bs[8];
    float4 xq[IP / 4];
    if (e >= 0) edge_fracs(pseudo, e, bs);
    else {
#pragma unroll
        for (int s = 0; s < 8; ++s) bs[s] = 0.f;
    }
    if (part == 0) posL[eLoc] = (e >= 0) ? pos[e] : -1;
#pragma unroll
    for (int g = 0; g < IP / 4; ++g)
        xq[g] = (e >= 0)
                    ? *(const float4*)(x + (size_t)src[e] * IN_C + part * IP + g * 4)
                    : make_float4(0.f, 0.f, 0.f, 0.f);
    const int wave = tid >> 6, lane = tid & 63;
    const int quad = lane >> 4, lm = lane & 15;
    floatx4 acc[NT];
#pragma unroll
    for (int nt = 0; nt < NT; ++nt) acc[nt] = (floatx4){0.f, 0.f, 0.f, 0.f};
    const short* myrow = &As[(wave * 16 + lm) * KP];
#pragma unroll
    for (int ph = 0; ph < PH; ++ph) {
        if (ph) __syncthreads();  // drain previous phase's MFMA reads
        // ---- stage slots [ph*SPP, ph*SPP+SPP) ----
#pragma unroll
        for (int s2 = 0; s2 < SPP; ++s2) {
            const float b = bs[ph * SPP + s2];
            short* rowp = &As[eLoc * KP + s2 * IN_C + part * IP];
#pragma unroll
            for (int g = 0; g < IP / 4; ++g) {
                unsigned lo = pack2bf(b * xq[g].x, b * xq[g].y);
                unsigned hi = pack2bf(b * xq[g].z, b * xq[g].w);
                *(uint2*)(rowp + 4 * g) = make_uint2(lo, hi);
            }
        }
        __syncthreads();
        // ---- MFMA over this phase's K ----
#pragma unroll
        for (int kstep = 0; kstep < KPH / 32; ++kstep) {
            const int kg = kstep * 32;
            const int s2 = kg / IN_C;
            const int i0 = kg % IN_C;
            const int s = ph * SPP + s2;
            const int ks = kbase + (s & 1) + 5 * ((s >> 1) & 1) + 25 * ((s >> 2) & 1);
            short8 a = *(const short8*)&myrow[kg + quad * 8];
#pragma unroll
            for (int nt = 0; nt < NT; ++nt) {
                const short* bp =
                    Wt + ((size_t)ks * OUT_C + nt * 16 + lm) * IN_C + i0 + quad * 8;
                short8 bfr = *(const short8*)bp;
                acc[nt] = __builtin_amdgcn_mfma_f32_16x16x32_bf16(a, bfr, acc[nt], 0, 0, 0);
            }
        }
    }
#pragma unroll
    for (int nt = 0; nt < NT; ++nt) {
#pragma unroll
        for (int r = 0; r < 4; ++r) {
            int row = wave * 16 + quad * 4 + r;
            int p = posL[row];
            if (p >= 0) y[(size_t)p * OUT_C + nt * 16 + lm] = f2bf(acc[nt][r]);
        }
    }
}

// ---------------------------------------------------------------------------
// Finalize (gather): out = (sum of dst's CSR run of bf16 y)/deg + x@R + B, ELU.
// ---------------------------------------------------------------------------
template <int OUT_C>
__device__ inline float csr_sum(const int* __restrict__ off,
                                const unsigned short* __restrict__ y, int j, int o,
                                float& dcount) {
    int b0 = off[j], b1 = off[j + 1];
    dcount = fmaxf((float)(b1 - b0), 1.f);
    float s0 = 0.f, s1 = 0.f, s2 = 0.f, s3 = 0.f;
    int r = b0;
    for (; r + 4 <= b1; r += 4) {
        s0 += bf2f(y[(size_t)(r + 0) * OUT_C + o]);
        s1 += bf2f(y[(size_t)(r + 1) * OUT_C + o]);
        s2 += bf2f(y[(size_t)(r + 2) * OUT_C + o]);
        s3 += bf2f(y[(size_t)(r + 3) * OUT_C + o]);
    }
    for (; r < b1; ++r) s0 += bf2f(y[(size_t)r * OUT_C + o]);
    return (s0 + s1) + (s2 + s3);
}

template <int IN_C, int OUT_C>
__global__ __launch_bounds__(256) void fin_gather_k(
    const float* __restrict__ xin, const float* __restrict__ R,
    const float* __restrict__ B, const int* __restrict__ off,
    const unsigned short* __restrict__ y, float* __restrict__ out, int n) {
    const int lane = threadIdx.x & 63;
    const int wid = threadIdx.x >> 6;
    constexpr int EPW = 64 / OUT_C;
    const int sub = (EPW == 2) ? (lane >> 5) : 0;
    const int o = lane & (OUT_C - 1);
    int j = (blockIdx.x * (blockDim.x >> 6) + wid) * EPW + sub;
    if (j >= n) return;
    float xv = (o < IN_C) ? xin[j * IN_C + o] : 0.f;
    float acc = B[o];
#pragma unroll 4
    for (int i = 0; i < IN_C; ++i) {
        float xi = __shfl(xv, i, OUT_C);
        acc = fmaf(xi, R[i * OUT_C + o], acc);
    }
    float d;
    float s = csr_sum<OUT_C>(off, y, j, o, d);
    float v = s / d + acc;
    out[j * OUT_C + o] = (v > 0.f) ? v : expm1f(v);
}

// ---------------------------------------------------------------------------
// Pool gather-max: every cluster has exactly 4 members (clist).
// ---------------------------------------------------------------------------
template <int OC>
__global__ __launch_bounds__(256) void pool_gather(const float* __restrict__ h,
                                                   const int* __restrict__ clist,
                                                   float* __restrict__ out, int m) {
    int idx = blockIdx.x * 256 + threadIdx.x;
    if (idx >= m * OC) return;
    int c = idx / OC;
    int ch = idx - c * OC;
    const int* mb = &clist[c * 4];
    float v0 = h[(size_t)mb[0] * OC + ch];
    float v1 = h[(size_t)mb[1] * OC + ch];
    float v2 = h[(size_t)mb[2] * OC + ch];
    float v3 = h[(size_t)mb[3] * OC + ch];
    out[idx] = fmaxf(fmaxf(v0, v1), fmaxf(v2, v3));
}

// ---------------------------------------------------------------------------
// Fallback kernels (small-ws path only).
// ---------------------------------------------------------------------------
__global__ __launch_bounds__(256) void conv1_fused(const float* __restrict__ x,
                                                   const int* __restrict__ src,
                                                   const int* __restrict__ dst,
                                                   const float* __restrict__ pseudo,
                                                   const float* __restrict__ W,
                                                   float* __restrict__ out, int E) {
    const int lane = threadIdx.x & 63;
    const int wid = threadIdx.x >> 6;
    const int sub = lane >> 5;
    const int o = lane & 31;
    int e = (blockIdx.x * 4 + wid) * 2 + sub;
    if (e >= E) return;
    float bs[8];
    int ks[8];
    edge_basis(pseudo, e, bs, ks);
    float acc = 0.f;
#pragma unroll
    for (int s = 0; s < 8; ++s) acc = fmaf(bs[s], W[ks[s] * 32 + o], acc);
    atomicAdd(&out[(size_t)dst[e] * 32 + o], acc * x[src[e]]);
}

template <int IN_C, int OUT_C>
__global__ __launch_bounds__(256) void conv_edges_inline(
    const float* __restrict__ x, const int* __restrict__ src,
    const int* __restrict__ dst, const float* __restrict__ pseudo,
    const float* __restrict__ W, float* __restrict__ out, int E) {
    const int lane = threadIdx.x & 63;
    const int wid = threadIdx.x >> 6;
    constexpr int EPW = 64 / OUT_C;
    const int sub = (EPW == 2) ? (lane >> 5) : 0;
    const int o = lane & (OUT_C - 1);
    long e = (long)(blockIdx.x * (blockDim.x >> 6) + wid) * EPW + sub;
    if (e >= E) return;
    float bs[8];
    int ks[8];
    edge_basis(pseudo, e, bs, ks);
    const int s_ = src[e];
    const int d_ = dst[e];
    float xv = (o < IN_C) ? x[s_ * IN_C + o] : 0.f;
    float acc = 0.f;
#pragma unroll
    for (int s = 0; s < 8; ++s) {
        const float b = bs[s];
        const float* Wk = W + (long)ks[s] * IN_C * OUT_C;
#pragma unroll 4
        for (int i = 0; i < IN_C; ++i) {
            float xi = __shfl(xv, i, OUT_C);
            acc = fmaf(b * xi, Wk[i * OUT_C + o], acc);
        }
    }
    atomicAdd(&out[(long)d_ * OUT_C + o], acc);
}

__global__ void deg_kernel(const int* __restrict__ dst, float* __restrict__ deg, int E) {
    int e = blockIdx.x * blockDim.x + threadIdx.x;
    if (e >= E) return;
    atomicAdd(&deg[dst[e]], 1.0f);
}

template <int IN_C, int OUT_C>
__global__ __launch_bounds__(256) void finalize_k(
    const float* __restrict__ xin, const float* __restrict__ R,
    const float* __restrict__ B, const float* __restrict__ deg,
    float* __restrict__ out, int n) {
    const int lane = threadIdx.x & 63;
    const int wid = threadIdx.x >> 6;
    constexpr int EPW = 64 / OUT_C;
    const int sub = (EPW == 2) ? (lane >> 5) : 0;
    const int o = lane & (OUT_C - 1);
    int j = (blockIdx.x * (blockDim.x >> 6) + wid) * EPW + sub;
    if (j >= n) return;
    float xv = (o < IN_C) ? xin[j * IN_C + o] : 0.f;
    float acc = B[o];
#pragma unroll 4
    for (int i = 0; i < IN_C; ++i) {
        float xi = __shfl(xv, i, OUT_C);
        acc = fmaf(xi, R[i * OUT_C + o], acc);
    }
    float d = fmaxf(deg[j], 1.f);
    float v = out[j * OUT_C + o] / d + acc;
    out[j * OUT_C + o] = (v > 0.f) ? v : expm1f(v);
}

__global__ void pool_scatter(const float* __restrict__ h, const int* __restrict__ cluster,
                             unsigned* __restrict__ pool, int n, int logC) {
    int idx = blockIdx.x * blockDim.x + threadIdx.x;
    if (idx >= (n << logC)) return;
    int j = idx >> logC;
    int c = idx & ((1 << logC) - 1);
    atomicMax(&pool[(cluster[j] << logC) + c], enc_f(h[idx]));
}

__global__ void pool_decode(const unsigned* __restrict__ pool, float* __restrict__ out, int total) {
    int idx = blockIdx.x * blockDim.x + threadIdx.x;
    if (idx >= total) return;
    unsigned u = pool[idx];
    int b = (u & 0x80000000u) ? (int)(u & 0x7FFFFFFFu) : (int)(~u);
    out[idx] = __int_as_float(b);
}

// ---------------------------------------------------------------------------
// Head: mean(64x64) -> fc1 -> fc2 -> log_softmax
// ---------------------------------------------------------------------------
__global__ void head_kernel(const float* __restrict__ h, const float* __restrict__ fc1w,
                            const float* __restrict__ fc1b, const float* __restrict__ fc2w,
                            const float* __restrict__ fc2b, float* __restrict__ out) {
    __shared__ float m[64], t[64], u[10];
    int lane = threadIdx.x;
    float s = 0.f;
    for (int j = 0; j < 64; ++j) s += h[j * 64 + lane];
    m[lane] = s * (1.f / 64.f);
    __syncthreads();
    float a = fc1b[lane];
    for (int i = 0; i < 64; ++i) a = fmaf(m[i], fc1w[i * 64 + lane], a);
    t[lane] = a;
    __syncthreads();
    if (lane < 10) {
        float b = fc2b[lane];
        for (int i = 0; i < 64; ++i) b = fmaf(t[i], fc2w[i * 10 + lane], b);
        u[lane] = b;
    }
    __syncthreads();
    if (lane < 10) {
        float mx = u[0];
        for (int i = 1; i < 10; ++i) mx = fmaxf(mx, u[i]);
        float se = 0.f;
        for (int i = 0; i < 10; ++i) se += expf(u[i] - mx);
        out[lane] = u[lane] - mx - logf(se);
    }
}

// ---------------------------------------------------------------------------
// Host side
// ---------------------------------------------------------------------------
static inline int cdiv(int a, int b) { return (a + b - 1) / b; }

extern "C" void kernel_launch(void* const* d_in, const int* in_sizes, int n_in,
                              void* d_out, int out_size, void* d_ws, size_t ws_size,
                              hipStream_t stream) {
    const float* x = (const float*)d_in[0];
    const int* src[4] = {(const int*)d_in[1], (const int*)d_in[5], (const int*)d_in[9], (const int*)d_in[13]};
    const int* dst[4] = {(const int*)d_in[2], (const int*)d_in[6], (const int*)d_in[10], (const int*)d_in[14]};
    const float* pseudo[4] = {(const float*)d_in[3], (const float*)d_in[7], (const float*)d_in[11], (const float*)d_in[15]};
    const int* cluster[4] = {(const int*)d_in[4], (const int*)d_in[8], (const int*)d_in[12], (const int*)d_in[16]};
    const float* Wp[8], *Rp[8], *Bp[8];
    for (int l = 0; l < 8; ++l) {
        Wp[l] = (const float*)d_in[17 + 3 * l];
        Rp[l] = (const float*)d_in[18 + 3 * l];
        Bp[l] = (const float*)d_in[19 + 3 * l];
    }
    const float* fc1w = (const float*)d_in[41];
    const float* fc1b = (const float*)d_in[42];
    const float* fc2w = (const float*)d_in[43];
    const float* fc2b = (const float*)d_in[44];
    float* outp = (float*)d_out;

    const int NS[5] = {16384, 4096, 1024, 256, 64};
    const int ES[4] = {16384 * 8, 4096 * 8, 1024 * 8, 256 * 8};
    const int MT[4] = {2048 + 64, 512 + 64, 128 + 64, 32 + 64};
    const int TB_[4] = {0, 2112, 2112 + 576, 2112 + 576 + 192};
    const int TOT_TILES = 2112 + 576 + 192 + 96;  // 2976
    const int DTOT = 21760;
    const int OFF2[4] = {0, 16385, 20482, 21507};
    const int OFFTOT = 21764;
    const int EBASE[4] = {0, 131072, 163840, 172032};
    const int ETOT = 174080;
    const int NODE_OFF[4] = {0, 16384, 20480, 21504};
    const int CCTOT = 4096 + 1024 + 256 + 64;  // 5440
    const int WT_OFF[7] = {0, 128000, 384000, 896000, 1408000, 1920000, 2432000};
    const int WT_TOT = 2944000;

    char* w = (char*)d_ws;
    auto take = [&](size_t bytes) -> char* {
        char* r = w;
        w += (bytes + 255) & ~(size_t)255;
        return r;
    };
    float* bufA = (float*)take((size_t)NS[0] * 64 * 4);
    float* bufB = (float*)take((size_t)NS[0] * 64 * 4);
    unsigned* pool = (unsigned*)take((size_t)NS[1] * 64 * 4);  // fallback only
    // ---- contiguous zero-init region: hist | ccnt | degi | tileOf ----
    char* zbase = w;
    int* hist = (int*)take((size_t)4 * 64 * 4);
    int* ccnt = (int*)take((size_t)CCTOT * 4);
    int* degi = (int*)take((size_t)DTOT * 4);
    int* tileOf = (int*)take((size_t)TOT_TILES * 4);
    size_t zbytes = (size_t)(w - zbase);
    size_t fallbackNeed = (size_t)(w - (char*)d_ws);
    int* gcur = (int*)take((size_t)4 * 64 * 4);
    int* pack = (int*)take((size_t)TOT_TILES * 64 * 4);
    int* csr = (int*)take((size_t)OFFTOT * 4);
    int* cur = (int*)take((size_t)DTOT * 4);
    int* posArr = (int*)take((size_t)ETOT * 4);
    int* clist = (int*)take((size_t)DTOT * 4);
    short* Wtb = (short*)take((size_t)WT_TOT * 2);
    unsigned short* y = (unsigned short*)take((size_t)ES[0] * 32 * 2);  // 8.4 MB bf16
    size_t need = (size_t)(w - (char*)d_ws);
    bool fast = ws_size >= need;

    const int TB = 256;

    if (fast) {
        // ---------- pre-pass: 1 memset + 5 kernels -------------------------
        (void)hipMemsetAsync(zbase, 0, zbytes, stream);
        hist_deg_clist_all<<<765, 256, 0, stream>>>(
            pseudo[0], pseudo[1], pseudo[2], pseudo[3],
            dst[0], dst[1], dst[2], dst[3],
            cluster[0], cluster[1], cluster[2], cluster[3], hist, degi, ccnt, clist);
        wcvt_all<<<cdiv(WT_TOT, 256), 256, 0, stream>>>(Wp[1], Wp[2], Wp[3], Wp[4],
                                                        Wp[5], Wp[6], Wp[7], Wtb);
        scan_pad_all<<<4, 64, 0, stream>>>(hist, gcur, tileOf, pack);
        csr_scan_all<<<4, 1024, 0, stream>>>(degi, csr, cur);
        scatter_pos_all<<<170, 256, 0, stream>>>(pseudo[0], pseudo[1], pseudo[2], pseudo[3],
                                                 dst[0], dst[1], dst[2], dst[3],
                                                 gcur, cur, pack, posArr);

        // ---------------- Level 0: conv1 (1->32), conv12 (32->32) ----------
        {
            int E = ES[0], n = NS[0];
            const int* off = csr + OFF2[0];
            const int* pos = posArr + EBASE[0];
            conv1_y<<<cdiv(E, 8), TB, 0, stream>>>(x, src[0], pseudo[0], pos, Wp[0], y, E);
            fin_gather_k<1, 32><<<cdiv(n, 8), TB, 0, stream>>>(x, Rp[0], Bp[0], off, y, bufA, n);
            mfma_conv<32, 32><<<MT[0], TB, 0, stream>>>(
                bufA, src[0], pseudo[0], pack, tileOf, pos, Wtb + WT_OFF[0], y, TB_[0]);
            fin_gather_k<32, 32><<<cdiv(n, 8), TB, 0, stream>>>(bufA, Rp[1], Bp[1], off, y, bufB, n);
            pool_gather<32><<<cdiv(NS[1] * 32, 256), 256, 0, stream>>>(
                bufB, clist + NODE_OFF[0], bufA, NS[1]);
        }
        // ---------------- Level 1: conv2 (32->64), conv3 (64->64) ----------
        {
            int n = NS[1];
            const int* off = csr + OFF2[1];
            const int* pos = posArr + EBASE[1];
            mfma_conv<32, 64><<<MT[1], TB, 0, stream>>>(
                bufA, src[1], pseudo[1], pack, tileOf, pos, Wtb + WT_OFF[1], y, TB_[1]);
            fin_gather_k<32, 64><<<cdiv(n, 4), TB, 0, stream>>>(bufA, Rp[2], Bp[2], off, y, bufB, n);
            mfma_conv<64, 64><<<MT[1], TB, 0, stream>>>(
                bufB, src[1], pseudo[1], pack, tileOf, pos, Wtb + WT_OFF[2], y, TB_[1]);
            fin_gather_k<64, 64><<<cdiv(n, 4), TB, 0, stream>>>(bufB, Rp[3], Bp[3], off, y, bufA, n);
            pool_gather<64><<<cdiv(NS[2] * 64, 256), 256, 0, stream>>>(
                bufA, clist + NODE_OFF[1], bufB, NS[2]);
        }
        // ---------------- Level 2: conv4, conv5 (64->64) -------------------
        {
            int n = NS[2];
            const int* off = csr + OFF2[2];
            const int* pos = posArr + EBASE[2];
            mfma_conv<64, 64><<<MT[2], TB, 0, stream>>>(
                bufB, src[2], pseudo[2], pack, tileOf, pos, Wtb + WT_OFF[3], y, TB_[2]);
            fin_gather_k<64, 64><<<cdiv(n, 4), TB, 0, stream>>>(bufB, Rp[4], Bp[4], off, y, bufA, n);
            mfma_conv<64, 64><<<MT[2], TB, 0, stream>>>(
                bufA, src[2], pseudo[2], pack, tileOf, pos, Wtb + WT_OFF[4], y, TB_[2]);
            fin_gather_k<64, 64><<<cdiv(n, 4), TB, 0, stream>>>(bufA, Rp[5], Bp[5], off, y, bufB, n);
            pool_gather<64><<<cdiv(NS[3] * 64, 256), 256, 0, stream>>>(
                bufB, clist + NODE_OFF[2], bufA, NS[3]);
        }
        // ---------------- Level 3: conv6, conv7 (64->64) -------------------
        {
            int n = NS[3];
            const int* off = csr + OFF2[3];
            const int* pos = posArr + EBASE[3];
            mfma_conv<64, 64><<<MT[3], TB, 0, stream>>>(
                bufA, src[3], pseudo[3], pack, tileOf, pos, Wtb + WT_OFF[5], y, TB_[3]);
            fin_gather_k<64, 64><<<cdiv(n, 4), TB, 0, stream>>>(bufA, Rp[6], Bp[6], off, y, bufB, n);
            mfma_conv<64, 64><<<MT[3], TB, 0, stream>>>(
                bufB, src[3], pseudo[3], pack, tileOf, pos, Wtb + WT_OFF[6], y, TB_[3]);
            fin_gather_k<64, 64><<<cdiv(n, 4), TB, 0, stream>>>(bufB, Rp[7], Bp[7], off, y, bufA, n);
            pool_gather<64><<<cdiv(NS[4] * 64, 256), 256, 0, stream>>>(
                bufA, clist + NODE_OFF[3], bufB, NS[4]);
        }
        head_kernel<<<1, 64, 0, stream>>>(bufB, fc1w, fc1b, fc2w, fc2b, outp);
    } else if (ws_size >= fallbackNeed) {
        // ---------------- legacy edge-centric fallback ---------------------
        float* h0 = bufA;
        float* h1 = bufB;
        float* deg = (float*)degi;
        for (int l = 0; l < 4; ++l) {
            int E = ES[l], n = NS[l];
            (void)hipMemsetAsync(deg, 0, n * 4, stream);
            deg_kernel<<<cdiv(E, TB), TB, 0, stream>>>(dst[l], deg, E);
            for (int cc = 0; cc < 2; ++cc) {
                int li = (l == 0) ? cc : 2 * l + cc;
                if (l == 0 && cc == 0) {
                    (void)hipMemsetAsync(h0, 0, (size_t)n * 32 * 4, stream);
                    conv1_fused<<<cdiv(E, 8), TB, 0, stream>>>(x, src[0], dst[0], pseudo[0], Wp[0], h0, E);
                    finalize_k<1, 32><<<cdiv(n, 8), TB, 0, stream>>>(x, Rp[0], Bp[0], deg, h0, n);
                } else {
                    int ic = (l == 0) ? 32 : ((l == 1 && cc == 0) ? 32 : 64);
                    int oc = (l == 0) ? 32 : 64;
                    (void)hipMemsetAsync(h1, 0, (size_t)n * oc * 4, stream);
                    if (ic == 32 && oc == 32) {
                        conv_edges_inline<32, 32><<<cdiv(E, 8), TB, 0, stream>>>(h0, src[l], dst[l], pseudo[l], Wp[li], h1, E);
                        finalize_k<32, 32><<<cdiv(n, 8), TB, 0, stream>>>(h0, Rp[li], Bp[li], deg, h1, n);
                    } else if (ic == 32) {
                        conv_edges_inline<32, 64><<<cdiv(E, 4), TB, 0, stream>>>(h0, src[l], dst[l], pseudo[l], Wp[li], h1, E);
                        finalize_k<32, 64><<<cdiv(n, 4), TB, 0, stream>>>(h0, Rp[li], Bp[li], deg, h1, n);
                    } else {
                        conv_edges_inline<64, 64><<<cdiv(E, 4), TB, 0, stream>>>(h0, src[l], dst[l], pseudo[l], Wp[li], h1, E);
                        finalize_k<64, 64><<<cdiv(n, 4), TB, 0, stream>>>(h0, Rp[li], Bp[li], deg, h1, n);
                    }
                    float* tmp = h0; h0 = h1; h1 = tmp;
                }
            }
            int oc = (l == 0) ? 32 : 64;
            int logC = (l == 0) ? 5 : 6;
            (void)hipMemsetAsync(pool, 0, (size_t)NS[l + 1] * oc * 4, stream);
            pool_scatter<<<cdiv(n * oc, TB), TB, 0, stream>>>(h0, cluster[l], pool, n, logC);
            pool_decode<<<cdiv(NS[l + 1] * oc, TB), TB, 0, stream>>>(pool, h1, NS[l + 1] * oc);
            float* tmp = h0; h0 = h1; h1 = tmp;
        }
        head_kernel<<<1, 64, 0, stream>>>(h0, fc1w, fc1b, fc2w, fc2b, outp);
    }
}